// Round 2
// baseline (6876.872 us; speedup 1.0000x reference)
//
#include <hip/hip_runtime.h>
#include <hip/hip_bf16.h>
#include <stdint.h>

#define NN 8192
#define EDG 131072
#define CHUNK 1024
#define NCHUNK 8
#define CSLICE 8            // col-stat row-slices per chunk
#define NSLICE (NCHUNK * CSLICE)

typedef __attribute__((ext_vector_type(8))) short bf16x8;
typedef __attribute__((ext_vector_type(4))) float f32x4;

__device__ __forceinline__ unsigned short f2bf(float f) {
  union { float f; unsigned u; } v; v.f = f;
  return (unsigned short)((v.u + 0x7fffu + ((v.u >> 16) & 1u)) >> 16);
}

__device__ __forceinline__ void load_lds16(const void* g, void* l) {
  __builtin_amdgcn_global_load_lds(
      (__attribute__((address_space(1))) void*)(uintptr_t)g,
      (__attribute__((address_space(3))) void*)(uintptr_t)l,
      16, 0, 0);
}

// ---------------------------------------------------------------------------
// C[M,N] (+)= A[M,K] * Bt[N,K]^T   (bf16 in, fp32 accum)
// grid = (M/128, N/128, zsplits), block = 256 (4 waves, 2x2 of 64x64)
// K range covered = gridDim.z * kPerSplit.
// AMODE 0: A bf16 row-major (lda), via global_load_lds
// AMODE 1: A[i,k] = exp(simp[i*NN+k]-stm[i])*sts[i]      (row softmax, i local)
// AMODE 2: A[j,k] = exp(simp[k*NN+j]-stm[j])*sts[j]      (col softmax, transposed)
// EPI 0: store; 1: atomicAdd; 2: +bias[col] store; 3: tanh(+bias[col]) store
// ---------------------------------------------------------------------------
template <int AMODE, int EPI>
__global__ __launch_bounds__(256) void gemm_k(
    const unsigned short* __restrict__ A, int lda,
    const unsigned short* __restrict__ Bt, int ldb,
    const float* __restrict__ simp, const float* __restrict__ stm,
    const float* __restrict__ sts, const float* __restrict__ bias,
    float* __restrict__ C, int ldc, int kPerSplit) {
  __shared__ alignas(16) unsigned short As[128 * 32];
  __shared__ alignas(16) unsigned short Bs[128 * 32];
  const int t = threadIdx.x;
  const int wave = t >> 6, lane = t & 63;
  const int wm = (wave >> 1) * 64, wn = (wave & 1) * 64;
  const int lrow = lane & 15, quad = lane >> 4;
  const int rowBase = blockIdx.x * 128;
  const int colBase = blockIdx.y * 128;
  const int k0 = blockIdx.z * kPerSplit;
  const int k1 = k0 + kPerSplit;

  f32x4 acc[4][4];
#pragma unroll
  for (int i = 0; i < 4; i++)
#pragma unroll
    for (int j = 0; j < 4; j++) acc[i][j] = f32x4{0.f, 0.f, 0.f, 0.f};

  const int sr = t >> 2;   // 0..63 staging row
  const int sch = t & 3;   // 16B chunk in 64B row

  float aM[4], aS[4];
  if (AMODE == 1) {
#pragma unroll
    for (int it = 0; it < 4; it++) {
      int r = (t >> 3) + it * 32;
      aM[it] = stm[rowBase + r];
      aS[it] = sts[rowBase + r];
    }
  }
  const int jl = t & 127, kg = t >> 7;
  float cM = 0.f, cS = 0.f;
  if (AMODE == 2) { cM = stm[rowBase + jl]; cS = sts[rowBase + jl]; }

  for (int kb = k0; kb < k1; kb += 32) {
    __syncthreads();
    { // B staging: 128x32, two wave-uniform-base async 16B loads
      const unsigned short* bsrc = Bt + (size_t)(colBase + sr) * ldb + kb + sch * 8;
      load_lds16(bsrc, (char*)Bs + t * 16);
      load_lds16(bsrc + (size_t)64 * ldb, (char*)Bs + t * 16 + 4096);
    }
    if (AMODE == 0) {
      const unsigned short* asrc = A + (size_t)(rowBase + sr) * lda + kb + sch * 8;
      load_lds16(asrc, (char*)As + t * 16);
      load_lds16(asrc + (size_t)64 * lda, (char*)As + t * 16 + 4096);
    } else if (AMODE == 1) {
#pragma unroll
      for (int it = 0; it < 4; it++) {
        const int r = (t >> 3) + it * 32;
        const int c4 = (t & 7) * 4;
        f32x4 v = *(const f32x4*)(simp + (size_t)(rowBase + r) * NN + kb + c4);
        unsigned u0 = f2bf(__expf(v.x - aM[it]) * aS[it]);
        unsigned u1 = f2bf(__expf(v.y - aM[it]) * aS[it]);
        unsigned u2 = f2bf(__expf(v.z - aM[it]) * aS[it]);
        unsigned u3 = f2bf(__expf(v.w - aM[it]) * aS[it]);
        uint2 pk; pk.x = u0 | (u1 << 16); pk.y = u2 | (u3 << 16);
        *(uint2*)&As[r * 32 + c4] = pk;
      }
    } else if (AMODE == 2) {
      unsigned pk[8];
#pragma unroll
      for (int q = 0; q < 8; q++) pk[q] = 0u;
#pragma unroll
      for (int kk = 0; kk < 16; kk++) {
        const int k = kg * 16 + kk;
        float x = simp[(size_t)(kb + k) * NN + rowBase + jl];
        unsigned b = f2bf(__expf(x - cM) * cS);
        pk[kk >> 1] |= b << ((kk & 1) * 16);
      }
      unsigned short* dst = &As[jl * 32 + kg * 16];
      uint4 w0; w0.x = pk[0]; w0.y = pk[1]; w0.z = pk[2]; w0.w = pk[3];
      uint4 w1; w1.x = pk[4]; w1.y = pk[5]; w1.z = pk[6]; w1.w = pk[7];
      *(uint4*)dst = w0;
      *(uint4*)(dst + 8) = w1;
    }
    __syncthreads();

    bf16x8 af[4], bfr[4];
#pragma unroll
    for (int i = 0; i < 4; i++)
      af[i] = *(const bf16x8*)&As[(wm + i * 16 + lrow) * 32 + quad * 8];
#pragma unroll
    for (int j = 0; j < 4; j++)
      bfr[j] = *(const bf16x8*)&Bs[(wn + j * 16 + lrow) * 32 + quad * 8];
#pragma unroll
    for (int i = 0; i < 4; i++)
#pragma unroll
      for (int j = 0; j < 4; j++)
        acc[i][j] = __builtin_amdgcn_mfma_f32_16x16x32_bf16(af[i], bfr[j], acc[i][j], 0, 0, 0);
  }

#pragma unroll
  for (int i = 0; i < 4; i++) {
    int row = rowBase + wm + i * 16 + quad * 4;
#pragma unroll
    for (int j = 0; j < 4; j++) {
      int col = colBase + wn + j * 16 + lrow;
#pragma unroll
      for (int r = 0; r < 4; r++) {
        float v = acc[i][j][r];
        size_t idx = (size_t)(row + r) * ldc + col;
        if (EPI == 0) C[idx] = v;
        else if (EPI == 1) atomicAdd(&C[idx], v);
        else {
          v += bias[col];
          if (EPI == 3) v = tanhf(v);
          C[idx] = v;
        }
      }
    }
  }
}

// --------------------------- small kernels ---------------------------------

__global__ void ws_sentinel(float* out) { out[0] = 12345.0f; out[1] = 12345.0f; }

__global__ void cvt_bf16(const float* __restrict__ in, unsigned short* __restrict__ out, int n) {
  int i = (blockIdx.x * 256 + threadIdx.x) * 4;
  if (i < n) {
    f32x4 v = *(const f32x4*)(in + i);
    uint2 p;
    p.x = f2bf(v.x) | ((unsigned)f2bf(v.y) << 16);
    p.y = f2bf(v.z) | ((unsigned)f2bf(v.w) << 16);
    *(uint2*)(out + i) = p;
  }
}

// dst[C][R] = bf16(src[R][C])
__global__ void transpose_bf16(const float* __restrict__ src, unsigned short* __restrict__ dst,
                               int R, int C) {
  __shared__ float tile[32][33];
  int c0 = blockIdx.x * 32, r0 = blockIdx.y * 32;
  int x = threadIdx.x, y = threadIdx.y;
  for (int i = y; i < 32; i += 8) tile[i][x] = src[(size_t)(r0 + i) * C + c0 + x];
  __syncthreads();
  for (int i = y; i < 32; i += 8) dst[(size_t)(c0 + i) * R + r0 + x] = f2bf(tile[x][i]);
}

__global__ void deg_count(const int* __restrict__ dst, int* __restrict__ deg) {
  int e = blockIdx.x * 256 + threadIdx.x;
  atomicAdd(&deg[dst[e]], 1);
}

__global__ void make_dinv(const int* __restrict__ deg, float* __restrict__ dinv) {
  int v = blockIdx.x * 256 + threadIdx.x;
  dinv[v] = rsqrtf((float)(deg[v] + 1));  // +1 self-loop
}

__global__ void gcn_selfinit(const float* __restrict__ dinv, const float* __restrict__ h,
                             float* __restrict__ c) {
  size_t e = ((size_t)blockIdx.x * 256 + threadIdx.x) * 4;
  int v = (int)(e >> 8);
  float w = dinv[v]; w = w * w;
  f32x4 hv = *(const f32x4*)(h + e);
  f32x4 o = {w * hv.x, w * hv.y, w * hv.z, w * hv.w};
  *(f32x4*)(c + e) = o;
}

__global__ void gcn_scatter(const int* __restrict__ src, const int* __restrict__ dst,
                            const float* __restrict__ dinv, const float* __restrict__ h,
                            float* __restrict__ c) {
  int e = blockIdx.x * 4 + (threadIdx.x >> 6);
  int lane = threadIdx.x & 63;
  int s = src[e], d = dst[e];
  float w = dinv[s] * dinv[d];
  f32x4 v = *(const f32x4*)(h + (size_t)s * 256 + lane * 4);
  float* cp = c + (size_t)d * 256 + lane * 4;
  atomicAdd(cp + 0, w * v.x);
  atomicAdd(cp + 1, w * v.y);
  atomicAdd(cp + 2, w * v.z);
  atomicAdd(cp + 3, w * v.w);
}

// per-chunk row softmax stats: one block per row (CHUNK rows)
__global__ void row_stats(const float* __restrict__ simc, float* __restrict__ rm,
                          float* __restrict__ rsi) {
  int row = blockIdx.x;
  const float* p = simc + (size_t)row * NN;
  int t = threadIdx.x;
  float m = -3.0e38f, s = 0.f;
  for (int j = t; j < NN; j += 256) {
    float x = p[j];
    if (x > m) { s = s * __expf(m - x) + 1.f; m = x; }
    else s += __expf(x - m);
  }
  __shared__ float sm[256], ss[256];
  sm[t] = m; ss[t] = s;
  __syncthreads();
  for (int off = 128; off > 0; off >>= 1) {
    if (t < off) {
      float m2 = sm[t + off], s2 = ss[t + off];
      float M = fmaxf(sm[t], m2);
      ss[t] = ss[t] * __expf(sm[t] - M) + s2 * __expf(m2 - M);
      sm[t] = M;
    }
    __syncthreads();
  }
  if (t == 0) { rm[row] = sm[0]; rsi[row] = 1.f / ss[0]; }
}

// per-chunk col partial stats: grid (32, CSLICE); slice = 128 rows of the chunk
__global__ void col_stats_part(const float* __restrict__ simc, float* __restrict__ pm,
                               float* __restrict__ ps) {
  int col = blockIdx.x * 256 + threadIdx.x;
  int rs = blockIdx.y;
  float m = -3.0e38f, s = 0.f;
  for (int i = rs * (CHUNK / CSLICE); i < (rs + 1) * (CHUNK / CSLICE); i++) {
    float x = simc[(size_t)i * NN + col];
    if (x > m) { s = s * __expf(m - x) + 1.f; m = x; }
    else s += __expf(x - m);
  }
  pm[(size_t)rs * NN + col] = m;
  ps[(size_t)rs * NN + col] = s;
}

__global__ void col_stats_merge(const float* __restrict__ pm, const float* __restrict__ ps,
                                float* __restrict__ cm, float* __restrict__ csi) {
  int col = blockIdx.x * 256 + threadIdx.x;
  float m = -3.0e38f, s = 0.f;
  for (int rs = 0; rs < NSLICE; rs++) {
    float m2 = pm[(size_t)rs * NN + col], s2 = ps[(size_t)rs * NN + col];
    float M = fmaxf(m, m2);
    s = s * __expf(m - M) + s2 * __expf(m2 - M);
    m = M;
  }
  cm[col] = m;
  csi[col] = 1.f / s;
}

// cat[i][:] = bf16([ c[i](256) | f[i](din) | f[i]-att[i](din) ])
__global__ void build_cat(const float* __restrict__ cbuf, const float* __restrict__ f,
                          const float* __restrict__ att, unsigned short* __restrict__ cat,
                          int din, int W) {
  int i = blockIdx.y;
  int c = blockIdx.x * 256 + threadIdx.x;
  float v;
  if (c < 256) v = cbuf[(size_t)i * 256 + c];
  else if (c < 256 + din) v = f[(size_t)i * din + (c - 256)];
  else v = f[(size_t)i * din + (c - 256 - din)] - att[(size_t)i * din + (c - 256 - din)];
  cat[(size_t)i * W + c] = f2bf(v);
}

__global__ void gated_pool(const float* __restrict__ q, const float* __restrict__ f,
                           float* __restrict__ p) {
  int col = threadIdx.x;
  int r0 = blockIdx.x * 128;
  float a = 0.f;
  for (int i = r0; i < r0 + 128; i++) {
    float qv = q[(size_t)i * 256 + col];
    a += f[(size_t)i * 256 + col] / (1.f + __expf(-qv));
  }
  atomicAdd(&p[col], a);
}

__global__ void ntn_bilinear(const float* __restrict__ p1, const float* __restrict__ tnW,
                             float* __restrict__ tmp) {
  int c = blockIdx.x * 256 + threadIdx.x;
  float a = 0.f;
#pragma unroll 8
  for (int i = 0; i < 256; i++) a += p1[i] * tnW[(size_t)i * 8192 + c];
  tmp[c] = a;
}

__global__ void ntn_final(const float* __restrict__ tmp, const float* __restrict__ p1,
                          const float* __restrict__ p2, const float* __restrict__ tnWb,
                          const float* __restrict__ tnb, const float* __restrict__ fc1W,
                          const float* __restrict__ fc1b, const float* __restrict__ scW,
                          const float* __restrict__ scb, const float* __restrict__ avgv,
                          float* __restrict__ out) {
  __shared__ float pc[512];
  __shared__ float ntn[32];
  __shared__ float sarr[16];
  int t = threadIdx.x;
  pc[t] = p1[t];
  pc[256 + t] = p2[t];
  __syncthreads();
  if (t < 32) {
    float sc = 0.f;
    for (int j = 0; j < 256; j++) sc += tmp[j * 32 + t] * pc[256 + j];
    float bl = 0.f;
    for (int k = 0; k < 512; k++) bl += tnWb[t * 512 + k] * pc[k];
    float v = sc + bl + tnb[t];
    ntn[t] = v > 0.f ? v : 0.f;
  }
  __syncthreads();
  if (t < 16) {
    float a = fc1b[t];
    for (int i = 0; i < 32; i++) a += ntn[i] * fc1W[i * 16 + t];
    sarr[t] = tanhf(a);
  }
  __syncthreads();
  if (t == 0) {
    float a = scb[0];
    for (int b = 0; b < 16; b++) a += sarr[b] * scW[b];
    float score = 1.f / (1.f + expf(-a));
    out[0] = score;
    out[1] = -logf(score) * avgv[0];
  }
}

// ---------------------------------------------------------------------------

extern "C" void kernel_launch(void* const* d_in, const int* in_sizes, int n_in,
                              void* d_out, int out_size, void* d_ws, size_t ws_size,
                              hipStream_t stream) {
  (void)in_sizes; (void)n_in; (void)out_size;
  const float* feat1 = (const float*)d_in[0];
  const float* feat2 = (const float*)d_in[1];
  const int* ei1 = (const int*)d_in[2];
  const int* ei2 = (const int*)d_in[3];
  const float* avgv = (const float*)d_in[4];
  const float* gcnW[3] = {(const float*)d_in[5], (const float*)d_in[8], (const float*)d_in[11]};
  const float* updW[3] = {(const float*)d_in[6], (const float*)d_in[9], (const float*)d_in[12]};
  const float* updb[3] = {(const float*)d_in[7], (const float*)d_in[10], (const float*)d_in[13]};
  const float* gatedW = (const float*)d_in[14];
  const float* gatedb = (const float*)d_in[15];
  const float* tnW = (const float*)d_in[16];
  const float* tnWb = (const float*)d_in[17];
  const float* tnb = (const float*)d_in[18];
  const float* fc1W = (const float*)d_in[19];
  const float* fc1b = (const float*)d_in[20];
  const float* scW = (const float*)d_in[21];
  const float* scb = (const float*)d_in[22];
  float* out = (float*)d_out;

  char* wp = (char*)d_ws;
  auto take = [&](size_t b) { char* p = wp; wp += (b + 255) & ~(size_t)255; return p; };
  float* simC = (float*)take((size_t)CHUNK * NN * 4);          // 32 MB (also cat1/cat2)
  float* fb1 = (float*)take((size_t)NN * 256 * 4);
  float* fb2 = (float*)take((size_t)NN * 256 * 4);
  unsigned short* f1b = (unsigned short*)take((size_t)NN * 256 * 2);
  unsigned short* f2b = (unsigned short*)take((size_t)NN * 256 * 2);
  unsigned short* f1bT = (unsigned short*)take((size_t)NN * 256 * 2);
  unsigned short* f2bT = (unsigned short*)take((size_t)NN * 256 * 2);
  float* h1 = (float*)take((size_t)NN * 256 * 4);   // h, then att1
  float* h2 = (float*)take((size_t)NN * 256 * 4);   // h, then att2
  float* c1 = (float*)take((size_t)NN * 256 * 4);   // gcn agg, then q (gated)
  float* c2 = (float*)take((size_t)NN * 256 * 4);
  unsigned short* WgT[3], *WuT[3];
  for (int l = 0; l < 3; l++) WgT[l] = (unsigned short*)take(256 * 256 * 2);
  for (int l = 0; l < 3; l++) WuT[l] = (unsigned short*)take(256 * 768 * 2);
  unsigned short* gWT = (unsigned short*)take(256 * 256 * 2);
  int* deg1 = (int*)take(NN * 4);
  int* deg2 = (int*)take(NN * 4);
  float* dinv1 = (float*)take(NN * 4);
  float* dinv2 = (float*)take(NN * 4);
  float* rm = (float*)take(NN * 4);
  float* rsi = (float*)take(NN * 4);
  float* cmx = (float*)take(NN * 4);
  float* csi = (float*)take(NN * 4);
  float* cpm = (float*)take((size_t)NSLICE * NN * 4);
  float* cps = (float*)take((size_t)NSLICE * NN * 4);
  float* p1 = (float*)take(1024);
  float* p2 = (float*)take(1024);
  float* tmp = (float*)take(NN * 4);
  // cat buffers overlap the (dead-by-then) sim chunk
  unsigned short* cat1 = (unsigned short*)simC;
  unsigned short* cat2 = cat1 + (size_t)NN * 768;

  size_t need = (size_t)(wp - (char*)d_ws);
  if (need > ws_size) {  // ws_size is call-invariant -> same work every call
    ws_sentinel<<<1, 1, 0, stream>>>(out);
    return;
  }

  // degree / dinv
  hipMemsetAsync(deg1, 0, NN * 4, stream);
  hipMemsetAsync(deg2, 0, NN * 4, stream);
  deg_count<<<EDG / 256, 256, 0, stream>>>(ei1 + EDG, deg1);
  deg_count<<<EDG / 256, 256, 0, stream>>>(ei2 + EDG, deg2);
  make_dinv<<<NN / 256, 256, 0, stream>>>(deg1, dinv1);
  make_dinv<<<NN / 256, 256, 0, stream>>>(deg2, dinv2);

  // weights -> bf16 [out][in]
  for (int l = 0; l < 3; l++) {
    int din = (l == 0) ? 128 : 256;
    int W = 256 + 2 * din;
    transpose_bf16<<<dim3(8, din / 32), dim3(32, 8), 0, stream>>>(gcnW[l], WgT[l], din, 256);
    transpose_bf16<<<dim3(8, W / 32), dim3(32, 8), 0, stream>>>(updW[l], WuT[l], W, 256);
  }
  transpose_bf16<<<dim3(8, 8), dim3(32, 8), 0, stream>>>(gatedW, gWT, 256, 256);

  const float* f1 = feat1;
  const float* f2 = feat2;

  for (int l = 0; l < 3; l++) {
    const int din = (l == 0) ? 128 : 256;
    const int W = 256 + 2 * din;
    const int nel = NN * din;

    cvt_bf16<<<nel / 1024, 256, 0, stream>>>(f1, f1b, nel);
    cvt_bf16<<<nel / 1024, 256, 0, stream>>>(f2, f2b, nel);
    transpose_bf16<<<dim3(din / 32, NN / 32), dim3(32, 8), 0, stream>>>(f1, f1bT, NN, din);
    transpose_bf16<<<dim3(din / 32, NN / 32), dim3(32, 8), 0, stream>>>(f2, f2bT, NN, din);

    // h = f @ Wg
    gemm_k<0, 0><<<dim3(64, 2, 1), 256, 0, stream>>>(f1b, din, WgT[l], din, nullptr, nullptr, nullptr, nullptr, h1, 256, din);
    gemm_k<0, 0><<<dim3(64, 2, 1), 256, 0, stream>>>(f2b, din, WgT[l], din, nullptr, nullptr, nullptr, nullptr, h2, 256, din);

    // c = D^-1/2 (A+I) D^-1/2 h
    gcn_selfinit<<<NN * 256 / 1024, 256, 0, stream>>>(dinv1, h1, c1);
    gcn_selfinit<<<NN * 256 / 1024, 256, 0, stream>>>(dinv2, h2, c2);
    gcn_scatter<<<EDG / 4, 256, 0, stream>>>(ei1, ei1 + EDG, dinv1, h1, c1);
    gcn_scatter<<<EDG / 4, 256, 0, stream>>>(ei2, ei2 + EDG, dinv2, h2, c2);

    // att1 accumulator (h1 now free), att2 accumulator zeroed later
    hipMemsetAsync(h1, 0, (size_t)NN * din * 4, stream);

    // pass 1: per row-chunk of sim: sim -> row stats -> att1 rows; col partials
    for (int ci = 0; ci < NCHUNK; ci++) {
      const int r0 = ci * CHUNK;
      gemm_k<0, 0><<<dim3(CHUNK / 128, 64, 1), 256, 0, stream>>>(
          f1b + (size_t)r0 * din, din, f2b, din, nullptr, nullptr, nullptr, nullptr,
          simC, NN, din);
      row_stats<<<CHUNK, 256, 0, stream>>>(simC, rm + r0, rsi + r0);
      col_stats_part<<<dim3(32, CSLICE), 256, 0, stream>>>(
          simC, cpm + (size_t)ci * CSLICE * NN, cps + (size_t)ci * CSLICE * NN);
      gemm_k<1, 1><<<dim3(CHUNK / 128, din / 128, 8), 256, 0, stream>>>(
          nullptr, 0, f2bT, NN, simC, rm + r0, rsi + r0, nullptr,
          h1 + (size_t)r0 * din, din, NN / 8);
    }
    col_stats_merge<<<NN / 256, 256, 0, stream>>>(cpm, cps, cmx, csi);

    // pass 2: recompute sim chunk, accumulate att2
    hipMemsetAsync(h2, 0, (size_t)NN * din * 4, stream);
    for (int ci = 0; ci < NCHUNK; ci++) {
      const int r0 = ci * CHUNK;
      gemm_k<0, 0><<<dim3(CHUNK / 128, 64, 1), 256, 0, stream>>>(
          f1b + (size_t)r0 * din, din, f2b, din, nullptr, nullptr, nullptr, nullptr,
          simC, NN, din);
      gemm_k<2, 1><<<dim3(64, din / 128, 2), 256, 0, stream>>>(
          nullptr, 0, f1bT + r0, NN, simC, cmx, csi, nullptr,
          h2, din, CHUNK / 2);
    }

    // g = tanh?(concat([c, f, f-att]) @ Wu + bu)   (cat overlaps dead simC)
    build_cat<<<dim3(W / 256, NN), 256, 0, stream>>>(c1, f1, h1, cat1, din, W);
    build_cat<<<dim3(W / 256, NN), 256, 0, stream>>>(c2, f2, h2, cat2, din, W);
    if (l < 2) {
      gemm_k<0, 3><<<dim3(64, 2, 1), 256, 0, stream>>>(cat1, W, WuT[l], W, nullptr, nullptr, nullptr, updb[l], fb1, 256, W);
      gemm_k<0, 3><<<dim3(64, 2, 1), 256, 0, stream>>>(cat2, W, WuT[l], W, nullptr, nullptr, nullptr, updb[l], fb2, 256, W);
    } else {
      gemm_k<0, 2><<<dim3(64, 2, 1), 256, 0, stream>>>(cat1, W, WuT[l], W, nullptr, nullptr, nullptr, updb[l], fb1, 256, W);
      gemm_k<0, 2><<<dim3(64, 2, 1), 256, 0, stream>>>(cat2, W, WuT[l], W, nullptr, nullptr, nullptr, updb[l], fb2, 256, W);
    }
    f1 = fb1;
    f2 = fb2;
  }

  // gated readout
  cvt_bf16<<<NN * 256 / 1024, 256, 0, stream>>>(f1, f1b, NN * 256);
  cvt_bf16<<<NN * 256 / 1024, 256, 0, stream>>>(f2, f2b, NN * 256);
  gemm_k<0, 2><<<dim3(64, 2, 1), 256, 0, stream>>>(f1b, 256, gWT, 256, nullptr, nullptr, nullptr, gatedb, c1, 256, 256);
  gemm_k<0, 2><<<dim3(64, 2, 1), 256, 0, stream>>>(f2b, 256, gWT, 256, nullptr, nullptr, nullptr, gatedb, c2, 256, 256);
  hipMemsetAsync(p1, 0, 256 * 4, stream);
  hipMemsetAsync(p2, 0, 256 * 4, stream);
  gated_pool<<<64, 256, 0, stream>>>(c1, f1, p1);
  gated_pool<<<64, 256, 0, stream>>>(c2, f2, p2);

  // NTN + scoring head
  ntn_bilinear<<<32, 256, 0, stream>>>(p1, tnW, tmp);
  ntn_final<<<1, 256, 0, stream>>>(tmp, p1, p2, tnWb, tnb, fc1W, fc1b, scW, scb, avgv, out);
}

// Round 3
// 4324.265 us; speedup vs baseline: 1.5903x; 1.5903x over previous
//
#include <hip/hip_runtime.h>
#include <hip/hip_bf16.h>
#include <stdint.h>

#define NN 8192
#define EDG 131072
#define CHUNK 1024
#define NCHUNK 8
#define CSLICE 8            // col-stat row-slices per chunk
#define NSLICE (NCHUNK * CSLICE)

typedef __attribute__((ext_vector_type(8))) short bf16x8;
typedef __attribute__((ext_vector_type(4))) float f32x4;

__device__ __forceinline__ unsigned short f2bf(float f) {
  union { float f; unsigned u; } v; v.f = f;
  return (unsigned short)((v.u + 0x7fffu + ((v.u >> 16) & 1u)) >> 16);
}

__device__ __forceinline__ void load_lds16(const void* g, void* l) {
  __builtin_amdgcn_global_load_lds(
      (__attribute__((address_space(1))) void*)(uintptr_t)g,
      (__attribute__((address_space(3))) void*)(uintptr_t)l,
      16, 0, 0);
}

// ---------------------------------------------------------------------------
// C[M,N] (+)= A[M,K] * Bt[N,K]^T   (bf16 in, fp32 accum)
// grid = (M/128, N/128, zsplits), block = 256 (4 waves, 2x2 of 64x64)
// AMODE 0: A bf16 row-major (lda), via global_load_lds
// AMODE 1: A[i,k] = exp(simp[i*NN+k]-stm[i])*sts[i]      (row softmax, i local)
// AMODE 2: A[j,k] = exp(simp[k*NN+j]-stm[j])*sts[j]      (col softmax, transposed)
// EPI 0: store; 1: atomicAdd; 2: +bias[col] store; 3: tanh(+bias[col]) store
// ---------------------------------------------------------------------------
template <int AMODE, int EPI>
__global__ __launch_bounds__(256) void gemm_k(
    const unsigned short* __restrict__ A, int lda,
    const unsigned short* __restrict__ Bt, int ldb,
    const float* __restrict__ simp, const float* __restrict__ stm,
    const float* __restrict__ sts, const float* __restrict__ bias,
    float* __restrict__ C, int ldc, int kPerSplit) {
  __shared__ alignas(16) unsigned short As[128 * 32];
  __shared__ alignas(16) unsigned short Bs[128 * 32];
  const int t = threadIdx.x;
  const int wave = t >> 6, lane = t & 63;
  const int wm = (wave >> 1) * 64, wn = (wave & 1) * 64;
  const int lrow = lane & 15, quad = lane >> 4;
  const int rowBase = blockIdx.x * 128;
  const int colBase = blockIdx.y * 128;
  const int k0 = blockIdx.z * kPerSplit;
  const int k1 = k0 + kPerSplit;

  f32x4 acc[4][4];
#pragma unroll
  for (int i = 0; i < 4; i++)
#pragma unroll
    for (int j = 0; j < 4; j++) acc[i][j] = f32x4{0.f, 0.f, 0.f, 0.f};

  const int sr = t >> 2;   // 0..63 staging row
  const int sch = t & 3;   // 16B chunk in 64B row

  float aM[4], aS[4];
  if (AMODE == 1) {
#pragma unroll
    for (int it = 0; it < 4; it++) {
      int r = (t >> 3) + it * 32;
      aM[it] = stm[rowBase + r];
      aS[it] = sts[rowBase + r];
    }
  }
  const int jl = t & 127, kg = t >> 7;
  float cM = 0.f, cS = 0.f;
  if (AMODE == 2) { cM = stm[rowBase + jl]; cS = sts[rowBase + jl]; }

  for (int kb = k0; kb < k1; kb += 32) {
    __syncthreads();
    { // B staging: 128x32, two wave-uniform-base async 16B loads
      const unsigned short* bsrc = Bt + (size_t)(colBase + sr) * ldb + kb + sch * 8;
      load_lds16(bsrc, (char*)Bs + t * 16);
      load_lds16(bsrc + (size_t)64 * ldb, (char*)Bs + t * 16 + 4096);
    }
    if (AMODE == 0) {
      const unsigned short* asrc = A + (size_t)(rowBase + sr) * lda + kb + sch * 8;
      load_lds16(asrc, (char*)As + t * 16);
      load_lds16(asrc + (size_t)64 * lda, (char*)As + t * 16 + 4096);
    } else if (AMODE == 1) {
#pragma unroll
      for (int it = 0; it < 4; it++) {
        const int r = (t >> 3) + it * 32;
        const int c4 = (t & 7) * 4;
        f32x4 v = *(const f32x4*)(simp + (size_t)(rowBase + r) * NN + kb + c4);
        unsigned u0 = f2bf(__expf(v.x - aM[it]) * aS[it]);
        unsigned u1 = f2bf(__expf(v.y - aM[it]) * aS[it]);
        unsigned u2 = f2bf(__expf(v.z - aM[it]) * aS[it]);
        unsigned u3 = f2bf(__expf(v.w - aM[it]) * aS[it]);
        uint2 pk; pk.x = u0 | (u1 << 16); pk.y = u2 | (u3 << 16);
        *(uint2*)&As[r * 32 + c4] = pk;
      }
    } else if (AMODE == 2) {
      unsigned pk[8];
#pragma unroll
      for (int q = 0; q < 8; q++) pk[q] = 0u;
#pragma unroll
      for (int kk = 0; kk < 16; kk++) {
        const int k = kg * 16 + kk;
        float x = simp[(size_t)(kb + k) * NN + rowBase + jl];
        unsigned b = f2bf(__expf(x - cM) * cS);
        pk[kk >> 1] |= b << ((kk & 1) * 16);
      }
      unsigned short* dst = &As[jl * 32 + kg * 16];
      uint4 w0; w0.x = pk[0]; w0.y = pk[1]; w0.z = pk[2]; w0.w = pk[3];
      uint4 w1; w1.x = pk[4]; w1.y = pk[5]; w1.z = pk[6]; w1.w = pk[7];
      *(uint4*)dst = w0;
      *(uint4*)(dst + 8) = w1;
    }
    __syncthreads();

    bf16x8 af[4], bfr[4];
#pragma unroll
    for (int i = 0; i < 4; i++)
      af[i] = *(const bf16x8*)&As[(wm + i * 16 + lrow) * 32 + quad * 8];
#pragma unroll
    for (int j = 0; j < 4; j++)
      bfr[j] = *(const bf16x8*)&Bs[(wn + j * 16 + lrow) * 32 + quad * 8];
#pragma unroll
    for (int i = 0; i < 4; i++)
#pragma unroll
      for (int j = 0; j < 4; j++)
        acc[i][j] = __builtin_amdgcn_mfma_f32_16x16x32_bf16(af[i], bfr[j], acc[i][j], 0, 0, 0);
  }

#pragma unroll
  for (int i = 0; i < 4; i++) {
    int row = rowBase + wm + i * 16 + quad * 4;
#pragma unroll
    for (int j = 0; j < 4; j++) {
      int col = colBase + wn + j * 16 + lrow;
#pragma unroll
      for (int r = 0; r < 4; r++) {
        float v = acc[i][j][r];
        size_t idx = (size_t)(row + r) * ldc + col;
        if (EPI == 0) C[idx] = v;
        else if (EPI == 1) atomicAdd(&C[idx], v);
        else {
          v += bias[col];
          if (EPI == 3) v = tanhf(v);
          C[idx] = v;
        }
      }
    }
  }
}

// --------------------------- small kernels ---------------------------------

__global__ void ws_sentinel(float* out) { out[0] = 12345.0f; out[1] = 12345.0f; }

__global__ void cvt_bf16(const float* __restrict__ in, unsigned short* __restrict__ out, int n) {
  int i = (blockIdx.x * 256 + threadIdx.x) * 4;
  if (i < n) {
    f32x4 v = *(const f32x4*)(in + i);
    uint2 p;
    p.x = f2bf(v.x) | ((unsigned)f2bf(v.y) << 16);
    p.y = f2bf(v.z) | ((unsigned)f2bf(v.w) << 16);
    *(uint2*)(out + i) = p;
  }
}

// dst[C][R] = bf16(src[R][C])
__global__ void transpose_bf16(const float* __restrict__ src, unsigned short* __restrict__ dst,
                               int R, int C) {
  __shared__ float tile[32][33];
  int c0 = blockIdx.x * 32, r0 = blockIdx.y * 32;
  int x = threadIdx.x, y = threadIdx.y;
  for (int i = y; i < 32; i += 8) tile[i][x] = src[(size_t)(r0 + i) * C + c0 + x];
  __syncthreads();
  for (int i = y; i < 32; i += 8) dst[(size_t)(c0 + i) * R + r0 + x] = f2bf(tile[x][i]);
}

__global__ void deg_count(const int* __restrict__ dst, int* __restrict__ deg) {
  int e = blockIdx.x * 256 + threadIdx.x;
  atomicAdd(&deg[dst[e]], 1);
}

__global__ void make_dinv(const int* __restrict__ deg, float* __restrict__ dinv) {
  int v = blockIdx.x * 256 + threadIdx.x;
  dinv[v] = rsqrtf((float)(deg[v] + 1));  // +1 self-loop
}

// exclusive prefix sum of deg[8192] -> rowstart[8193]; single block of 1024
__global__ void scan_deg(const int* __restrict__ deg, int* __restrict__ rowstart) {
  __shared__ int part[1024];
  int t = threadIdx.x;
  int base = t * 8;
  int local[8];
  int s = 0;
#pragma unroll
  for (int i = 0; i < 8; i++) { local[i] = s; s += deg[base + i]; }
  part[t] = s;
  __syncthreads();
  for (int off = 1; off < 1024; off <<= 1) {
    int v = (t >= off) ? part[t - off] : 0;
    __syncthreads();
    part[t] += v;
    __syncthreads();
  }
  int offset = (t == 0) ? 0 : part[t - 1];
#pragma unroll
  for (int i = 0; i < 8; i++) rowstart[base + i] = offset + local[i];
  if (t == 1023) rowstart[8192] = offset + s;
}

__global__ void csr_fill(const int* __restrict__ src, const int* __restrict__ dst,
                         int* __restrict__ cursor, int* __restrict__ csr_src) {
  int e = blockIdx.x * 256 + threadIdx.x;
  int pos = atomicAdd(&cursor[dst[e]], 1);
  csr_src[pos] = src[e];
}

// c[v] = dinv[v]^2*h[v] + sum_{e in-edges} dinv[src]*dinv[v]*h[src]
// one wave per node, lane holds 4 dims; no atomics.
__global__ __launch_bounds__(256) void gcn_agg(
    const int* __restrict__ rowstart, const int* __restrict__ csr_src,
    const float* __restrict__ dinv, const float* __restrict__ h,
    float* __restrict__ c) {
  int node = blockIdx.x * 4 + (threadIdx.x >> 6);
  int lane = threadIdx.x & 63;
  float dn = dinv[node];
  f32x4 acc = *(const f32x4*)(h + (size_t)node * 256 + lane * 4);
  float w0 = dn * dn;
  acc.x *= w0; acc.y *= w0; acc.z *= w0; acc.w *= w0;
  int s0 = rowstart[node], s1 = rowstart[node + 1];
  for (int j = s0; j < s1; j++) {
    int s = csr_src[j];
    float w = dinv[s] * dn;
    f32x4 v = *(const f32x4*)(h + (size_t)s * 256 + lane * 4);
    acc.x += w * v.x; acc.y += w * v.y; acc.z += w * v.z; acc.w += w * v.w;
  }
  *(f32x4*)(c + (size_t)node * 256 + lane * 4) = acc;
}

// per-chunk row softmax stats: one block per row (CHUNK rows)
__global__ void row_stats(const float* __restrict__ simc, float* __restrict__ rm,
                          float* __restrict__ rsi) {
  int row = blockIdx.x;
  const float* p = simc + (size_t)row * NN;
  int t = threadIdx.x;
  float m = -3.0e38f, s = 0.f;
  for (int j = t; j < NN; j += 256) {
    float x = p[j];
    if (x > m) { s = s * __expf(m - x) + 1.f; m = x; }
    else s += __expf(x - m);
  }
  __shared__ float sm[256], ss[256];
  sm[t] = m; ss[t] = s;
  __syncthreads();
  for (int off = 128; off > 0; off >>= 1) {
    if (t < off) {
      float m2 = sm[t + off], s2 = ss[t + off];
      float M = fmaxf(sm[t], m2);
      ss[t] = ss[t] * __expf(sm[t] - M) + s2 * __expf(m2 - M);
      sm[t] = M;
    }
    __syncthreads();
  }
  if (t == 0) { rm[row] = sm[0]; rsi[row] = 1.f / ss[0]; }
}

// per-chunk col partial stats: grid (32, CSLICE); slice = 128 rows of the chunk
__global__ void col_stats_part(const float* __restrict__ simc, float* __restrict__ pm,
                               float* __restrict__ ps) {
  int col = blockIdx.x * 256 + threadIdx.x;
  int rs = blockIdx.y;
  float m = -3.0e38f, s = 0.f;
  for (int i = rs * (CHUNK / CSLICE); i < (rs + 1) * (CHUNK / CSLICE); i++) {
    float x = simc[(size_t)i * NN + col];
    if (x > m) { s = s * __expf(m - x) + 1.f; m = x; }
    else s += __expf(x - m);
  }
  pm[(size_t)rs * NN + col] = m;
  ps[(size_t)rs * NN + col] = s;
}

__global__ void col_stats_merge(const float* __restrict__ pm, const float* __restrict__ ps,
                                float* __restrict__ cm, float* __restrict__ csi) {
  int col = blockIdx.x * 256 + threadIdx.x;
  float m = -3.0e38f, s = 0.f;
  for (int rs = 0; rs < NSLICE; rs++) {
    float m2 = pm[(size_t)rs * NN + col], s2 = ps[(size_t)rs * NN + col];
    float M = fmaxf(m, m2);
    s = s * __expf(m - M) + s2 * __expf(m2 - M);
    m = M;
  }
  cm[col] = m;
  csi[col] = 1.f / s;
}

// cat[i][:] = bf16([ c[i](256) | f[i](din) | f[i]-att[i](din) ])
__global__ void build_cat(const float* __restrict__ cbuf, const float* __restrict__ f,
                          const float* __restrict__ att, unsigned short* __restrict__ cat,
                          int din, int W) {
  int i = blockIdx.y;
  int c = blockIdx.x * 256 + threadIdx.x;
  float v;
  if (c < 256) v = cbuf[(size_t)i * 256 + c];
  else if (c < 256 + din) v = f[(size_t)i * din + (c - 256)];
  else v = f[(size_t)i * din + (c - 256 - din)] - att[(size_t)i * din + (c - 256 - din)];
  cat[(size_t)i * W + c] = f2bf(v);
}

__global__ void gated_pool(const float* __restrict__ q, const float* __restrict__ f,
                           float* __restrict__ p) {
  int col = threadIdx.x;
  int r0 = blockIdx.x * 128;
  float a = 0.f;
  for (int i = r0; i < r0 + 128; i++) {
    float qv = q[(size_t)i * 256 + col];
    a += f[(size_t)i * 256 + col] / (1.f + __expf(-qv));
  }
  atomicAdd(&p[col], a);
}

__global__ void ntn_bilinear(const float* __restrict__ p1, const float* __restrict__ tnW,
                             float* __restrict__ tmp) {
  int c = blockIdx.x * 256 + threadIdx.x;
  float a = 0.f;
#pragma unroll 8
  for (int i = 0; i < 256; i++) a += p1[i] * tnW[(size_t)i * 8192 + c];
  tmp[c] = a;
}

__global__ void ntn_final(const float* __restrict__ tmp, const float* __restrict__ p1,
                          const float* __restrict__ p2, const float* __restrict__ tnWb,
                          const float* __restrict__ tnb, const float* __restrict__ fc1W,
                          const float* __restrict__ fc1b, const float* __restrict__ scW,
                          const float* __restrict__ scb, const float* __restrict__ avgv,
                          float* __restrict__ out) {
  __shared__ float pc[512];
  __shared__ float ntn[32];
  __shared__ float sarr[16];
  int t = threadIdx.x;
  pc[t] = p1[t];
  pc[256 + t] = p2[t];
  __syncthreads();
  if (t < 32) {
    float sc = 0.f;
    for (int j = 0; j < 256; j++) sc += tmp[j * 32 + t] * pc[256 + j];
    float bl = 0.f;
    for (int k = 0; k < 512; k++) bl += tnWb[t * 512 + k] * pc[k];
    float v = sc + bl + tnb[t];
    ntn[t] = v > 0.f ? v : 0.f;
  }
  __syncthreads();
  if (t < 16) {
    float a = fc1b[t];
    for (int i = 0; i < 32; i++) a += ntn[i] * fc1W[i * 16 + t];
    sarr[t] = tanhf(a);
  }
  __syncthreads();
  if (t == 0) {
    float a = scb[0];
    for (int b = 0; b < 16; b++) a += sarr[b] * scW[b];
    float score = 1.f / (1.f + expf(-a));
    out[0] = score;
    out[1] = -logf(score) * avgv[0];
  }
}

// ---------------------------------------------------------------------------

extern "C" void kernel_launch(void* const* d_in, const int* in_sizes, int n_in,
                              void* d_out, int out_size, void* d_ws, size_t ws_size,
                              hipStream_t stream) {
  (void)in_sizes; (void)n_in; (void)out_size;
  const float* feat1 = (const float*)d_in[0];
  const float* feat2 = (const float*)d_in[1];
  const int* ei1 = (const int*)d_in[2];
  const int* ei2 = (const int*)d_in[3];
  const float* avgv = (const float*)d_in[4];
  const float* gcnW[3] = {(const float*)d_in[5], (const float*)d_in[8], (const float*)d_in[11]};
  const float* updW[3] = {(const float*)d_in[6], (const float*)d_in[9], (const float*)d_in[12]};
  const float* updb[3] = {(const float*)d_in[7], (const float*)d_in[10], (const float*)d_in[13]};
  const float* gatedW = (const float*)d_in[14];
  const float* gatedb = (const float*)d_in[15];
  const float* tnW = (const float*)d_in[16];
  const float* tnWb = (const float*)d_in[17];
  const float* tnb = (const float*)d_in[18];
  const float* fc1W = (const float*)d_in[19];
  const float* fc1b = (const float*)d_in[20];
  const float* scW = (const float*)d_in[21];
  const float* scb = (const float*)d_in[22];
  float* out = (float*)d_out;

  char* wp = (char*)d_ws;
  auto take = [&](size_t b) { char* p = wp; wp += (b + 255) & ~(size_t)255; return p; };
  float* simC = (float*)take((size_t)CHUNK * NN * 4);          // 32 MB (also cat1/cat2)
  float* fb1 = (float*)take((size_t)NN * 256 * 4);
  float* fb2 = (float*)take((size_t)NN * 256 * 4);
  unsigned short* f1b = (unsigned short*)take((size_t)NN * 256 * 2);
  unsigned short* f2b = (unsigned short*)take((size_t)NN * 256 * 2);
  unsigned short* f1bT = (unsigned short*)take((size_t)NN * 256 * 2);
  unsigned short* f2bT = (unsigned short*)take((size_t)NN * 256 * 2);
  float* h1 = (float*)take((size_t)NN * 256 * 4);   // h, then att1
  float* h2 = (float*)take((size_t)NN * 256 * 4);   // h, then att2
  float* c1 = (float*)take((size_t)NN * 256 * 4);   // gcn agg, then q (gated)
  float* c2 = (float*)take((size_t)NN * 256 * 4);
  unsigned short* WgT[3], *WuT[3];
  for (int l = 0; l < 3; l++) WgT[l] = (unsigned short*)take(256 * 256 * 2);
  for (int l = 0; l < 3; l++) WuT[l] = (unsigned short*)take(256 * 768 * 2);
  unsigned short* gWT = (unsigned short*)take(256 * 256 * 2);
  int* deg1 = (int*)take(NN * 4);
  int* deg2 = (int*)take(NN * 4);
  float* dinv1 = (float*)take(NN * 4);
  float* dinv2 = (float*)take(NN * 4);
  int* rs1 = (int*)take((NN + 1) * 4);
  int* rs2 = (int*)take((NN + 1) * 4);
  int* cur1 = (int*)take(NN * 4);
  int* cur2 = (int*)take(NN * 4);
  int* csr1 = (int*)take((size_t)EDG * 4);
  int* csr2 = (int*)take((size_t)EDG * 4);
  float* rm = (float*)take(NN * 4);
  float* rsi = (float*)take(NN * 4);
  float* cmx = (float*)take(NN * 4);
  float* csi = (float*)take(NN * 4);
  float* cpm = (float*)take((size_t)NSLICE * NN * 4);
  float* cps = (float*)take((size_t)NSLICE * NN * 4);
  float* p1 = (float*)take(1024);
  float* p2 = (float*)take(1024);
  float* tmp = (float*)take(NN * 4);
  // cat buffers overlap the (dead-by-then) sim chunk
  unsigned short* cat1 = (unsigned short*)simC;
  unsigned short* cat2 = cat1 + (size_t)NN * 768;

  size_t need = (size_t)(wp - (char*)d_ws);
  if (need > ws_size) {
    ws_sentinel<<<1, 1, 0, stream>>>(out);
    return;
  }

  // degree / dinv / CSR (edge structure is layer-invariant)
  hipMemsetAsync(deg1, 0, NN * 4, stream);
  hipMemsetAsync(deg2, 0, NN * 4, stream);
  deg_count<<<EDG / 256, 256, 0, stream>>>(ei1 + EDG, deg1);
  deg_count<<<EDG / 256, 256, 0, stream>>>(ei2 + EDG, deg2);
  make_dinv<<<NN / 256, 256, 0, stream>>>(deg1, dinv1);
  make_dinv<<<NN / 256, 256, 0, stream>>>(deg2, dinv2);
  scan_deg<<<1, 1024, 0, stream>>>(deg1, rs1);
  scan_deg<<<1, 1024, 0, stream>>>(deg2, rs2);
  hipMemcpyAsync(cur1, rs1, NN * 4, hipMemcpyDeviceToDevice, stream);
  hipMemcpyAsync(cur2, rs2, NN * 4, hipMemcpyDeviceToDevice, stream);
  csr_fill<<<EDG / 256, 256, 0, stream>>>(ei1, ei1 + EDG, cur1, csr1);
  csr_fill<<<EDG / 256, 256, 0, stream>>>(ei2, ei2 + EDG, cur2, csr2);

  // weights -> bf16 [out][in]
  for (int l = 0; l < 3; l++) {
    int din = (l == 0) ? 128 : 256;
    int W = 256 + 2 * din;
    transpose_bf16<<<dim3(8, din / 32), dim3(32, 8), 0, stream>>>(gcnW[l], WgT[l], din, 256);
    transpose_bf16<<<dim3(8, W / 32), dim3(32, 8), 0, stream>>>(updW[l], WuT[l], W, 256);
  }
  transpose_bf16<<<dim3(8, 8), dim3(32, 8), 0, stream>>>(gatedW, gWT, 256, 256);

  const float* f1 = feat1;
  const float* f2 = feat2;

  for (int l = 0; l < 3; l++) {
    const int din = (l == 0) ? 128 : 256;
    const int W = 256 + 2 * din;
    const int nel = NN * din;

    cvt_bf16<<<nel / 1024, 256, 0, stream>>>(f1, f1b, nel);
    cvt_bf16<<<nel / 1024, 256, 0, stream>>>(f2, f2b, nel);
    transpose_bf16<<<dim3(din / 32, NN / 32), dim3(32, 8), 0, stream>>>(f1, f1bT, NN, din);
    transpose_bf16<<<dim3(din / 32, NN / 32), dim3(32, 8), 0, stream>>>(f2, f2bT, NN, din);

    // h = f @ Wg
    gemm_k<0, 0><<<dim3(64, 2, 1), 256, 0, stream>>>(f1b, din, WgT[l], din, nullptr, nullptr, nullptr, nullptr, h1, 256, din);
    gemm_k<0, 0><<<dim3(64, 2, 1), 256, 0, stream>>>(f2b, din, WgT[l], din, nullptr, nullptr, nullptr, nullptr, h2, 256, din);

    // c = D^-1/2 (A+I) D^-1/2 h  — CSR gather, no atomics
    gcn_agg<<<NN / 4, 256, 0, stream>>>(rs1, csr1, dinv1, h1, c1);
    gcn_agg<<<NN / 4, 256, 0, stream>>>(rs2, csr2, dinv2, h2, c2);

    // att1 accumulator (h1 now free)
    hipMemsetAsync(h1, 0, (size_t)NN * din * 4, stream);

    // pass 1: per row-chunk of sim: sim -> row stats -> att1 rows; col partials
    for (int ci = 0; ci < NCHUNK; ci++) {
      const int r0 = ci * CHUNK;
      gemm_k<0, 0><<<dim3(CHUNK / 128, 64, 1), 256, 0, stream>>>(
          f1b + (size_t)r0 * din, din, f2b, din, nullptr, nullptr, nullptr, nullptr,
          simC, NN, din);
      row_stats<<<CHUNK, 256, 0, stream>>>(simC, rm + r0, rsi + r0);
      col_stats_part<<<dim3(32, CSLICE), 256, 0, stream>>>(
          simC, cpm + (size_t)ci * CSLICE * NN, cps + (size_t)ci * CSLICE * NN);
      gemm_k<1, 1><<<dim3(CHUNK / 128, din / 128, 8), 256, 0, stream>>>(
          nullptr, 0, f2bT, NN, simC, rm + r0, rsi + r0, nullptr,
          h1 + (size_t)r0 * din, din, NN / 8);
    }
    col_stats_merge<<<NN / 256, 256, 0, stream>>>(cpm, cps, cmx, csi);

    // pass 2: recompute sim chunk, accumulate att2
    hipMemsetAsync(h2, 0, (size_t)NN * din * 4, stream);
    for (int ci = 0; ci < NCHUNK; ci++) {
      const int r0 = ci * CHUNK;
      gemm_k<0, 0><<<dim3(CHUNK / 128, 64, 1), 256, 0, stream>>>(
          f1b + (size_t)r0 * din, din, f2b, din, nullptr, nullptr, nullptr, nullptr,
          simC, NN, din);
      gemm_k<2, 1><<<dim3(64, din / 128, 2), 256, 0, stream>>>(
          nullptr, 0, f1bT + r0, NN, simC, cmx, csi, nullptr,
          h2, din, CHUNK / 2);
    }

    // g = tanh?(concat([c, f, f-att]) @ Wu + bu)   (cat overlaps dead simC)
    build_cat<<<dim3(W / 256, NN), 256, 0, stream>>>(c1, f1, h1, cat1, din, W);
    build_cat<<<dim3(W / 256, NN), 256, 0, stream>>>(c2, f2, h2, cat2, din, W);
    if (l < 2) {
      gemm_k<0, 3><<<dim3(64, 2, 1), 256, 0, stream>>>(cat1, W, WuT[l], W, nullptr, nullptr, nullptr, updb[l], fb1, 256, W);
      gemm_k<0, 3><<<dim3(64, 2, 1), 256, 0, stream>>>(cat2, W, WuT[l], W, nullptr, nullptr, nullptr, updb[l], fb2, 256, W);
    } else {
      gemm_k<0, 2><<<dim3(64, 2, 1), 256, 0, stream>>>(cat1, W, WuT[l], W, nullptr, nullptr, nullptr, updb[l], fb1, 256, W);
      gemm_k<0, 2><<<dim3(64, 2, 1), 256, 0, stream>>>(cat2, W, WuT[l], W, nullptr, nullptr, nullptr, updb[l], fb2, 256, W);
    }
    f1 = fb1;
    f2 = fb2;
  }

  // gated readout
  cvt_bf16<<<NN * 256 / 1024, 256, 0, stream>>>(f1, f1b, NN * 256);
  cvt_bf16<<<NN * 256 / 1024, 256, 0, stream>>>(f2, f2b, NN * 256);
  gemm_k<0, 2><<<dim3(64, 2, 1), 256, 0, stream>>>(f1b, 256, gWT, 256, nullptr, nullptr, nullptr, gatedb, c1, 256, 256);
  gemm_k<0, 2><<<dim3(64, 2, 1), 256, 0, stream>>>(f2b, 256, gWT, 256, nullptr, nullptr, nullptr, gatedb, c2, 256, 256);
  hipMemsetAsync(p1, 0, 256 * 4, stream);
  hipMemsetAsync(p2, 0, 256 * 4, stream);
  gated_pool<<<64, 256, 0, stream>>>(c1, f1, p1);
  gated_pool<<<64, 256, 0, stream>>>(c2, f2, p2);

  // NTN + scoring head
  ntn_bilinear<<<32, 256, 0, stream>>>(p1, tnW, tmp);
  ntn_final<<<1, 256, 0, stream>>>(tmp, p1, p2, tnWb, tnb, fc1W, fc1b, scW, scb, avgv, out);
}

// Round 4
// 4013.339 us; speedup vs baseline: 1.7135x; 1.0775x over previous
//
#include <hip/hip_runtime.h>
#include <hip/hip_bf16.h>
#include <stdint.h>

#define NN 8192
#define EDG 131072
#define CHUNK 1024
#define NCHUNK 8
#define CSLICE 8            // col-stat row-slices per chunk

typedef __attribute__((ext_vector_type(8))) short bf16x8;
typedef __attribute__((ext_vector_type(4))) float f32x4;

__device__ __forceinline__ unsigned short f2bf(float f) {
  union { float f; unsigned u; } v; v.f = f;
  return (unsigned short)((v.u + 0x7fffu + ((v.u >> 16) & 1u)) >> 16);
}

__device__ __forceinline__ float bf2f(unsigned short u) {
  union { unsigned u; float f; } v; v.u = ((unsigned)u) << 16;
  return v.f;
}

__device__ __forceinline__ void load_lds16(const void* g, void* l) {
  __builtin_amdgcn_global_load_lds(
      (__attribute__((address_space(1))) void*)(uintptr_t)g,
      (__attribute__((address_space(3))) void*)(uintptr_t)l,
      16, 0, 0);
}

// ---------------------------------------------------------------------------
// C[M,N] (+)= A[M,K] * Bt[N,K]^T   (bf16 in, fp32 accum)
// grid = (M/128, N/128, zsplits), block = 256 (4 waves, 2x2 of 64x64)
// AMODE 0: A bf16 row-major (lda), via global_load_lds
// AMODE 1: A[i,k] = exp(bf16 simp[i*NN+k]-stm[i])*sts[i]   (row softmax)
// AMODE 2: A[j,k] = exp(bf16 simp[k*NN+j]-stm[j])*(sts?:1) (col softmax, transposed)
// EPI 0: fp32 store; 1: atomicAdd; 2: +bias store; 3: tanh(+bias) store; 4: bf16 store
// ---------------------------------------------------------------------------
template <int AMODE, int EPI>
__global__ __launch_bounds__(256) void gemm_k(
    const unsigned short* __restrict__ A, int lda,
    const unsigned short* __restrict__ Bt, int ldb,
    const unsigned short* __restrict__ simp, const float* __restrict__ stm,
    const float* __restrict__ sts, const float* __restrict__ bias,
    float* __restrict__ C, int ldc, int kPerSplit) {
  __shared__ alignas(16) unsigned short As[128 * 32];
  __shared__ alignas(16) unsigned short Bs[128 * 32];
  const int t = threadIdx.x;
  const int wave = t >> 6, lane = t & 63;
  const int wm = (wave >> 1) * 64, wn = (wave & 1) * 64;
  const int lrow = lane & 15, quad = lane >> 4;
  const int rowBase = blockIdx.x * 128;
  const int colBase = blockIdx.y * 128;
  const int k0 = blockIdx.z * kPerSplit;
  const int k1 = k0 + kPerSplit;

  f32x4 acc[4][4];
#pragma unroll
  for (int i = 0; i < 4; i++)
#pragma unroll
    for (int j = 0; j < 4; j++) acc[i][j] = f32x4{0.f, 0.f, 0.f, 0.f};

  const int sr = t >> 2;   // 0..63 staging row
  const int sch = t & 3;   // 16B chunk in 64B row

  float aM[2], aS[2];
  if (AMODE == 1) {
#pragma unroll
    for (int it = 0; it < 2; it++) {
      int r = (t >> 2) + it * 64;
      aM[it] = stm[rowBase + r];
      aS[it] = sts[rowBase + r];
    }
  }
  const int jl = t & 127, kg = t >> 7;
  float cM = 0.f, cS = 1.f;
  if (AMODE == 2) { cM = stm[rowBase + jl]; cS = sts ? sts[rowBase + jl] : 1.0f; }

  for (int kb = k0; kb < k1; kb += 32) {
    __syncthreads();
    { // B staging: 128x32, two wave-uniform-base async 16B loads
      const unsigned short* bsrc = Bt + (size_t)(colBase + sr) * ldb + kb + sch * 8;
      load_lds16(bsrc, (char*)Bs + t * 16);
      load_lds16(bsrc + (size_t)64 * ldb, (char*)Bs + t * 16 + 4096);
    }
    if (AMODE == 0) {
      const unsigned short* asrc = A + (size_t)(rowBase + sr) * lda + kb + sch * 8;
      load_lds16(asrc, (char*)As + t * 16);
      load_lds16(asrc + (size_t)64 * lda, (char*)As + t * 16 + 4096);
    } else if (AMODE == 1) {
#pragma unroll
      for (int it = 0; it < 2; it++) {
        const int r = (t >> 2) + it * 64;
        const int c8 = (t & 3) * 8;
        uint4 raw = *(const uint4*)(simp + (size_t)(rowBase + r) * NN + kb + c8);
        unsigned short u[8];
        u[0] = raw.x & 0xffffu; u[1] = raw.x >> 16;
        u[2] = raw.y & 0xffffu; u[3] = raw.y >> 16;
        u[4] = raw.z & 0xffffu; u[5] = raw.z >> 16;
        u[6] = raw.w & 0xffffu; u[7] = raw.w >> 16;
        unsigned o[4];
#pragma unroll
        for (int q = 0; q < 4; q++) {
          unsigned b0 = f2bf(__expf(bf2f(u[2 * q]) - aM[it]) * aS[it]);
          unsigned b1 = f2bf(__expf(bf2f(u[2 * q + 1]) - aM[it]) * aS[it]);
          o[q] = b0 | (b1 << 16);
        }
        uint4 w; w.x = o[0]; w.y = o[1]; w.z = o[2]; w.w = o[3];
        *(uint4*)&As[r * 32 + c8] = w;   // byte addr = t*16 + it*4096: conflict-free
      }
    } else if (AMODE == 2) {
      unsigned pk[8];
#pragma unroll
      for (int q = 0; q < 8; q++) pk[q] = 0u;
#pragma unroll
      for (int kk = 0; kk < 16; kk++) {
        const int k = kg * 16 + kk;
        float x = bf2f(simp[(size_t)(kb + k) * NN + rowBase + jl]);
        unsigned b = f2bf(__expf(x - cM) * cS);
        pk[kk >> 1] |= b << ((kk & 1) * 16);
      }
      unsigned short* dst = &As[jl * 32 + kg * 16];
      uint4 w0; w0.x = pk[0]; w0.y = pk[1]; w0.z = pk[2]; w0.w = pk[3];
      uint4 w1; w1.x = pk[4]; w1.y = pk[5]; w1.z = pk[6]; w1.w = pk[7];
      *(uint4*)dst = w0;
      *(uint4*)(dst + 8) = w1;
    }
    __syncthreads();

    bf16x8 af[4], bfr[4];
#pragma unroll
    for (int i = 0; i < 4; i++)
      af[i] = *(const bf16x8*)&As[(wm + i * 16 + lrow) * 32 + quad * 8];
#pragma unroll
    for (int j = 0; j < 4; j++)
      bfr[j] = *(const bf16x8*)&Bs[(wn + j * 16 + lrow) * 32 + quad * 8];
#pragma unroll
    for (int i = 0; i < 4; i++)
#pragma unroll
      for (int j = 0; j < 4; j++)
        acc[i][j] = __builtin_amdgcn_mfma_f32_16x16x32_bf16(af[i], bfr[j], acc[i][j], 0, 0, 0);
  }

#pragma unroll
  for (int i = 0; i < 4; i++) {
    int row = rowBase + wm + i * 16 + quad * 4;
#pragma unroll
    for (int j = 0; j < 4; j++) {
      int col = colBase + wn + j * 16 + lrow;
#pragma unroll
      for (int r = 0; r < 4; r++) {
        float v = acc[i][j][r];
        size_t idx = (size_t)(row + r) * ldc + col;
        if (EPI == 0) C[idx] = v;
        else if (EPI == 1) atomicAdd(&C[idx], v);
        else if (EPI == 4) ((unsigned short*)C)[idx] = f2bf(v);
        else {
          v += bias[col];
          if (EPI == 3) v = tanhf(v);
          C[idx] = v;
        }
      }
    }
  }
}

// --------------------------- small kernels ---------------------------------

__global__ void ws_sentinel(float* out) { out[0] = 12345.0f; out[1] = 12345.0f; }

__global__ void cvt_bf16(const float* __restrict__ in, unsigned short* __restrict__ out, int n) {
  int i = (blockIdx.x * 256 + threadIdx.x) * 4;
  if (i < n) {
    f32x4 v = *(const f32x4*)(in + i);
    uint2 p;
    p.x = f2bf(v.x) | ((unsigned)f2bf(v.y) << 16);
    p.y = f2bf(v.z) | ((unsigned)f2bf(v.w) << 16);
    *(uint2*)(out + i) = p;
  }
}

// dst[C][R] = bf16(src[R][C])
__global__ void transpose_bf16(const float* __restrict__ src, unsigned short* __restrict__ dst,
                               int R, int C) {
  __shared__ float tile[32][33];
  int c0 = blockIdx.x * 32, r0 = blockIdx.y * 32;
  int x = threadIdx.x, y = threadIdx.y;
  for (int i = y; i < 32; i += 8) tile[i][x] = src[(size_t)(r0 + i) * C + c0 + x];
  __syncthreads();
  for (int i = y; i < 32; i += 8) dst[(size_t)(c0 + i) * R + r0 + x] = f2bf(tile[x][i]);
}

__global__ void deg_count(const int* __restrict__ dst, int* __restrict__ deg) {
  int e = blockIdx.x * 256 + threadIdx.x;
  atomicAdd(&deg[dst[e]], 1);
}

__global__ void make_dinv(const int* __restrict__ deg, float* __restrict__ dinv) {
  int v = blockIdx.x * 256 + threadIdx.x;
  dinv[v] = rsqrtf((float)(deg[v] + 1));  // +1 self-loop
}

// exclusive prefix sum of deg[8192] -> rowstart[8193]; single block of 1024
__global__ void scan_deg(const int* __restrict__ deg, int* __restrict__ rowstart) {
  __shared__ int part[1024];
  int t = threadIdx.x;
  int base = t * 8;
  int local[8];
  int s = 0;
#pragma unroll
  for (int i = 0; i < 8; i++) { local[i] = s; s += deg[base + i]; }
  part[t] = s;
  __syncthreads();
  for (int off = 1; off < 1024; off <<= 1) {
    int v = (t >= off) ? part[t - off] : 0;
    __syncthreads();
    part[t] += v;
    __syncthreads();
  }
  int offset = (t == 0) ? 0 : part[t - 1];
#pragma unroll
  for (int i = 0; i < 8; i++) rowstart[base + i] = offset + local[i];
  if (t == 1023) rowstart[8192] = offset + s;
}

__global__ void csr_fill(const int* __restrict__ src, const int* __restrict__ dst,
                         int* __restrict__ cursor, int* __restrict__ csr_src) {
  int e = blockIdx.x * 256 + threadIdx.x;
  int pos = atomicAdd(&cursor[dst[e]], 1);
  csr_src[pos] = src[e];
}

// c[v] = dinv[v]^2*h[v] + sum_in dinv[s]*dinv[v]*h[s]; one wave per node
__global__ __launch_bounds__(256) void gcn_agg(
    const int* __restrict__ rowstart, const int* __restrict__ csr_src,
    const float* __restrict__ dinv, const float* __restrict__ h,
    float* __restrict__ c) {
  int node = blockIdx.x * 4 + (threadIdx.x >> 6);
  int lane = threadIdx.x & 63;
  float dn = dinv[node];
  f32x4 acc = *(const f32x4*)(h + (size_t)node * 256 + lane * 4);
  float w0 = dn * dn;
  acc.x *= w0; acc.y *= w0; acc.z *= w0; acc.w *= w0;
  int s0 = rowstart[node], s1 = rowstart[node + 1];
  for (int j = s0; j < s1; j++) {
    int s = csr_src[j];
    float w = dinv[s] * dn;
    f32x4 v = *(const f32x4*)(h + (size_t)s * 256 + lane * 4);
    acc.x += w * v.x; acc.y += w * v.y; acc.z += w * v.z; acc.w += w * v.w;
  }
  *(f32x4*)(c + (size_t)node * 256 + lane * 4) = acc;
}

// row softmax stats over bf16 sim chunk: one block per row
__global__ void row_stats(const unsigned short* __restrict__ simc, float* __restrict__ rm,
                          float* __restrict__ rsi) {
  int row = blockIdx.x;
  const unsigned short* p = simc + (size_t)row * NN;
  int t = threadIdx.x;
  float m = -3.0e38f, s = 0.f;
  for (int j = t; j < NN; j += 256) {
    float x = bf2f(p[j]);
    if (x > m) { s = s * __expf(m - x) + 1.f; m = x; }
    else s += __expf(x - m);
  }
  __shared__ float sm[256], ss[256];
  sm[t] = m; ss[t] = s;
  __syncthreads();
  for (int off = 128; off > 0; off >>= 1) {
    if (t < off) {
      float m2 = sm[t + off], s2 = ss[t + off];
      float M = fmaxf(sm[t], m2);
      ss[t] = ss[t] * __expf(sm[t] - M) + s2 * __expf(m2 - M);
      sm[t] = M;
    }
    __syncthreads();
  }
  if (t == 0) { rm[row] = sm[0]; rsi[row] = 1.f / ss[0]; }
}

// per-chunk col partial stats: grid (32, CSLICE); slice = CHUNK/CSLICE rows
__global__ void col_stats_part(const unsigned short* __restrict__ simc, float* __restrict__ pm,
                               float* __restrict__ ps) {
  int col = blockIdx.x * 256 + threadIdx.x;
  int rs = blockIdx.y;
  float m = -3.0e38f, s = 0.f;
  for (int i = rs * (CHUNK / CSLICE); i < (rs + 1) * (CHUNK / CSLICE); i++) {
    float x = bf2f(simc[(size_t)i * NN + col]);
    if (x > m) { s = s * __expf(m - x) + 1.f; m = x; }
    else s += __expf(x - m);
  }
  pm[(size_t)rs * NN + col] = m;
  ps[(size_t)rs * NN + col] = s;
}

// merge chunk slices into per-chunk (m,s), fold into running (M,S), emit alpha
__global__ void col_chunk_merge(const float* __restrict__ pm, const float* __restrict__ ps,
                                float* __restrict__ Mrun, float* __restrict__ Srun,
                                float* __restrict__ alpha) {
  int col = blockIdx.x * 256 + threadIdx.x;
  float m = -3.0e38f, s = 0.f;
  for (int rs = 0; rs < CSLICE; rs++) {
    float m2 = pm[(size_t)rs * NN + col], s2 = ps[(size_t)rs * NN + col];
    float M = fmaxf(m, m2);
    s = s * __expf(m - M) + s2 * __expf(m2 - M);
    m = M;
  }
  float Mo = Mrun[col], So = Srun[col];
  float Mn = fmaxf(Mo, m);
  float a = __expf(Mo - Mn);
  Srun[col] = So * a + s * __expf(m - Mn);
  Mrun[col] = Mn;
  alpha[col] = a;
}

__global__ void init_colstats(float* __restrict__ M, float* __restrict__ S) {
  int c = blockIdx.x * 256 + threadIdx.x;
  M[c] = -3.0e38f;
  S[c] = 0.f;
}

// att2[j,:] *= alpha[j]; dshift = log2(din)
__global__ void scale_att2(float* __restrict__ att2, const float* __restrict__ alpha,
                           int dshift) {
  size_t e = ((size_t)blockIdx.x * 256 + threadIdx.x) * 4;
  int j = (int)(e >> dshift);
  float a = alpha[j];
  f32x4 v = *(const f32x4*)(att2 + e);
  v.x *= a; v.y *= a; v.z *= a; v.w *= a;
  *(f32x4*)(att2 + e) = v;
}

// cat[i][:] = bf16([ c[i](256) | f[i](din) | f[i]-att[i]/Sdiv[i](din) ])
__global__ void build_cat(const float* __restrict__ cbuf, const float* __restrict__ f,
                          const float* __restrict__ att, const float* __restrict__ Sdiv,
                          unsigned short* __restrict__ cat, int din, int W) {
  int i = blockIdx.y;
  int c = blockIdx.x * 256 + threadIdx.x;
  float v;
  if (c < 256) v = cbuf[(size_t)i * 256 + c];
  else if (c < 256 + din) v = f[(size_t)i * din + (c - 256)];
  else {
    float a = att[(size_t)i * din + (c - 256 - din)];
    if (Sdiv) a /= Sdiv[i];
    v = f[(size_t)i * din + (c - 256 - din)] - a;
  }
  cat[(size_t)i * W + c] = f2bf(v);
}

__global__ void gated_pool(const float* __restrict__ q, const float* __restrict__ f,
                           float* __restrict__ p) {
  int col = threadIdx.x;
  int r0 = blockIdx.x * 128;
  float a = 0.f;
  for (int i = r0; i < r0 + 128; i++) {
    float qv = q[(size_t)i * 256 + col];
    a += f[(size_t)i * 256 + col] / (1.f + __expf(-qv));
  }
  atomicAdd(&p[col], a);
}

__global__ void ntn_bilinear(const float* __restrict__ p1, const float* __restrict__ tnW,
                             float* __restrict__ tmp) {
  int c = blockIdx.x * 256 + threadIdx.x;
  float a = 0.f;
#pragma unroll 8
  for (int i = 0; i < 256; i++) a += p1[i] * tnW[(size_t)i * 8192 + c];
  tmp[c] = a;
}

__global__ void ntn_final(const float* __restrict__ tmp, const float* __restrict__ p1,
                          const float* __restrict__ p2, const float* __restrict__ tnWb,
                          const float* __restrict__ tnb, const float* __restrict__ fc1W,
                          const float* __restrict__ fc1b, const float* __restrict__ scW,
                          const float* __restrict__ scb, const float* __restrict__ avgv,
                          float* __restrict__ out) {
  __shared__ float pc[512];
  __shared__ float ntn[32];
  __shared__ float sarr[16];
  int t = threadIdx.x;
  pc[t] = p1[t];
  pc[256 + t] = p2[t];
  __syncthreads();
  if (t < 32) {
    float sc = 0.f;
    for (int j = 0; j < 256; j++) sc += tmp[j * 32 + t] * pc[256 + j];
    float bl = 0.f;
    for (int k = 0; k < 512; k++) bl += tnWb[t * 512 + k] * pc[k];
    float v = sc + bl + tnb[t];
    ntn[t] = v > 0.f ? v : 0.f;
  }
  __syncthreads();
  if (t < 16) {
    float a = fc1b[t];
    for (int i = 0; i < 32; i++) a += ntn[i] * fc1W[i * 16 + t];
    sarr[t] = tanhf(a);
  }
  __syncthreads();
  if (t == 0) {
    float a = scb[0];
    for (int b = 0; b < 16; b++) a += sarr[b] * scW[b];
    float score = 1.f / (1.f + expf(-a));
    out[0] = score;
    out[1] = -logf(score) * avgv[0];
  }
}

// ---------------------------------------------------------------------------

extern "C" void kernel_launch(void* const* d_in, const int* in_sizes, int n_in,
                              void* d_out, int out_size, void* d_ws, size_t ws_size,
                              hipStream_t stream) {
  (void)in_sizes; (void)n_in; (void)out_size;
  const float* feat1 = (const float*)d_in[0];
  const float* feat2 = (const float*)d_in[1];
  const int* ei1 = (const int*)d_in[2];
  const int* ei2 = (const int*)d_in[3];
  const float* avgv = (const float*)d_in[4];
  const float* gcnW[3] = {(const float*)d_in[5], (const float*)d_in[8], (const float*)d_in[11]};
  const float* updW[3] = {(const float*)d_in[6], (const float*)d_in[9], (const float*)d_in[12]};
  const float* updb[3] = {(const float*)d_in[7], (const float*)d_in[10], (const float*)d_in[13]};
  const float* gatedW = (const float*)d_in[14];
  const float* gatedb = (const float*)d_in[15];
  const float* tnW = (const float*)d_in[16];
  const float* tnWb = (const float*)d_in[17];
  const float* tnb = (const float*)d_in[18];
  const float* fc1W = (const float*)d_in[19];
  const float* fc1b = (const float*)d_in[20];
  const float* scW = (const float*)d_in[21];
  const float* scb = (const float*)d_in[22];
  float* out = (float*)d_out;

  char* wp = (char*)d_ws;
  auto take = [&](size_t b) { char* p = wp; wp += (b + 255) & ~(size_t)255; return p; };
  // 32 MB region: bf16 sim chunk (16 MB) early, cat1+cat2 (25 MB) late
  unsigned short* simC = (unsigned short*)take((size_t)CHUNK * NN * 4);
  float* fb1 = (float*)take((size_t)NN * 256 * 4);
  float* fb2 = (float*)take((size_t)NN * 256 * 4);
  unsigned short* f1b = (unsigned short*)take((size_t)NN * 256 * 2);
  unsigned short* f2b = (unsigned short*)take((size_t)NN * 256 * 2);
  unsigned short* f1bT = (unsigned short*)take((size_t)NN * 256 * 2);
  unsigned short* f2bT = (unsigned short*)take((size_t)NN * 256 * 2);
  float* h1 = (float*)take((size_t)NN * 256 * 4);   // h, then att1
  float* h2 = (float*)take((size_t)NN * 256 * 4);   // h, then att2
  float* c1 = (float*)take((size_t)NN * 256 * 4);   // gcn agg, then q (gated)
  float* c2 = (float*)take((size_t)NN * 256 * 4);
  unsigned short* WgT[3], *WuT[3];
  for (int l = 0; l < 3; l++) WgT[l] = (unsigned short*)take(256 * 256 * 2);
  for (int l = 0; l < 3; l++) WuT[l] = (unsigned short*)take(256 * 768 * 2);
  unsigned short* gWT = (unsigned short*)take(256 * 256 * 2);
  int* deg1 = (int*)take(NN * 4);
  int* deg2 = (int*)take(NN * 4);
  float* dinv1 = (float*)take(NN * 4);
  float* dinv2 = (float*)take(NN * 4);
  int* rs1 = (int*)take((NN + 1) * 4);
  int* rs2 = (int*)take((NN + 1) * 4);
  int* cur1 = (int*)take(NN * 4);
  int* cur2 = (int*)take(NN * 4);
  int* csr1 = (int*)take((size_t)EDG * 4);
  int* csr2 = (int*)take((size_t)EDG * 4);
  float* rm = (float*)take(NN * 4);
  float* rsi = (float*)take(NN * 4);
  float* Mrun = (float*)take(NN * 4);
  float* Srun = (float*)take(NN * 4);
  float* alpha = (float*)take(NN * 4);
  float* cpm = (float*)take((size_t)CSLICE * NN * 4);
  float* cps = (float*)take((size_t)CSLICE * NN * 4);
  float* p1 = (float*)take(1024);
  float* p2 = (float*)take(1024);
  float* tmp = (float*)take(NN * 4);
  unsigned short* cat1 = (unsigned short*)simC;
  unsigned short* cat2 = cat1 + (size_t)NN * 768;

  size_t need = (size_t)(wp - (char*)d_ws);
  if (need > ws_size) {
    ws_sentinel<<<1, 1, 0, stream>>>(out);
    return;
  }

  // degree / dinv / CSR (edge structure is layer-invariant)
  hipMemsetAsync(deg1, 0, NN * 4, stream);
  hipMemsetAsync(deg2, 0, NN * 4, stream);
  deg_count<<<EDG / 256, 256, 0, stream>>>(ei1 + EDG, deg1);
  deg_count<<<EDG / 256, 256, 0, stream>>>(ei2 + EDG, deg2);
  make_dinv<<<NN / 256, 256, 0, stream>>>(deg1, dinv1);
  make_dinv<<<NN / 256, 256, 0, stream>>>(deg2, dinv2);
  scan_deg<<<1, 1024, 0, stream>>>(deg1, rs1);
  scan_deg<<<1, 1024, 0, stream>>>(deg2, rs2);
  hipMemcpyAsync(cur1, rs1, NN * 4, hipMemcpyDeviceToDevice, stream);
  hipMemcpyAsync(cur2, rs2, NN * 4, hipMemcpyDeviceToDevice, stream);
  csr_fill<<<EDG / 256, 256, 0, stream>>>(ei1, ei1 + EDG, cur1, csr1);
  csr_fill<<<EDG / 256, 256, 0, stream>>>(ei2, ei2 + EDG, cur2, csr2);

  // weights -> bf16 [out][in]
  for (int l = 0; l < 3; l++) {
    int din = (l == 0) ? 128 : 256;
    int W = 256 + 2 * din;
    transpose_bf16<<<dim3(8, din / 32), dim3(32, 8), 0, stream>>>(gcnW[l], WgT[l], din, 256);
    transpose_bf16<<<dim3(8, W / 32), dim3(32, 8), 0, stream>>>(updW[l], WuT[l], W, 256);
  }
  transpose_bf16<<<dim3(8, 8), dim3(32, 8), 0, stream>>>(gatedW, gWT, 256, 256);

  const float* f1 = feat1;
  const float* f2 = feat2;

  for (int l = 0; l < 3; l++) {
    const int din = (l == 0) ? 128 : 256;
    const int dshift = (l == 0) ? 7 : 8;
    const int W = 256 + 2 * din;
    const int nel = NN * din;

    cvt_bf16<<<nel / 1024, 256, 0, stream>>>(f1, f1b, nel);
    cvt_bf16<<<nel / 1024, 256, 0, stream>>>(f2, f2b, nel);
    transpose_bf16<<<dim3(din / 32, NN / 32), dim3(32, 8), 0, stream>>>(f1, f1bT, NN, din);
    transpose_bf16<<<dim3(din / 32, NN / 32), dim3(32, 8), 0, stream>>>(f2, f2bT, NN, din);

    // h = f @ Wg
    gemm_k<0, 0><<<dim3(64, 2, 1), 256, 0, stream>>>(f1b, din, WgT[l], din, nullptr, nullptr, nullptr, nullptr, h1, 256, din);
    gemm_k<0, 0><<<dim3(64, 2, 1), 256, 0, stream>>>(f2b, din, WgT[l], din, nullptr, nullptr, nullptr, nullptr, h2, 256, din);

    // c = D^-1/2 (A+I) D^-1/2 h — CSR gather, no atomics
    gcn_agg<<<NN / 4, 256, 0, stream>>>(rs1, csr1, dinv1, h1, c1);
    gcn_agg<<<NN / 4, 256, 0, stream>>>(rs2, csr2, dinv2, h2, c2);

    // attention accumulators
    hipMemsetAsync(h1, 0, (size_t)NN * din * 4, stream);   // att1
    hipMemsetAsync(h2, 0, (size_t)NN * din * 4, stream);   // att2 (online)
    init_colstats<<<NN / 256, 256, 0, stream>>>(Mrun, Srun);

    // single pass over row-chunks: sim(bf16) -> row softmax/att1; online col softmax/att2
    for (int ci = 0; ci < NCHUNK; ci++) {
      const int r0 = ci * CHUNK;
      gemm_k<0, 4><<<dim3(CHUNK / 128, 64, 1), 256, 0, stream>>>(
          f1b + (size_t)r0 * din, din, f2b, din, nullptr, nullptr, nullptr, nullptr,
          (float*)simC, NN, din);
      row_stats<<<CHUNK, 256, 0, stream>>>(simC, rm + r0, rsi + r0);
      gemm_k<1, 1><<<dim3(CHUNK / 128, din / 128, 16), 256, 0, stream>>>(
          nullptr, 0, f2bT, NN, simC, rm + r0, rsi + r0, nullptr,
          h1 + (size_t)r0 * din, din, NN / 16);
      col_stats_part<<<dim3(NN / 256, CSLICE), 256, 0, stream>>>(simC, cpm, cps);
      col_chunk_merge<<<NN / 256, 256, 0, stream>>>(cpm, cps, Mrun, Srun, alpha);
      scale_att2<<<(NN * din / 4) / 256, 256, 0, stream>>>(h2, alpha, dshift);
      gemm_k<2, 1><<<dim3(64, din / 128, 2), 256, 0, stream>>>(
          nullptr, 0, f1bT + r0, NN, simC, Mrun, nullptr, nullptr,
          h2, din, CHUNK / 2);
    }

    // g = tanh?(concat([c, f, f-att]) @ Wu + bu)  (cat overlaps dead simC)
    build_cat<<<dim3(W / 256, NN), 256, 0, stream>>>(c1, f1, h1, nullptr, cat1, din, W);
    build_cat<<<dim3(W / 256, NN), 256, 0, stream>>>(c2, f2, h2, Srun, cat2, din, W);
    if (l < 2) {
      gemm_k<0, 3><<<dim3(64, 2, 1), 256, 0, stream>>>(cat1, W, WuT[l], W, nullptr, nullptr, nullptr, updb[l], fb1, 256, W);
      gemm_k<0, 3><<<dim3(64, 2, 1), 256, 0, stream>>>(cat2, W, WuT[l], W, nullptr, nullptr, nullptr, updb[l], fb2, 256, W);
    } else {
      gemm_k<0, 2><<<dim3(64, 2, 1), 256, 0, stream>>>(cat1, W, WuT[l], W, nullptr, nullptr, nullptr, updb[l], fb1, 256, W);
      gemm_k<0, 2><<<dim3(64, 2, 1), 256, 0, stream>>>(cat2, W, WuT[l], W, nullptr, nullptr, nullptr, updb[l], fb2, 256, W);
    }
    f1 = fb1;
    f2 = fb2;
  }

  // gated readout
  cvt_bf16<<<NN * 256 / 1024, 256, 0, stream>>>(f1, f1b, NN * 256);
  cvt_bf16<<<NN * 256 / 1024, 256, 0, stream>>>(f2, f2b, NN * 256);
  gemm_k<0, 2><<<dim3(64, 2, 1), 256, 0, stream>>>(f1b, 256, gWT, 256, nullptr, nullptr, nullptr, gatedb, c1, 256, 256);
  gemm_k<0, 2><<<dim3(64, 2, 1), 256, 0, stream>>>(f2b, 256, gWT, 256, nullptr, nullptr, nullptr, gatedb, c2, 256, 256);
  hipMemsetAsync(p1, 0, 256 * 4, stream);
  hipMemsetAsync(p2, 0, 256 * 4, stream);
  gated_pool<<<64, 256, 0, stream>>>(c1, f1, p1);
  gated_pool<<<64, 256, 0, stream>>>(c2, f2, p2);

  // NTN + scoring head
  ntn_bilinear<<<32, 256, 0, stream>>>(p1, tnW, tmp);
  ntn_final<<<1, 256, 0, stream>>>(tmp, p1, p2, tnWb, tnb, fc1W, fc1b, scW, scb, avgv, out);
}

// Round 5
// 1714.581 us; speedup vs baseline: 4.0108x; 2.3407x over previous
//
#include <hip/hip_runtime.h>
#include <hip/hip_bf16.h>
#include <stdint.h>

#define NN 8192
#define EDG 131072
#define NSPLIT 4

typedef __attribute__((ext_vector_type(8))) short bf16x8;
typedef __attribute__((ext_vector_type(4))) float f32x4;

__device__ __forceinline__ unsigned short f2bf(float f) {
  union { float f; unsigned u; } v; v.f = f;
  return (unsigned short)((v.u + 0x7fffu + ((v.u >> 16) & 1u)) >> 16);
}

__device__ __forceinline__ float bf2f(unsigned short u) {
  union { unsigned u; float f; } v; v.u = ((unsigned)u) << 16;
  return v.f;
}

__device__ __forceinline__ void load_lds16(const void* g, void* l) {
  __builtin_amdgcn_global_load_lds(
      (__attribute__((address_space(1))) void*)(uintptr_t)g,
      (__attribute__((address_space(3))) void*)(uintptr_t)l,
      16, 0, 0);
}

// ---------------------------------------------------------------------------
// C[M,N] = A[M,K] * Bt[N,K]^T (+bias, +tanh)   bf16 in, fp32 accum
// grid=(M/128, N/128), block=256 (4 waves, 2x2 of 64x64)
// EPI 0: store; 2: +bias[col]; 3: tanh(+bias[col])
// ---------------------------------------------------------------------------
template <int EPI>
__global__ __launch_bounds__(256) void gemm_k(
    const unsigned short* __restrict__ A, int lda,
    const unsigned short* __restrict__ Bt, int ldb,
    const float* __restrict__ bias, float* __restrict__ C, int ldc, int K) {
  __shared__ alignas(16) unsigned short As[128 * 32];
  __shared__ alignas(16) unsigned short Bs[128 * 32];
  const int t = threadIdx.x;
  const int wave = t >> 6, lane = t & 63;
  const int wm = (wave >> 1) * 64, wn = (wave & 1) * 64;
  const int lrow = lane & 15, quad = lane >> 4;
  const int rowBase = blockIdx.x * 128;
  const int colBase = blockIdx.y * 128;

  f32x4 acc[4][4];
#pragma unroll
  for (int i = 0; i < 4; i++)
#pragma unroll
    for (int j = 0; j < 4; j++) acc[i][j] = f32x4{0.f, 0.f, 0.f, 0.f};

  const int sr = t >> 2, sch = t & 3;

  for (int kb = 0; kb < K; kb += 32) {
    __syncthreads();
    const unsigned short* bsrc = Bt + (size_t)(colBase + sr) * ldb + kb + sch * 8;
    load_lds16(bsrc, (char*)Bs + t * 16);
    load_lds16(bsrc + (size_t)64 * ldb, (char*)Bs + t * 16 + 4096);
    const unsigned short* asrc = A + (size_t)(rowBase + sr) * lda + kb + sch * 8;
    load_lds16(asrc, (char*)As + t * 16);
    load_lds16(asrc + (size_t)64 * lda, (char*)As + t * 16 + 4096);
    __syncthreads();

    bf16x8 af[4], bfr[4];
#pragma unroll
    for (int i = 0; i < 4; i++)
      af[i] = *(const bf16x8*)&As[(wm + i * 16 + lrow) * 32 + quad * 8];
#pragma unroll
    for (int j = 0; j < 4; j++)
      bfr[j] = *(const bf16x8*)&Bs[(wn + j * 16 + lrow) * 32 + quad * 8];
#pragma unroll
    for (int i = 0; i < 4; i++)
#pragma unroll
      for (int j = 0; j < 4; j++)
        acc[i][j] = __builtin_amdgcn_mfma_f32_16x16x32_bf16(af[i], bfr[j], acc[i][j], 0, 0, 0);
  }

#pragma unroll
  for (int i = 0; i < 4; i++) {
    int row = rowBase + wm + i * 16 + quad * 4;
#pragma unroll
    for (int j = 0; j < 4; j++) {
      int col = colBase + wn + j * 16 + lrow;
#pragma unroll
      for (int r = 0; r < 4; r++) {
        float v = acc[i][j][r];
        size_t idx = (size_t)(row + r) * ldc + col;
        if (EPI == 0) C[idx] = v;
        else {
          v += bias[col];
          if (EPI == 3) v = tanhf(v);
          C[idx] = v;
        }
      }
    }
  }
}

// ---------------------------------------------------------------------------
// Flash attention: O = softmax_row(Q @ K^T) @ V, online softmax over kv-splits.
// Q[NN][DIN], K[NN][DIN] bf16 row-major; Vt[DIN][NN] bf16 (V transposed).
// grid=(NN/128, NSPLIT), block=256. Writes un-normalized O partial (bf16),
// plus per-row m (max) and l (sum) per split. Merge kernel combines splits.
// ---------------------------------------------------------------------------
template <int DIN>
__global__ __launch_bounds__(256, 1) void flash_att(
    const unsigned short* __restrict__ Q, const unsigned short* __restrict__ K,
    const unsigned short* __restrict__ Vt, unsigned short* __restrict__ Opart,
    float* __restrict__ mpart, float* __restrict__ lpart, int kvPerSplit) {
  constexpr int NH = DIN / 128;
  __shared__ alignas(16) unsigned short As[128 * 32];
  __shared__ alignas(16) unsigned short Bs[128 * 32];
  __shared__ alignas(16) unsigned short Ps[128 * 136];   // pad 136: conflict-light
  __shared__ float redM[2][128];
  __shared__ float redL[2][128];
  const int t = threadIdx.x;
  const int wave = t >> 6, lane = t & 63;
  const int wm = (wave >> 1) * 64, wn = (wave & 1) * 64;
  const int lrow = lane & 15, quad = lane >> 4;
  const int rowBase = blockIdx.x * 128;
  const int split = blockIdx.y;
  const int kv0 = split * kvPerSplit;
  const int sr = t >> 2, sch = t & 3;

  float m_i[16], l_i[16];           // index x = i*4 + r; row = wm+i*16+quad*4+r
#pragma unroll
  for (int x = 0; x < 16; x++) { m_i[x] = -3.0e38f; l_i[x] = 0.f; }
  f32x4 accO[NH][4][4];
#pragma unroll
  for (int h = 0; h < NH; h++)
#pragma unroll
    for (int i = 0; i < 4; i++)
#pragma unroll
      for (int j = 0; j < 4; j++) accO[h][i][j] = f32x4{0.f, 0.f, 0.f, 0.f};

  for (int kt = kv0; kt < kv0 + kvPerSplit; kt += 128) {
    // ---- Phase 1: S = Q_tile @ K_tile^T ----
    f32x4 accS[4][4];
#pragma unroll
    for (int i = 0; i < 4; i++)
#pragma unroll
      for (int j = 0; j < 4; j++) accS[i][j] = f32x4{0.f, 0.f, 0.f, 0.f};
    for (int kb = 0; kb < DIN; kb += 32) {
      __syncthreads();
      const unsigned short* qsrc = Q + (size_t)(rowBase + sr) * DIN + kb + sch * 8;
      load_lds16(qsrc, (char*)As + t * 16);
      load_lds16(qsrc + (size_t)64 * DIN, (char*)As + t * 16 + 4096);
      const unsigned short* ksrc = K + (size_t)(kt + sr) * DIN + kb + sch * 8;
      load_lds16(ksrc, (char*)Bs + t * 16);
      load_lds16(ksrc + (size_t)64 * DIN, (char*)Bs + t * 16 + 4096);
      __syncthreads();
      bf16x8 af[4], bfr[4];
#pragma unroll
      for (int i = 0; i < 4; i++)
        af[i] = *(const bf16x8*)&As[(wm + i * 16 + lrow) * 32 + quad * 8];
#pragma unroll
      for (int j = 0; j < 4; j++)
        bfr[j] = *(const bf16x8*)&Bs[(wn + j * 16 + lrow) * 32 + quad * 8];
#pragma unroll
      for (int i = 0; i < 4; i++)
#pragma unroll
        for (int j = 0; j < 4; j++)
          accS[i][j] = __builtin_amdgcn_mfma_f32_16x16x32_bf16(af[i], bfr[j], accS[i][j], 0, 0, 0);
    }

    // ---- Phase 2: online softmax ----
    float tm[16];
#pragma unroll
    for (int i = 0; i < 4; i++)
#pragma unroll
      for (int r = 0; r < 4; r++) {
        float v = fmaxf(fmaxf(accS[i][0][r], accS[i][1][r]),
                        fmaxf(accS[i][2][r], accS[i][3][r]));
        tm[i * 4 + r] = v;
      }
#pragma unroll
    for (int mask = 1; mask < 16; mask <<= 1)
#pragma unroll
      for (int x = 0; x < 16; x++) tm[x] = fmaxf(tm[x], __shfl_xor(tm[x], mask));
    if (lrow == 0) {
#pragma unroll
      for (int i = 0; i < 4; i++)
#pragma unroll
        for (int r = 0; r < 4; r++)
          redM[wave & 1][wm + i * 16 + quad * 4 + r] = tm[i * 4 + r];
    }
    __syncthreads();
    float alpha[16];
#pragma unroll
    for (int i = 0; i < 4; i++)
#pragma unroll
      for (int r = 0; r < 4; r++) {
        int x = i * 4 + r, row = wm + i * 16 + quad * 4 + r;
        float mt = fmaxf(redM[0][row], redM[1][row]);
        float mn = fmaxf(m_i[x], mt);
        alpha[x] = __expf(m_i[x] - mn);
        m_i[x] = mn;
      }
    float ts[16];
#pragma unroll
    for (int x = 0; x < 16; x++) ts[x] = 0.f;
#pragma unroll
    for (int i = 0; i < 4; i++)
#pragma unroll
      for (int j = 0; j < 4; j++)
#pragma unroll
        for (int r = 0; r < 4; r++) {
          int x = i * 4 + r;
          float p = __expf(accS[i][j][r] - m_i[x]);
          ts[x] += p;
          Ps[(wm + i * 16 + quad * 4 + r) * 136 + wn + j * 16 + lrow] = f2bf(p);
        }
#pragma unroll
    for (int mask = 1; mask < 16; mask <<= 1)
#pragma unroll
      for (int x = 0; x < 16; x++) ts[x] += __shfl_xor(ts[x], mask);
    if (lrow == 0) {
#pragma unroll
      for (int i = 0; i < 4; i++)
#pragma unroll
        for (int r = 0; r < 4; r++)
          redL[wave & 1][wm + i * 16 + quad * 4 + r] = ts[i * 4 + r];
    }
    __syncthreads();   // also makes Ps visible to all waves
#pragma unroll
    for (int i = 0; i < 4; i++)
#pragma unroll
      for (int r = 0; r < 4; r++) {
        int x = i * 4 + r, row = wm + i * 16 + quad * 4 + r;
        l_i[x] = l_i[x] * alpha[x] + redL[0][row] + redL[1][row];
      }
#pragma unroll
    for (int h = 0; h < NH; h++)
#pragma unroll
      for (int i = 0; i < 4; i++)
#pragma unroll
        for (int j = 0; j < 4; j++)
#pragma unroll
          for (int r = 0; r < 4; r++) accO[h][i][j][r] *= alpha[i * 4 + r];

    // ---- Phase 3: O += P @ V ----
    for (int h = 0; h < NH; h++) {
      for (int kb = 0; kb < 128; kb += 32) {
        __syncthreads();
        const unsigned short* vsrc = Vt + (size_t)(h * 128 + sr) * NN + kt + kb + sch * 8;
        load_lds16(vsrc, (char*)Bs + t * 16);
        load_lds16(vsrc + (size_t)64 * NN, (char*)Bs + t * 16 + 4096);
        __syncthreads();
        bf16x8 af[4], bfr[4];
#pragma unroll
        for (int i = 0; i < 4; i++)
          af[i] = *(const bf16x8*)&Ps[(wm + i * 16 + lrow) * 136 + kb + quad * 8];
#pragma unroll
        for (int j = 0; j < 4; j++)
          bfr[j] = *(const bf16x8*)&Bs[(wn + j * 16 + lrow) * 32 + quad * 8];
#pragma unroll
        for (int i = 0; i < 4; i++)
#pragma unroll
          for (int j = 0; j < 4; j++)
            accO[h][i][j] = __builtin_amdgcn_mfma_f32_16x16x32_bf16(af[i], bfr[j], accO[h][i][j], 0, 0, 0);
      }
    }
  }

  // ---- epilogue: un-normalized partials ----
#pragma unroll
  for (int h = 0; h < NH; h++)
#pragma unroll
    for (int i = 0; i < 4; i++)
#pragma unroll
      for (int j = 0; j < 4; j++)
#pragma unroll
        for (int r = 0; r < 4; r++) {
          int row = rowBase + wm + i * 16 + quad * 4 + r;
          int col = h * 128 + wn + j * 16 + lrow;
          Opart[((size_t)split * NN + row) * DIN + col] = f2bf(accO[h][i][j][r]);
        }
  if (lrow == 0) {
#pragma unroll
    for (int i = 0; i < 4; i++)
#pragma unroll
      for (int r = 0; r < 4; r++) {
        int row = rowBase + wm + i * 16 + quad * 4 + r;
        mpart[(size_t)split * NN + row] = m_i[i * 4 + r];
        lpart[(size_t)split * NN + row] = l_i[i * 4 + r];
      }
  }
}

// combine NSPLIT flash partials: att[row][f] = sum_s w_s*O_s / sum_s w_s*l_s
__global__ void flash_merge(const unsigned short* __restrict__ Op, const float* __restrict__ mp,
                            const float* __restrict__ lp, float* __restrict__ att,
                            int din, int dshift) {
  int idx = blockIdx.x * 256 + threadIdx.x;
  int pair = idx * 2;
  int row = pair >> dshift;
  int f = pair & (din - 1);
  float m0 = mp[row], m1 = mp[NN + row], m2 = mp[2 * NN + row], m3 = mp[3 * NN + row];
  float M = fmaxf(fmaxf(m0, m1), fmaxf(m2, m3));
  float w0 = __expf(m0 - M), w1 = __expf(m1 - M);
  float w2 = __expf(m2 - M), w3 = __expf(m3 - M);
  float L = lp[row] * w0 + lp[NN + row] * w1 + lp[2 * NN + row] * w2 + lp[3 * NN + row] * w3;
  float inv = 1.f / L;
  size_t base = (size_t)row * din + f;
  size_t stride = (size_t)NN * din;
  float a0 = 0.f, a1 = 0.f;
  unsigned u;
  u = *(const unsigned*)(Op + base);
  a0 += w0 * bf2f(u & 0xffffu); a1 += w0 * bf2f(u >> 16);
  u = *(const unsigned*)(Op + stride + base);
  a0 += w1 * bf2f(u & 0xffffu); a1 += w1 * bf2f(u >> 16);
  u = *(const unsigned*)(Op + 2 * stride + base);
  a0 += w2 * bf2f(u & 0xffffu); a1 += w2 * bf2f(u >> 16);
  u = *(const unsigned*)(Op + 3 * stride + base);
  a0 += w3 * bf2f(u & 0xffffu); a1 += w3 * bf2f(u >> 16);
  float2 o; o.x = a0 * inv; o.y = a1 * inv;
  *(float2*)(att + base) = o;
}

// --------------------------- small kernels ---------------------------------

__global__ void ws_sentinel(float* out) { out[0] = 12345.0f; out[1] = 12345.0f; }

__global__ void cvt_bf16(const float* __restrict__ in, unsigned short* __restrict__ out, int n) {
  int i = (blockIdx.x * 256 + threadIdx.x) * 4;
  if (i < n) {
    f32x4 v = *(const f32x4*)(in + i);
    uint2 p;
    p.x = f2bf(v.x) | ((unsigned)f2bf(v.y) << 16);
    p.y = f2bf(v.z) | ((unsigned)f2bf(v.w) << 16);
    *(uint2*)(out + i) = p;
  }
}

// dst[C][R] = bf16(src[R][C])
__global__ void transpose_bf16(const float* __restrict__ src, unsigned short* __restrict__ dst,
                               int R, int C) {
  __shared__ float tile[32][33];
  int c0 = blockIdx.x * 32, r0 = blockIdx.y * 32;
  int x = threadIdx.x, y = threadIdx.y;
  for (int i = y; i < 32; i += 8) tile[i][x] = src[(size_t)(r0 + i) * C + c0 + x];
  __syncthreads();
  for (int i = y; i < 32; i += 8) dst[(size_t)(c0 + i) * R + r0 + x] = f2bf(tile[x][i]);
}

__global__ void deg_count(const int* __restrict__ dst, int* __restrict__ deg) {
  int e = blockIdx.x * 256 + threadIdx.x;
  atomicAdd(&deg[dst[e]], 1);
}

__global__ void make_dinv(const int* __restrict__ deg, float* __restrict__ dinv) {
  int v = blockIdx.x * 256 + threadIdx.x;
  dinv[v] = rsqrtf((float)(deg[v] + 1));  // +1 self-loop
}

// exclusive prefix sum of deg[8192] -> rowstart[8193]; single block of 1024
__global__ void scan_deg(const int* __restrict__ deg, int* __restrict__ rowstart) {
  __shared__ int part[1024];
  int t = threadIdx.x;
  int base = t * 8;
  int local[8];
  int s = 0;
#pragma unroll
  for (int i = 0; i < 8; i++) { local[i] = s; s += deg[base + i]; }
  part[t] = s;
  __syncthreads();
  for (int off = 1; off < 1024; off <<= 1) {
    int v = (t >= off) ? part[t - off] : 0;
    __syncthreads();
    part[t] += v;
    __syncthreads();
  }
  int offset = (t == 0) ? 0 : part[t - 1];
#pragma unroll
  for (int i = 0; i < 8; i++) rowstart[base + i] = offset + local[i];
  if (t == 1023) rowstart[8192] = offset + s;
}

__global__ void csr_fill(const int* __restrict__ src, const int* __restrict__ dst,
                         int* __restrict__ cursor, int* __restrict__ csr_src) {
  int e = blockIdx.x * 256 + threadIdx.x;
  int pos = atomicAdd(&cursor[dst[e]], 1);
  csr_src[pos] = src[e];
}

// c[v] = dinv[v]^2*h[v] + sum_in dinv[s]*dinv[v]*h[s]; one wave per node
__global__ __launch_bounds__(256) void gcn_agg(
    const int* __restrict__ rowstart, const int* __restrict__ csr_src,
    const float* __restrict__ dinv, const float* __restrict__ h,
    float* __restrict__ c) {
  int node = blockIdx.x * 4 + (threadIdx.x >> 6);
  int lane = threadIdx.x & 63;
  float dn = dinv[node];
  f32x4 acc = *(const f32x4*)(h + (size_t)node * 256 + lane * 4);
  float w0 = dn * dn;
  acc.x *= w0; acc.y *= w0; acc.z *= w0; acc.w *= w0;
  int s0 = rowstart[node], s1 = rowstart[node + 1];
  for (int j = s0; j < s1; j++) {
    int s = csr_src[j];
    float w = dinv[s] * dn;
    f32x4 v = *(const f32x4*)(h + (size_t)s * 256 + lane * 4);
    acc.x += w * v.x; acc.y += w * v.y; acc.z += w * v.z; acc.w += w * v.w;
  }
  *(f32x4*)(c + (size_t)node * 256 + lane * 4) = acc;
}

// cat[i][:] = bf16([ c[i](256) | f[i](din) | f[i]-att[i](din) ])
__global__ void build_cat(const float* __restrict__ cbuf, const float* __restrict__ f,
                          const float* __restrict__ att, unsigned short* __restrict__ cat,
                          int din, int W) {
  int i = blockIdx.y;
  int c = blockIdx.x * 256 + threadIdx.x;
  float v;
  if (c < 256) v = cbuf[(size_t)i * 256 + c];
  else if (c < 256 + din) v = f[(size_t)i * din + (c - 256)];
  else v = f[(size_t)i * din + (c - 256 - din)] - att[(size_t)i * din + (c - 256 - din)];
  cat[(size_t)i * W + c] = f2bf(v);
}

__global__ void gated_pool(const float* __restrict__ q, const float* __restrict__ f,
                           float* __restrict__ p) {
  int col = threadIdx.x;
  int r0 = blockIdx.x * 128;
  float a = 0.f;
  for (int i = r0; i < r0 + 128; i++) {
    float qv = q[(size_t)i * 256 + col];
    a += f[(size_t)i * 256 + col] / (1.f + __expf(-qv));
  }
  atomicAdd(&p[col], a);
}

__global__ void ntn_bilinear(const float* __restrict__ p1, const float* __restrict__ tnW,
                             float* __restrict__ tmp) {
  int c = blockIdx.x * 256 + threadIdx.x;
  float a = 0.f;
#pragma unroll 8
  for (int i = 0; i < 256; i++) a += p1[i] * tnW[(size_t)i * 8192 + c];
  tmp[c] = a;
}

__global__ void ntn_final(const float* __restrict__ tmp, const float* __restrict__ p1,
                          const float* __restrict__ p2, const float* __restrict__ tnWb,
                          const float* __restrict__ tnb, const float* __restrict__ fc1W,
                          const float* __restrict__ fc1b, const float* __restrict__ scW,
                          const float* __restrict__ scb, const float* __restrict__ avgv,
                          float* __restrict__ out) {
  __shared__ float pc[512];
  __shared__ float ntn[32];
  __shared__ float sarr[16];
  int t = threadIdx.x;
  pc[t] = p1[t];
  pc[256 + t] = p2[t];
  __syncthreads();
  if (t < 32) {
    float sc = 0.f;
    for (int j = 0; j < 256; j++) sc += tmp[j * 32 + t] * pc[256 + j];
    float bl = 0.f;
    for (int k = 0; k < 512; k++) bl += tnWb[t * 512 + k] * pc[k];
    float v = sc + bl + tnb[t];
    ntn[t] = v > 0.f ? v : 0.f;
  }
  __syncthreads();
  if (t < 16) {
    float a = fc1b[t];
    for (int i = 0; i < 32; i++) a += ntn[i] * fc1W[i * 16 + t];
    sarr[t] = tanhf(a);
  }
  __syncthreads();
  if (t == 0) {
    float a = scb[0];
    for (int b = 0; b < 16; b++) a += sarr[b] * scW[b];
    float score = 1.f / (1.f + expf(-a));
    out[0] = score;
    out[1] = -logf(score) * avgv[0];
  }
}

// ---------------------------------------------------------------------------

extern "C" void kernel_launch(void* const* d_in, const int* in_sizes, int n_in,
                              void* d_out, int out_size, void* d_ws, size_t ws_size,
                              hipStream_t stream) {
  (void)in_sizes; (void)n_in; (void)out_size;
  const float* feat1 = (const float*)d_in[0];
  const float* feat2 = (const float*)d_in[1];
  const int* ei1 = (const int*)d_in[2];
  const int* ei2 = (const int*)d_in[3];
  const float* avgv = (const float*)d_in[4];
  const float* gcnW[3] = {(const float*)d_in[5], (const float*)d_in[8], (const float*)d_in[11]};
  const float* updW[3] = {(const float*)d_in[6], (const float*)d_in[9], (const float*)d_in[12]};
  const float* updb[3] = {(const float*)d_in[7], (const float*)d_in[10], (const float*)d_in[13]};
  const float* gatedW = (const float*)d_in[14];
  const float* gatedb = (const float*)d_in[15];
  const float* tnW = (const float*)d_in[16];
  const float* tnWb = (const float*)d_in[17];
  const float* tnb = (const float*)d_in[18];
  const float* fc1W = (const float*)d_in[19];
  const float* fc1b = (const float*)d_in[20];
  const float* scW = (const float*)d_in[21];
  const float* scb = (const float*)d_in[22];
  float* out = (float*)d_out;

  char* wp = (char*)d_ws;
  auto take = [&](size_t b) { char* p = wp; wp += (b + 255) & ~(size_t)255; return p; };
  // 32 MB region: flash O-partials early, cat1/cat2 late
  unsigned short* opReg = (unsigned short*)take((size_t)2 * NSPLIT * NN * 256 * 2);
  unsigned short* Op1 = opReg;
  unsigned short* Op2 = opReg + (size_t)NSPLIT * NN * 256;
  unsigned short* cat1 = opReg;
  unsigned short* cat2 = cat1 + (size_t)NN * 768;
  float* fb1 = (float*)take((size_t)NN * 256 * 4);
  float* fb2 = (float*)take((size_t)NN * 256 * 4);
  unsigned short* f1b = (unsigned short*)take((size_t)NN * 256 * 2);
  unsigned short* f2b = (unsigned short*)take((size_t)NN * 256 * 2);
  unsigned short* f1bT = (unsigned short*)take((size_t)NN * 256 * 2);
  unsigned short* f2bT = (unsigned short*)take((size_t)NN * 256 * 2);
  float* h1 = (float*)take((size_t)NN * 256 * 4);   // h, then att1
  float* h2 = (float*)take((size_t)NN * 256 * 4);   // h, then att2
  float* c1 = (float*)take((size_t)NN * 256 * 4);   // gcn agg, then q (gated)
  float* c2 = (float*)take((size_t)NN * 256 * 4);
  unsigned short* WgT[3], *WuT[3];
  for (int l = 0; l < 3; l++) WgT[l] = (unsigned short*)take(256 * 256 * 2);
  for (int l = 0; l < 3; l++) WuT[l] = (unsigned short*)take(256 * 768 * 2);
  unsigned short* gWT = (unsigned short*)take(256 * 256 * 2);
  int* deg1 = (int*)take(NN * 4);
  int* deg2 = (int*)take(NN * 4);
  float* dinv1 = (float*)take(NN * 4);
  float* dinv2 = (float*)take(NN * 4);
  int* rs1 = (int*)take((NN + 1) * 4);
  int* rs2 = (int*)take((NN + 1) * 4);
  int* cur1 = (int*)take(NN * 4);
  int* cur2 = (int*)take(NN * 4);
  int* csr1 = (int*)take((size_t)EDG * 4);
  int* csr2 = (int*)take((size_t)EDG * 4);
  float* mp1 = (float*)take((size_t)NSPLIT * NN * 4);
  float* lp1 = (float*)take((size_t)NSPLIT * NN * 4);
  float* mp2 = (float*)take((size_t)NSPLIT * NN * 4);
  float* lp2 = (float*)take((size_t)NSPLIT * NN * 4);
  float* p1 = (float*)take(1024);
  float* p2 = (float*)take(1024);
  float* tmp = (float*)take(NN * 4);

  size_t need = (size_t)(wp - (char*)d_ws);
  if (need > ws_size) {
    ws_sentinel<<<1, 1, 0, stream>>>(out);
    return;
  }

  // degree / dinv / CSR (edge structure is layer-invariant)
  hipMemsetAsync(deg1, 0, NN * 4, stream);
  hipMemsetAsync(deg2, 0, NN * 4, stream);
  deg_count<<<EDG / 256, 256, 0, stream>>>(ei1 + EDG, deg1);
  deg_count<<<EDG / 256, 256, 0, stream>>>(ei2 + EDG, deg2);
  make_dinv<<<NN / 256, 256, 0, stream>>>(deg1, dinv1);
  make_dinv<<<NN / 256, 256, 0, stream>>>(deg2, dinv2);
  scan_deg<<<1, 1024, 0, stream>>>(deg1, rs1);
  scan_deg<<<1, 1024, 0, stream>>>(deg2, rs2);
  hipMemcpyAsync(cur1, rs1, NN * 4, hipMemcpyDeviceToDevice, stream);
  hipMemcpyAsync(cur2, rs2, NN * 4, hipMemcpyDeviceToDevice, stream);
  csr_fill<<<EDG / 256, 256, 0, stream>>>(ei1, ei1 + EDG, cur1, csr1);
  csr_fill<<<EDG / 256, 256, 0, stream>>>(ei2, ei2 + EDG, cur2, csr2);

  // weights -> bf16 [out][in]
  for (int l = 0; l < 3; l++) {
    int din = (l == 0) ? 128 : 256;
    int W = 256 + 2 * din;
    transpose_bf16<<<dim3(8, din / 32), dim3(32, 8), 0, stream>>>(gcnW[l], WgT[l], din, 256);
    transpose_bf16<<<dim3(8, W / 32), dim3(32, 8), 0, stream>>>(updW[l], WuT[l], W, 256);
  }
  transpose_bf16<<<dim3(8, 8), dim3(32, 8), 0, stream>>>(gatedW, gWT, 256, 256);

  const float* f1 = feat1;
  const float* f2 = feat2;

  for (int l = 0; l < 3; l++) {
    const int din = (l == 0) ? 128 : 256;
    const int dshift = (l == 0) ? 7 : 8;
    const int W = 256 + 2 * din;
    const int nel = NN * din;

    cvt_bf16<<<nel / 1024, 256, 0, stream>>>(f1, f1b, nel);
    cvt_bf16<<<nel / 1024, 256, 0, stream>>>(f2, f2b, nel);
    transpose_bf16<<<dim3(din / 32, NN / 32), dim3(32, 8), 0, stream>>>(f1, f1bT, NN, din);
    transpose_bf16<<<dim3(din / 32, NN / 32), dim3(32, 8), 0, stream>>>(f2, f2bT, NN, din);

    // h = f @ Wg
    gemm_k<0><<<dim3(64, 2), 256, 0, stream>>>(f1b, din, WgT[l], din, nullptr, h1, 256, din);
    gemm_k<0><<<dim3(64, 2), 256, 0, stream>>>(f2b, din, WgT[l], din, nullptr, h2, 256, din);

    // c = D^-1/2 (A+I) D^-1/2 h — CSR gather, no atomics
    gcn_agg<<<NN / 4, 256, 0, stream>>>(rs1, csr1, dinv1, h1, c1);
    gcn_agg<<<NN / 4, 256, 0, stream>>>(rs2, csr2, dinv2, h2, c2);

    // fused attention, both directions:
    // att1 = Flash(Q=f1, K=f2, V=f2); att2 = Flash(Q=f2, K=f1, V=f1)
    if (l == 0) {
      flash_att<128><<<dim3(NN / 128, NSPLIT), 256, 0, stream>>>(f1b, f2b, f2bT, Op1, mp1, lp1, NN / NSPLIT);
      flash_att<128><<<dim3(NN / 128, NSPLIT), 256, 0, stream>>>(f2b, f1b, f1bT, Op2, mp2, lp2, NN / NSPLIT);
    } else {
      flash_att<256><<<dim3(NN / 128, NSPLIT), 256, 0, stream>>>(f1b, f2b, f2bT, Op1, mp1, lp1, NN / NSPLIT);
      flash_att<256><<<dim3(NN / 128, NSPLIT), 256, 0, stream>>>(f2b, f1b, f1bT, Op2, mp2, lp2, NN / NSPLIT);
    }
    flash_merge<<<(NN * din / 2) / 256, 256, 0, stream>>>(Op1, mp1, lp1, h1, din, dshift);
    flash_merge<<<(NN * din / 2) / 256, 256, 0, stream>>>(Op2, mp2, lp2, h2, din, dshift);

    // g = tanh?(concat([c, f, f-att]) @ Wu + bu)   (cat overlaps dead Op region)
    build_cat<<<dim3(W / 256, NN), 256, 0, stream>>>(c1, f1, h1, cat1, din, W);
    build_cat<<<dim3(W / 256, NN), 256, 0, stream>>>(c2, f2, h2, cat2, din, W);
    if (l < 2) {
      gemm_k<3><<<dim3(64, 2), 256, 0, stream>>>(cat1, W, WuT[l], W, updb[l], fb1, 256, W);
      gemm_k<3><<<dim3(64, 2), 256, 0, stream>>>(cat2, W, WuT[l], W, updb[l], fb2, 256, W);
    } else {
      gemm_k<2><<<dim3(64, 2), 256, 0, stream>>>(cat1, W, WuT[l], W, updb[l], fb1, 256, W);
      gemm_k<2><<<dim3(64, 2), 256, 0, stream>>>(cat2, W, WuT[l], W, updb[l], fb2, 256, W);
    }
    f1 = fb1;
    f2 = fb2;
  }

  // gated readout
  cvt_bf16<<<NN * 256 / 1024, 256, 0, stream>>>(f1, f1b, NN * 256);
  cvt_bf16<<<NN * 256 / 1024, 256, 0, stream>>>(f2, f2b, NN * 256);
  gemm_k<2><<<dim3(64, 2), 256, 0, stream>>>(f1b, 256, gWT, 256, gatedb, c1, 256, 256);
  gemm_k<2><<<dim3(64, 2), 256, 0, stream>>>(f2b, 256, gWT, 256, gatedb, c2, 256, 256);
  hipMemsetAsync(p1, 0, 256 * 4, stream);
  hipMemsetAsync(p2, 0, 256 * 4, stream);
  gated_pool<<<64, 256, 0, stream>>>(c1, f1, p1);
  gated_pool<<<64, 256, 0, stream>>>(c2, f2, p2);

  // NTN + scoring head
  ntn_bilinear<<<32, 256, 0, stream>>>(p1, tnW, tmp);
  ntn_final<<<1, 256, 0, stream>>>(tmp, p1, p2, tnWb, tnb, fc1W, fc1b, scW, scb, avgv, out);
}

// Round 6
// 1635.855 us; speedup vs baseline: 4.2038x; 1.0481x over previous
//
#include <hip/hip_runtime.h>
#include <hip/hip_bf16.h>
#include <stdint.h>

#define NN 8192
#define EDG 131072
#define NSPLIT 8

typedef __attribute__((ext_vector_type(8))) short bf16x8;
typedef __attribute__((ext_vector_type(4))) float f32x4;

__device__ __forceinline__ unsigned short f2bf(float f) {
  union { float f; unsigned u; } v; v.f = f;
  return (unsigned short)((v.u + 0x7fffu + ((v.u >> 16) & 1u)) >> 16);
}

__device__ __forceinline__ float bf2f(unsigned short u) {
  union { unsigned u; float f; } v; v.u = ((unsigned)u) << 16;
  return v.f;
}

__device__ __forceinline__ void load_lds16(const void* g, void* l) {
  __builtin_amdgcn_global_load_lds(
      (__attribute__((address_space(1))) void*)(uintptr_t)g,
      (__attribute__((address_space(3))) void*)(uintptr_t)l,
      16, 0, 0);
}

// ---------------------------------------------------------------------------
// C[M,N] = A[M,K] * Bt[N,K]^T (+bias, +tanh)   bf16 in, fp32 accum
// EPI 0: store; 2: +bias[col]; 3: tanh(+bias[col])
// ---------------------------------------------------------------------------
template <int EPI>
__global__ __launch_bounds__(256) void gemm_k(
    const unsigned short* __restrict__ A, int lda,
    const unsigned short* __restrict__ Bt, int ldb,
    const float* __restrict__ bias, float* __restrict__ C, int ldc, int K) {
  __shared__ alignas(16) unsigned short As[128 * 32];
  __shared__ alignas(16) unsigned short Bs[128 * 32];
  const int t = threadIdx.x;
  const int wave = t >> 6, lane = t & 63;
  const int wm = (wave >> 1) * 64, wn = (wave & 1) * 64;
  const int lrow = lane & 15, quad = lane >> 4;
  const int rowBase = blockIdx.x * 128;
  const int colBase = blockIdx.y * 128;

  f32x4 acc[4][4];
#pragma unroll
  for (int i = 0; i < 4; i++)
#pragma unroll
    for (int j = 0; j < 4; j++) acc[i][j] = f32x4{0.f, 0.f, 0.f, 0.f};

  const int sr = t >> 2, sch = t & 3;

  for (int kb = 0; kb < K; kb += 32) {
    __syncthreads();
    const unsigned short* bsrc = Bt + (size_t)(colBase + sr) * ldb + kb + sch * 8;
    load_lds16(bsrc, (char*)Bs + t * 16);
    load_lds16(bsrc + (size_t)64 * ldb, (char*)Bs + t * 16 + 4096);
    const unsigned short* asrc = A + (size_t)(rowBase + sr) * lda + kb + sch * 8;
    load_lds16(asrc, (char*)As + t * 16);
    load_lds16(asrc + (size_t)64 * lda, (char*)As + t * 16 + 4096);
    __syncthreads();

    bf16x8 af[4], bfr[4];
#pragma unroll
    for (int i = 0; i < 4; i++)
      af[i] = *(const bf16x8*)&As[(wm + i * 16 + lrow) * 32 + quad * 8];
#pragma unroll
    for (int j = 0; j < 4; j++)
      bfr[j] = *(const bf16x8*)&Bs[(wn + j * 16 + lrow) * 32 + quad * 8];
#pragma unroll
    for (int i = 0; i < 4; i++)
#pragma unroll
      for (int j = 0; j < 4; j++)
        acc[i][j] = __builtin_amdgcn_mfma_f32_16x16x32_bf16(af[i], bfr[j], acc[i][j], 0, 0, 0);
  }

#pragma unroll
  for (int i = 0; i < 4; i++) {
    int row = rowBase + wm + i * 16 + quad * 4;
#pragma unroll
    for (int j = 0; j < 4; j++) {
      int col = colBase + wn + j * 16 + lrow;
#pragma unroll
      for (int r = 0; r < 4; r++) {
        float v = acc[i][j][r];
        size_t idx = (size_t)(row + r) * ldc + col;
        if (EPI == 0) C[idx] = v;
        else {
          v += bias[col];
          if (EPI == 3) v = tanhf(v);
          C[idx] = v;
        }
      }
    }
  }
}

// ---------------------------------------------------------------------------
// Flash attention, double-buffered staging + swizzled P.
// Q[NN][DIN], K[NN][DIN] bf16; Vt[DIN][NN] bf16. grid=(NN/128, NSPLIT).
// Ps layout: P[row][col] at row*128 + ((g ^ (key<<1))<<3) + (col&7),
//   g=col>>3, key=((row>>2)&3)^(row&3)  -> 32-bank coverage on write.
// ---------------------------------------------------------------------------
template <int DIN>
__global__ __launch_bounds__(256, 1) void flash_att(
    const unsigned short* __restrict__ Q, const unsigned short* __restrict__ K,
    const unsigned short* __restrict__ Vt, unsigned short* __restrict__ Opart,
    float* __restrict__ mpart, float* __restrict__ lpart, int kvPerSplit) {
  constexpr int NH = DIN / 128;
  constexpr int NKC = DIN / 32;
  __shared__ alignas(16) unsigned short As[2][128 * 32];
  __shared__ alignas(16) unsigned short Bs[2][128 * 32];
  __shared__ alignas(16) unsigned short Ps[128 * 128];
  __shared__ float redM[2][2][128];
  __shared__ float redL[2][2][128];
  const int t = threadIdx.x;
  const int wave = t >> 6, lane = t & 63;
  const int wm = (wave >> 1) * 64, wn = (wave & 1) * 64;
  const int lrow = lane & 15, quad = lane >> 4;
  const int rowBase = blockIdx.x * 128;
  const int split = blockIdx.y;
  const int kv0 = split * kvPerSplit;
  const int sr = t >> 2, sch = t & 3;
  const int pkey = ((lrow >> 2) ^ lrow) & 3;   // P-read swizzle key

  float m_i[16], l_i[16];
#pragma unroll
  for (int x = 0; x < 16; x++) { m_i[x] = -3.0e38f; l_i[x] = 0.f; }
  f32x4 accO[NH][4][4];
#pragma unroll
  for (int h = 0; h < NH; h++)
#pragma unroll
    for (int i = 0; i < 4; i++)
#pragma unroll
      for (int j = 0; j < 4; j++) accO[h][i][j] = f32x4{0.f, 0.f, 0.f, 0.f};

  int ktp = 0;
  for (int kt = kv0; kt < kv0 + kvPerSplit; kt += 128, ktp ^= 1) {
    // ---- Phase 1: S = Q_tile @ K_tile^T (dbuf staging, 1 barrier/chunk) ----
    {  // prologue: chunk 0 -> buf 0
      const unsigned short* qsrc = Q + (size_t)(rowBase + sr) * DIN + sch * 8;
      load_lds16(qsrc, (char*)As[0] + t * 16);
      load_lds16(qsrc + (size_t)64 * DIN, (char*)As[0] + t * 16 + 4096);
      const unsigned short* ksrc = K + (size_t)(kt + sr) * DIN + sch * 8;
      load_lds16(ksrc, (char*)Bs[0] + t * 16);
      load_lds16(ksrc + (size_t)64 * DIN, (char*)Bs[0] + t * 16 + 4096);
    }
    f32x4 accS[4][4];
#pragma unroll
    for (int i = 0; i < 4; i++)
#pragma unroll
      for (int j = 0; j < 4; j++) accS[i][j] = f32x4{0.f, 0.f, 0.f, 0.f};

    for (int kc = 0; kc < NKC; kc++) {
      const int buf = kc & 1;
      __syncthreads();                              // drain loads for buf
      if (kc + 1 < NKC) {                           // prefetch next chunk
        const int kb = (kc + 1) * 32;
        const unsigned short* qsrc = Q + (size_t)(rowBase + sr) * DIN + kb + sch * 8;
        load_lds16(qsrc, (char*)As[buf ^ 1] + t * 16);
        load_lds16(qsrc + (size_t)64 * DIN, (char*)As[buf ^ 1] + t * 16 + 4096);
        const unsigned short* ksrc = K + (size_t)(kt + sr) * DIN + kb + sch * 8;
        load_lds16(ksrc, (char*)Bs[buf ^ 1] + t * 16);
        load_lds16(ksrc + (size_t)64 * DIN, (char*)Bs[buf ^ 1] + t * 16 + 4096);
      }
      bf16x8 af[4], bfr[4];
#pragma unroll
      for (int i = 0; i < 4; i++)
        af[i] = *(const bf16x8*)&As[buf][(wm + i * 16 + lrow) * 32 + quad * 8];
#pragma unroll
      for (int j = 0; j < 4; j++)
        bfr[j] = *(const bf16x8*)&Bs[buf][(wn + j * 16 + lrow) * 32 + quad * 8];
#pragma unroll
      for (int i = 0; i < 4; i++)
#pragma unroll
        for (int j = 0; j < 4; j++)
          accS[i][j] = __builtin_amdgcn_mfma_f32_16x16x32_bf16(af[i], bfr[j], accS[i][j], 0, 0, 0);
    }

    // prefetch V chunk 0 into Bs[0] (K data dead; overlaps softmax VALU)
    {
      const unsigned short* vsrc = Vt + (size_t)sr * NN + kt + sch * 8;
      load_lds16(vsrc, (char*)Bs[0] + t * 16);
      load_lds16(vsrc + (size_t)64 * NN, (char*)Bs[0] + t * 16 + 4096);
    }

    // ---- Phase 2: online softmax ----
    float tm[16];
#pragma unroll
    for (int i = 0; i < 4; i++)
#pragma unroll
      for (int r = 0; r < 4; r++)
        tm[i * 4 + r] = fmaxf(fmaxf(accS[i][0][r], accS[i][1][r]),
                              fmaxf(accS[i][2][r], accS[i][3][r]));
#pragma unroll
    for (int mask = 1; mask < 16; mask <<= 1)
#pragma unroll
      for (int x = 0; x < 16; x++) tm[x] = fmaxf(tm[x], __shfl_xor(tm[x], mask));
    if (lrow == 0) {
#pragma unroll
      for (int i = 0; i < 4; i++)
#pragma unroll
        for (int r = 0; r < 4; r++)
          redM[ktp][wave & 1][wm + i * 16 + quad * 4 + r] = tm[i * 4 + r];
    }
    __syncthreads();   // A: redM visible
    float alpha[16];
#pragma unroll
    for (int i = 0; i < 4; i++)
#pragma unroll
      for (int r = 0; r < 4; r++) {
        int x = i * 4 + r, row = wm + i * 16 + quad * 4 + r;
        float mt = fmaxf(redM[ktp][0][row], redM[ktp][1][row]);
        float mn = fmaxf(m_i[x], mt);
        alpha[x] = __expf(m_i[x] - mn);
        m_i[x] = mn;
      }
    float ts[16];
#pragma unroll
    for (int x = 0; x < 16; x++) ts[x] = 0.f;
#pragma unroll
    for (int i = 0; i < 4; i++)
#pragma unroll
      for (int j = 0; j < 4; j++)
#pragma unroll
        for (int r = 0; r < 4; r++) {
          int x = i * 4 + r;
          float p = __expf(accS[i][j][r] - m_i[x]);
          ts[x] += p;
          int prow = wm + i * 16 + quad * 4 + r;
          int key = (quad ^ r) & 3;
          int g = (wn + j * 16 + lrow) >> 3;
          Ps[prow * 128 + ((g ^ (key << 1)) << 3) + (lrow & 7)] = f2bf(p);
        }
#pragma unroll
    for (int mask = 1; mask < 16; mask <<= 1)
#pragma unroll
      for (int x = 0; x < 16; x++) ts[x] += __shfl_xor(ts[x], mask);
    if (lrow == 0) {
#pragma unroll
      for (int i = 0; i < 4; i++)
#pragma unroll
        for (int r = 0; r < 4; r++)
          redL[ktp][wave & 1][wm + i * 16 + quad * 4 + r] = ts[i * 4 + r];
    }
    // rescale O before the barrier (independent of redL)
#pragma unroll
    for (int h = 0; h < NH; h++)
#pragma unroll
      for (int i = 0; i < 4; i++)
#pragma unroll
        for (int j = 0; j < 4; j++)
#pragma unroll
          for (int r = 0; r < 4; r++) accO[h][i][j][r] *= alpha[i * 4 + r];

    // ---- Phase 3: O += P @ V (dbuf staging over NH*4 chunks) ----
    for (int cc = 0; cc < NH * 4; cc++) {
      const int buf = cc & 1;
      __syncthreads();   // cc=0: Ps + redL + V0 visible
      if (cc == 0) {
#pragma unroll
        for (int i = 0; i < 4; i++)
#pragma unroll
          for (int r = 0; r < 4; r++) {
            int x = i * 4 + r, row = wm + i * 16 + quad * 4 + r;
            l_i[x] = l_i[x] * alpha[x] + redL[ktp][0][row] + redL[ktp][1][row];
          }
      }
      if (cc + 1 < NH * 4) {
        const int h2 = (cc + 1) >> 2, kbc2 = (cc + 1) & 3;
        const unsigned short* vsrc =
            Vt + (size_t)(h2 * 128 + sr) * NN + kt + kbc2 * 32 + sch * 8;
        load_lds16(vsrc, (char*)Bs[buf ^ 1] + t * 16);
        load_lds16(vsrc + (size_t)64 * NN, (char*)Bs[buf ^ 1] + t * 16 + 4096);
      }
      const int h = cc >> 2, kbc = cc & 3;
      bf16x8 af[4], bfr[4];
#pragma unroll
      for (int i = 0; i < 4; i++) {
        int g = kbc * 4 + quad;
        af[i] = *(const bf16x8*)&Ps[(wm + i * 16 + lrow) * 128 + ((g ^ (pkey << 1)) << 3)];
      }
#pragma unroll
      for (int j = 0; j < 4; j++)
        bfr[j] = *(const bf16x8*)&Bs[buf][(wn + j * 16 + lrow) * 32 + quad * 8];
#pragma unroll
      for (int i = 0; i < 4; i++)
#pragma unroll
        for (int j = 0; j < 4; j++)
          accO[h][i][j] = __builtin_amdgcn_mfma_f32_16x16x32_bf16(af[i], bfr[j], accO[h][i][j], 0, 0, 0);
    }
  }

  // ---- epilogue: un-normalized partials ----
#pragma unroll
  for (int h = 0; h < NH; h++)
#pragma unroll
    for (int i = 0; i < 4; i++)
#pragma unroll
      for (int j = 0; j < 4; j++)
#pragma unroll
        for (int r = 0; r < 4; r++) {
          int row = rowBase + wm + i * 16 + quad * 4 + r;
          int col = h * 128 + wn + j * 16 + lrow;
          Opart[((size_t)split * NN + row) * DIN + col] = f2bf(accO[h][i][j][r]);
        }
  if (lrow == 0) {
#pragma unroll
    for (int i = 0; i < 4; i++)
#pragma unroll
      for (int r = 0; r < 4; r++) {
        int row = rowBase + wm + i * 16 + quad * 4 + r;
        mpart[(size_t)split * NN + row] = m_i[i * 4 + r];
        lpart[(size_t)split * NN + row] = l_i[i * 4 + r];
      }
  }
}

// combine NSPLIT flash partials
__global__ void flash_merge(const unsigned short* __restrict__ Op, const float* __restrict__ mp,
                            const float* __restrict__ lp, float* __restrict__ att,
                            int din, int dshift) {
  int idx = blockIdx.x * 256 + threadIdx.x;
  int pair = idx * 2;
  int row = pair >> dshift;
  int f = pair & (din - 1);
  float m[NSPLIT], w[NSPLIT];
  float M = -3.0e38f;
#pragma unroll
  for (int s = 0; s < NSPLIT; s++) { m[s] = mp[(size_t)s * NN + row]; M = fmaxf(M, m[s]); }
  float L = 0.f;
#pragma unroll
  for (int s = 0; s < NSPLIT; s++) { w[s] = __expf(m[s] - M); L += lp[(size_t)s * NN + row] * w[s]; }
  float inv = 1.f / L;
  size_t base = (size_t)row * din + f;
  size_t stride = (size_t)NN * din;
  float a0 = 0.f, a1 = 0.f;
#pragma unroll
  for (int s = 0; s < NSPLIT; s++) {
    unsigned u = *(const unsigned*)(Op + (size_t)s * stride + base);
    a0 += w[s] * bf2f(u & 0xffffu);
    a1 += w[s] * bf2f(u >> 16);
  }
  float2 o; o.x = a0 * inv; o.y = a1 * inv;
  *(float2*)(att + base) = o;
}

// --------------------------- small kernels ---------------------------------

__global__ void ws_sentinel(float* out) { out[0] = 12345.0f; out[1] = 12345.0f; }

__global__ void cvt_bf16(const float* __restrict__ in, unsigned short* __restrict__ out, int n) {
  int i = (blockIdx.x * 256 + threadIdx.x) * 4;
  if (i < n) {
    f32x4 v = *(const f32x4*)(in + i);
    uint2 p;
    p.x = f2bf(v.x) | ((unsigned)f2bf(v.y) << 16);
    p.y = f2bf(v.z) | ((unsigned)f2bf(v.w) << 16);
    *(uint2*)(out + i) = p;
  }
}

__global__ void transpose_bf16(const float* __restrict__ src, unsigned short* __restrict__ dst,
                               int R, int C) {
  __shared__ float tile[32][33];
  int c0 = blockIdx.x * 32, r0 = blockIdx.y * 32;
  int x = threadIdx.x, y = threadIdx.y;
  for (int i = y; i < 32; i += 8) tile[i][x] = src[(size_t)(r0 + i) * C + c0 + x];
  __syncthreads();
  for (int i = y; i < 32; i += 8) dst[(size_t)(c0 + i) * R + r0 + x] = f2bf(tile[x][i]);
}

__global__ void deg_count(const int* __restrict__ dst, int* __restrict__ deg) {
  int e = blockIdx.x * 256 + threadIdx.x;
  atomicAdd(&deg[dst[e]], 1);
}

__global__ void make_dinv(const int* __restrict__ deg, float* __restrict__ dinv) {
  int v = blockIdx.x * 256 + threadIdx.x;
  dinv[v] = rsqrtf((float)(deg[v] + 1));
}

__global__ void scan_deg(const int* __restrict__ deg, int* __restrict__ rowstart) {
  __shared__ int part[1024];
  int t = threadIdx.x;
  int base = t * 8;
  int local[8];
  int s = 0;
#pragma unroll
  for (int i = 0; i < 8; i++) { local[i] = s; s += deg[base + i]; }
  part[t] = s;
  __syncthreads();
  for (int off = 1; off < 1024; off <<= 1) {
    int v = (t >= off) ? part[t - off] : 0;
    __syncthreads();
    part[t] += v;
    __syncthreads();
  }
  int offset = (t == 0) ? 0 : part[t - 1];
#pragma unroll
  for (int i = 0; i < 8; i++) rowstart[base + i] = offset + local[i];
  if (t == 1023) rowstart[8192] = offset + s;
}

__global__ void csr_fill(const int* __restrict__ src, const int* __restrict__ dst,
                         int* __restrict__ cursor, int* __restrict__ csr_src) {
  int e = blockIdx.x * 256 + threadIdx.x;
  int pos = atomicAdd(&cursor[dst[e]], 1);
  csr_src[pos] = src[e];
}

__global__ __launch_bounds__(256) void gcn_agg(
    const int* __restrict__ rowstart, const int* __restrict__ csr_src,
    const float* __restrict__ dinv, const float* __restrict__ h,
    float* __restrict__ c) {
  int node = blockIdx.x * 4 + (threadIdx.x >> 6);
  int lane = threadIdx.x & 63;
  float dn = dinv[node];
  f32x4 acc = *(const f32x4*)(h + (size_t)node * 256 + lane * 4);
  float w0 = dn * dn;
  acc.x *= w0; acc.y *= w0; acc.z *= w0; acc.w *= w0;
  int s0 = rowstart[node], s1 = rowstart[node + 1];
  for (int j = s0; j < s1; j++) {
    int s = csr_src[j];
    float w = dinv[s] * dn;
    f32x4 v = *(const f32x4*)(h + (size_t)s * 256 + lane * 4);
    acc.x += w * v.x; acc.y += w * v.y; acc.z += w * v.z; acc.w += w * v.w;
  }
  *(f32x4*)(c + (size_t)node * 256 + lane * 4) = acc;
}

__global__ void build_cat(const float* __restrict__ cbuf, const float* __restrict__ f,
                          const float* __restrict__ att, unsigned short* __restrict__ cat,
                          int din, int W) {
  int i = blockIdx.y;
  int c = blockIdx.x * 256 + threadIdx.x;
  float v;
  if (c < 256) v = cbuf[(size_t)i * 256 + c];
  else if (c < 256 + din) v = f[(size_t)i * din + (c - 256)];
  else v = f[(size_t)i * din + (c - 256 - din)] - att[(size_t)i * din + (c - 256 - din)];
  cat[(size_t)i * W + c] = f2bf(v);
}

__global__ void gated_pool(const float* __restrict__ q, const float* __restrict__ f,
                           float* __restrict__ p) {
  int col = threadIdx.x;
  int r0 = blockIdx.x * 128;
  float a = 0.f;
  for (int i = r0; i < r0 + 128; i++) {
    float qv = q[(size_t)i * 256 + col];
    a += f[(size_t)i * 256 + col] / (1.f + __expf(-qv));
  }
  atomicAdd(&p[col], a);
}

__global__ void ntn_bilinear(const float* __restrict__ p1, const float* __restrict__ tnW,
                             float* __restrict__ tmp) {
  int c = blockIdx.x * 256 + threadIdx.x;
  float a = 0.f;
#pragma unroll 8
  for (int i = 0; i < 256; i++) a += p1[i] * tnW[(size_t)i * 8192 + c];
  tmp[c] = a;
}

__global__ void ntn_final(const float* __restrict__ tmp, const float* __restrict__ p1,
                          const float* __restrict__ p2, const float* __restrict__ tnWb,
                          const float* __restrict__ tnb, const float* __restrict__ fc1W,
                          const float* __restrict__ fc1b, const float* __restrict__ scW,
                          const float* __restrict__ scb, const float* __restrict__ avgv,
                          float* __restrict__ out) {
  __shared__ float pc[512];
  __shared__ float ntn[32];
  __shared__ float sarr[16];
  int t = threadIdx.x;
  pc[t] = p1[t];
  pc[256 + t] = p2[t];
  __syncthreads();
  if (t < 32) {
    float sc = 0.f;
    for (int j = 0; j < 256; j++) sc += tmp[j * 32 + t] * pc[256 + j];
    float bl = 0.f;
    for (int k = 0; k < 512; k++) bl += tnWb[t * 512 + k] * pc[k];
    float v = sc + bl + tnb[t];
    ntn[t] = v > 0.f ? v : 0.f;
  }
  __syncthreads();
  if (t < 16) {
    float a = fc1b[t];
    for (int i = 0; i < 32; i++) a += ntn[i] * fc1W[i * 16 + t];
    sarr[t] = tanhf(a);
  }
  __syncthreads();
  if (t == 0) {
    float a = scb[0];
    for (int b = 0; b < 16; b++) a += sarr[b] * scW[b];
    float score = 1.f / (1.f + expf(-a));
    out[0] = score;
    out[1] = -logf(score) * avgv[0];
  }
}

// ---------------------------------------------------------------------------

extern "C" void kernel_launch(void* const* d_in, const int* in_sizes, int n_in,
                              void* d_out, int out_size, void* d_ws, size_t ws_size,
                              hipStream_t stream) {
  (void)in_sizes; (void)n_in; (void)out_size;
  const float* feat1 = (const float*)d_in[0];
  const float* feat2 = (const float*)d_in[1];
  const int* ei1 = (const int*)d_in[2];
  const int* ei2 = (const int*)d_in[3];
  const float* avgv = (const float*)d_in[4];
  const float* gcnW[3] = {(const float*)d_in[5], (const float*)d_in[8], (const float*)d_in[11]};
  const float* updW[3] = {(const float*)d_in[6], (const float*)d_in[9], (const float*)d_in[12]};
  const float* updb[3] = {(const float*)d_in[7], (const float*)d_in[10], (const float*)d_in[13]};
  const float* gatedW = (const float*)d_in[14];
  const float* gatedb = (const float*)d_in[15];
  const float* tnW = (const float*)d_in[16];
  const float* tnWb = (const float*)d_in[17];
  const float* tnb = (const float*)d_in[18];
  const float* fc1W = (const float*)d_in[19];
  const float* fc1b = (const float*)d_in[20];
  const float* scW = (const float*)d_in[21];
  const float* scb = (const float*)d_in[22];
  float* out = (float*)d_out;

  char* wp = (char*)d_ws;
  auto take = [&](size_t b) { char* p = wp; wp += (b + 255) & ~(size_t)255; return p; };
  // 32 MB region: flash O-partials (shared by both directions), cat1/cat2 late
  unsigned short* Op = (unsigned short*)take((size_t)NSPLIT * NN * 256 * 2);
  unsigned short* cat1 = Op;
  unsigned short* cat2 = cat1 + (size_t)NN * 768;
  float* fb1 = (float*)take((size_t)NN * 256 * 4);
  float* fb2 = (float*)take((size_t)NN * 256 * 4);
  unsigned short* f1b = (unsigned short*)take((size_t)NN * 256 * 2);
  unsigned short* f2b = (unsigned short*)take((size_t)NN * 256 * 2);
  unsigned short* f1bT = (unsigned short*)take((size_t)NN * 256 * 2);
  unsigned short* f2bT = (unsigned short*)take((size_t)NN * 256 * 2);
  float* h1 = (float*)take((size_t)NN * 256 * 4);   // h, then att1
  float* h2 = (float*)take((size_t)NN * 256 * 4);   // h, then att2
  float* c1 = (float*)take((size_t)NN * 256 * 4);
  float* c2 = (float*)take((size_t)NN * 256 * 4);
  unsigned short* WgT[3], *WuT[3];
  for (int l = 0; l < 3; l++) WgT[l] = (unsigned short*)take(256 * 256 * 2);
  for (int l = 0; l < 3; l++) WuT[l] = (unsigned short*)take(256 * 768 * 2);
  unsigned short* gWT = (unsigned short*)take(256 * 256 * 2);
  int* deg1 = (int*)take(NN * 4);
  int* deg2 = (int*)take(NN * 4);
  float* dinv1 = (float*)take(NN * 4);
  float* dinv2 = (float*)take(NN * 4);
  int* rs1 = (int*)take((NN + 1) * 4);
  int* rs2 = (int*)take((NN + 1) * 4);
  int* cur1 = (int*)take(NN * 4);
  int* cur2 = (int*)take(NN * 4);
  int* csr1 = (int*)take((size_t)EDG * 4);
  int* csr2 = (int*)take((size_t)EDG * 4);
  float* mp = (float*)take((size_t)NSPLIT * NN * 4);
  float* lp = (float*)take((size_t)NSPLIT * NN * 4);
  float* p1 = (float*)take(1024);
  float* p2 = (float*)take(1024);
  float* tmp = (float*)take(NN * 4);

  size_t need = (size_t)(wp - (char*)d_ws);
  if (need > ws_size) {
    ws_sentinel<<<1, 1, 0, stream>>>(out);
    return;
  }

  // degree / dinv / CSR (edge structure is layer-invariant)
  hipMemsetAsync(deg1, 0, NN * 4, stream);
  hipMemsetAsync(deg2, 0, NN * 4, stream);
  deg_count<<<EDG / 256, 256, 0, stream>>>(ei1 + EDG, deg1);
  deg_count<<<EDG / 256, 256, 0, stream>>>(ei2 + EDG, deg2);
  make_dinv<<<NN / 256, 256, 0, stream>>>(deg1, dinv1);
  make_dinv<<<NN / 256, 256, 0, stream>>>(deg2, dinv2);
  scan_deg<<<1, 1024, 0, stream>>>(deg1, rs1);
  scan_deg<<<1, 1024, 0, stream>>>(deg2, rs2);
  hipMemcpyAsync(cur1, rs1, NN * 4, hipMemcpyDeviceToDevice, stream);
  hipMemcpyAsync(cur2, rs2, NN * 4, hipMemcpyDeviceToDevice, stream);
  csr_fill<<<EDG / 256, 256, 0, stream>>>(ei1, ei1 + EDG, cur1, csr1);
  csr_fill<<<EDG / 256, 256, 0, stream>>>(ei2, ei2 + EDG, cur2, csr2);

  // weights -> bf16 [out][in]
  for (int l = 0; l < 3; l++) {
    int din = (l == 0) ? 128 : 256;
    int W = 256 + 2 * din;
    transpose_bf16<<<dim3(8, din / 32), dim3(32, 8), 0, stream>>>(gcnW[l], WgT[l], din, 256);
    transpose_bf16<<<dim3(8, W / 32), dim3(32, 8), 0, stream>>>(updW[l], WuT[l], W, 256);
  }
  transpose_bf16<<<dim3(8, 8), dim3(32, 8), 0, stream>>>(gatedW, gWT, 256, 256);

  const float* f1 = feat1;
  const float* f2 = feat2;

  for (int l = 0; l < 3; l++) {
    const int din = (l == 0) ? 128 : 256;
    const int dshift = (l == 0) ? 7 : 8;
    const int W = 256 + 2 * din;
    const int nel = NN * din;

    cvt_bf16<<<nel / 1024, 256, 0, stream>>>(f1, f1b, nel);
    cvt_bf16<<<nel / 1024, 256, 0, stream>>>(f2, f2b, nel);
    transpose_bf16<<<dim3(din / 32, NN / 32), dim3(32, 8), 0, stream>>>(f1, f1bT, NN, din);
    transpose_bf16<<<dim3(din / 32, NN / 32), dim3(32, 8), 0, stream>>>(f2, f2bT, NN, din);

    // h = f @ Wg
    gemm_k<0><<<dim3(64, 2), 256, 0, stream>>>(f1b, din, WgT[l], din, nullptr, h1, 256, din);
    gemm_k<0><<<dim3(64, 2), 256, 0, stream>>>(f2b, din, WgT[l], din, nullptr, h2, 256, din);

    // c = D^-1/2 (A+I) D^-1/2 h — CSR gather, no atomics
    gcn_agg<<<NN / 4, 256, 0, stream>>>(rs1, csr1, dinv1, h1, c1);
    gcn_agg<<<NN / 4, 256, 0, stream>>>(rs2, csr2, dinv2, h2, c2);

    // att1 = Flash(Q=f1,K=f2,V=f2); att2 = Flash(Q=f2,K=f1,V=f1) — shared Op
    if (l == 0) {
      flash_att<128><<<dim3(NN / 128, NSPLIT), 256, 0, stream>>>(f1b, f2b, f2bT, Op, mp, lp, NN / NSPLIT);
      flash_merge<<<(NN * din / 2) / 256, 256, 0, stream>>>(Op, mp, lp, h1, din, dshift);
      flash_att<128><<<dim3(NN / 128, NSPLIT), 256, 0, stream>>>(f2b, f1b, f1bT, Op, mp, lp, NN / NSPLIT);
      flash_merge<<<(NN * din / 2) / 256, 256, 0, stream>>>(Op, mp, lp, h2, din, dshift);
    } else {
      flash_att<256><<<dim3(NN / 128, NSPLIT), 256, 0, stream>>>(f1b, f2b, f2bT, Op, mp, lp, NN / NSPLIT);
      flash_merge<<<(NN * din / 2) / 256, 256, 0, stream>>>(Op, mp, lp, h1, din, dshift);
      flash_att<256><<<dim3(NN / 128, NSPLIT), 256, 0, stream>>>(f2b, f1b, f1bT, Op, mp, lp, NN / NSPLIT);
      flash_merge<<<(NN * din / 2) / 256, 256, 0, stream>>>(Op, mp, lp, h2, din, dshift);
    }

    // g = tanh?(concat([c, f, f-att]) @ Wu + bu)  (cat overlaps dead Op)
    build_cat<<<dim3(W / 256, NN), 256, 0, stream>>>(c1, f1, h1, cat1, din, W);
    build_cat<<<dim3(W / 256, NN), 256, 0, stream>>>(c2, f2, h2, cat2, din, W);
    if (l < 2) {
      gemm_k<3><<<dim3(64, 2), 256, 0, stream>>>(cat1, W, WuT[l], W, updb[l], fb1, 256, W);
      gemm_k<3><<<dim3(64, 2), 256, 0, stream>>>(cat2, W, WuT[l], W, updb[l], fb2, 256, W);
    } else {
      gemm_k<2><<<dim3(64, 2), 256, 0, stream>>>(cat1, W, WuT[l], W, updb[l], fb1, 256, W);
      gemm_k<2><<<dim3(64, 2), 256, 0, stream>>>(cat2, W, WuT[l], W, updb[l], fb2, 256, W);
    }
    f1 = fb1;
    f2 = fb2;
  }

  // gated readout
  cvt_bf16<<<NN * 256 / 1024, 256, 0, stream>>>(f1, f1b, NN * 256);
  cvt_bf16<<<NN * 256 / 1024, 256, 0, stream>>>(f2, f2b, NN * 256);
  gemm_k<2><<<dim3(64, 2), 256, 0, stream>>>(f1b, 256, gWT, 256, gatedb, c1, 256, 256);
  gemm_k<2><<<dim3(64, 2), 256, 0, stream>>>(f2b, 256, gWT, 256, gatedb, c2, 256, 256);
  hipMemsetAsync(p1, 0, 256 * 4, stream);
  hipMemsetAsync(p2, 0, 256 * 4, stream);
  gated_pool<<<64, 256, 0, stream>>>(c1, f1, p1);
  gated_pool<<<64, 256, 0, stream>>>(c2, f2, p2);

  // NTN + scoring head
  ntn_bilinear<<<32, 256, 0, stream>>>(p1, tnW, tmp);
  ntn_final<<<1, 256, 0, stream>>>(tmp, p1, p2, tnWb, tnb, fc1W, fc1b, scW, scb, avgv, out);
}

// Round 7
// 1568.027 us; speedup vs baseline: 4.3857x; 1.0433x over previous
//
#include <hip/hip_runtime.h>
#include <hip/hip_bf16.h>
#include <stdint.h>

#define NN 8192
#define EDG 131072
#define NSPLIT 8

typedef __attribute__((ext_vector_type(8))) short bf16x8;
typedef __attribute__((ext_vector_type(4))) float f32x4;

__device__ __forceinline__ unsigned short f2bf(float f) {
  union { float f; unsigned u; } v; v.f = f;
  return (unsigned short)((v.u + 0x7fffu + ((v.u >> 16) & 1u)) >> 16);
}

__device__ __forceinline__ unsigned short f2bf_trunc(float f) {
  union { float f; unsigned u; } v; v.f = f;
  return (unsigned short)(v.u >> 16);
}

__device__ __forceinline__ float bf2f(unsigned short u) {
  union { unsigned u; float f; } v; v.u = ((unsigned)u) << 16;
  return v.f;
}

__device__ __forceinline__ void load_lds16(const void* g, void* l) {
  __builtin_amdgcn_global_load_lds(
      (__attribute__((address_space(1))) void*)(uintptr_t)g,
      (__attribute__((address_space(3))) void*)(uintptr_t)l,
      16, 0, 0);
}

// ---------------------------------------------------------------------------
// C[M,N] = A[M,K] * Bt[N,K]^T (+bias, +tanh)   bf16 in, fp32 accum
// EPI 0: store; 2: +bias[col]; 3: tanh(+bias[col])
// ---------------------------------------------------------------------------
template <int EPI>
__global__ __launch_bounds__(256) void gemm_k(
    const unsigned short* __restrict__ A, int lda,
    const unsigned short* __restrict__ Bt, int ldb,
    const float* __restrict__ bias, float* __restrict__ C, int ldc, int K) {
  __shared__ alignas(16) unsigned short As[128 * 32];
  __shared__ alignas(16) unsigned short Bs[128 * 32];
  const int t = threadIdx.x;
  const int wave = t >> 6, lane = t & 63;
  const int wm = (wave >> 1) * 64, wn = (wave & 1) * 64;
  const int lrow = lane & 15, quad = lane >> 4;
  const int rowBase = blockIdx.x * 128;
  const int colBase = blockIdx.y * 128;

  f32x4 acc[4][4];
#pragma unroll
  for (int i = 0; i < 4; i++)
#pragma unroll
    for (int j = 0; j < 4; j++) acc[i][j] = f32x4{0.f, 0.f, 0.f, 0.f};

  const int sr = t >> 2, sch = t & 3;

  for (int kb = 0; kb < K; kb += 32) {
    __syncthreads();
    const unsigned short* bsrc = Bt + (size_t)(colBase + sr) * ldb + kb + sch * 8;
    load_lds16(bsrc, (char*)Bs + t * 16);
    load_lds16(bsrc + (size_t)64 * ldb, (char*)Bs + t * 16 + 4096);
    const unsigned short* asrc = A + (size_t)(rowBase + sr) * lda + kb + sch * 8;
    load_lds16(asrc, (char*)As + t * 16);
    load_lds16(asrc + (size_t)64 * lda, (char*)As + t * 16 + 4096);
    __syncthreads();

    bf16x8 af[4], bfr[4];
#pragma unroll
    for (int i = 0; i < 4; i++)
      af[i] = *(const bf16x8*)&As[(wm + i * 16 + lrow) * 32 + quad * 8];
#pragma unroll
    for (int j = 0; j < 4; j++)
      bfr[j] = *(const bf16x8*)&Bs[(wn + j * 16 + lrow) * 32 + quad * 8];
#pragma unroll
    for (int i = 0; i < 4; i++)
#pragma unroll
      for (int j = 0; j < 4; j++)
        acc[i][j] = __builtin_amdgcn_mfma_f32_16x16x32_bf16(af[i], bfr[j], acc[i][j], 0, 0, 0);
  }

#pragma unroll
  for (int i = 0; i < 4; i++) {
    int row = rowBase + wm + i * 16 + quad * 4;
#pragma unroll
    for (int j = 0; j < 4; j++) {
      int col = colBase + wn + j * 16 + lrow;
#pragma unroll
      for (int r = 0; r < 4; r++) {
        float v = acc[i][j][r];
        size_t idx = (size_t)(row + r) * ldc + col;
        if (EPI == 0) C[idx] = v;
        else {
          v += bias[col];
          if (EPI == 3) v = tanhf(v);
          C[idx] = v;
        }
      }
    }
  }
}

// ---------------------------------------------------------------------------
// Flash attention: persistent-Q LDS, cross-kt K pipelining, swizzled P.
// Q[NN][DIN], K[NN][DIN] bf16; Vt[DIN][NN] bf16. grid=(NN/128, NSPLIT).
// ---------------------------------------------------------------------------
template <int DIN>
__global__ __launch_bounds__(256, 1) void flash_att(
    const unsigned short* __restrict__ Q, const unsigned short* __restrict__ K,
    const unsigned short* __restrict__ Vt, unsigned short* __restrict__ Opart,
    float* __restrict__ mpart, float* __restrict__ lpart, int kvPerSplit) {
  constexpr int NH = DIN / 128;
  constexpr int NKC = DIN / 32;
  __shared__ alignas(16) unsigned short Qs[NKC][128 * 32];  // persistent
  __shared__ alignas(16) unsigned short Bs[2][128 * 32];    // K/V dbuf
  __shared__ alignas(16) unsigned short Ps[128 * 128];
  __shared__ float redM[2][2][128];
  __shared__ float redL[2][2][128];
  const int t = threadIdx.x;
  const int wave = t >> 6, lane = t & 63;
  const int wm = (wave >> 1) * 64, wn = (wave & 1) * 64;
  const int lrow = lane & 15, quad = lane >> 4;
  const int rowBase = blockIdx.x * 128;
  const int split = blockIdx.y;
  const int kv0 = split * kvPerSplit;
  const int sr = t >> 2, sch = t & 3;
  const int pkey = ((lrow >> 2) ^ lrow) & 3;   // P-read swizzle key

  // stage all Q chunks once (chunk-blocked so global_load_lds dest is linear)
#pragma unroll
  for (int kc = 0; kc < NKC; kc++) {
    const unsigned short* qsrc = Q + (size_t)(rowBase + sr) * DIN + kc * 32 + sch * 8;
    load_lds16(qsrc, (char*)&Qs[kc][0] + t * 16);
    load_lds16(qsrc + (size_t)64 * DIN, (char*)&Qs[kc][0] + t * 16 + 4096);
  }
  { // K chunk 0 of first kt
    const unsigned short* ksrc = K + (size_t)(kv0 + sr) * DIN + sch * 8;
    load_lds16(ksrc, (char*)Bs[0] + t * 16);
    load_lds16(ksrc + (size_t)64 * DIN, (char*)Bs[0] + t * 16 + 4096);
  }

  float m_i[16], l_i[16];
#pragma unroll
  for (int x = 0; x < 16; x++) { m_i[x] = -3.0e38f; l_i[x] = 0.f; }
  f32x4 accO[NH][4][4];
#pragma unroll
  for (int h = 0; h < NH; h++)
#pragma unroll
    for (int i = 0; i < 4; i++)
#pragma unroll
      for (int j = 0; j < 4; j++) accO[h][i][j] = f32x4{0.f, 0.f, 0.f, 0.f};

  int ktp = 0;
  for (int kt = kv0; kt < kv0 + kvPerSplit; kt += 128, ktp ^= 1) {
    // ---- Phase 1: S = Q_tile @ K_tile^T (K dbuf, Q persistent) ----
    f32x4 accS[4][4];
#pragma unroll
    for (int i = 0; i < 4; i++)
#pragma unroll
      for (int j = 0; j < 4; j++) accS[i][j] = f32x4{0.f, 0.f, 0.f, 0.f};

    for (int kc = 0; kc < NKC; kc++) {
      const int buf = kc & 1;
      __syncthreads();                              // drain loads for buf
      if (kc + 1 < NKC) {                           // prefetch next K chunk
        const int kb = (kc + 1) * 32;
        const unsigned short* ksrc = K + (size_t)(kt + sr) * DIN + kb + sch * 8;
        load_lds16(ksrc, (char*)Bs[buf ^ 1] + t * 16);
        load_lds16(ksrc + (size_t)64 * DIN, (char*)Bs[buf ^ 1] + t * 16 + 4096);
      }
      bf16x8 af[4], bfr[4];
#pragma unroll
      for (int i = 0; i < 4; i++)
        af[i] = *(const bf16x8*)&Qs[kc][(wm + i * 16 + lrow) * 32 + quad * 8];
#pragma unroll
      for (int j = 0; j < 4; j++)
        bfr[j] = *(const bf16x8*)&Bs[buf][(wn + j * 16 + lrow) * 32 + quad * 8];
#pragma unroll
      for (int i = 0; i < 4; i++)
#pragma unroll
        for (int j = 0; j < 4; j++)
          accS[i][j] = __builtin_amdgcn_mfma_f32_16x16x32_bf16(af[i], bfr[j], accS[i][j], 0, 0, 0);
    }

    // prefetch V chunk 0 into Bs[0] (S last chunk used Bs[1]; Bs[0] reads fenced)
    {
      const unsigned short* vsrc = Vt + (size_t)sr * NN + kt + sch * 8;
      load_lds16(vsrc, (char*)Bs[0] + t * 16);
      load_lds16(vsrc + (size_t)64 * NN, (char*)Bs[0] + t * 16 + 4096);
    }

    // ---- Phase 2: online softmax ----
    float tm[16];
#pragma unroll
    for (int i = 0; i < 4; i++)
#pragma unroll
      for (int r = 0; r < 4; r++)
        tm[i * 4 + r] = fmaxf(fmaxf(accS[i][0][r], accS[i][1][r]),
                              fmaxf(accS[i][2][r], accS[i][3][r]));
#pragma unroll
    for (int mask = 1; mask < 16; mask <<= 1)
#pragma unroll
      for (int x = 0; x < 16; x++) tm[x] = fmaxf(tm[x], __shfl_xor(tm[x], mask));
    if (lrow == 0) {
#pragma unroll
      for (int i = 0; i < 4; i++)
#pragma unroll
        for (int r = 0; r < 4; r++)
          redM[ktp][wave & 1][wm + i * 16 + quad * 4 + r] = tm[i * 4 + r];
    }
    __syncthreads();   // redM visible (also drains V0 — acceptable)
    float alpha[16];
#pragma unroll
    for (int i = 0; i < 4; i++)
#pragma unroll
      for (int r = 0; r < 4; r++) {
        int x = i * 4 + r, row = wm + i * 16 + quad * 4 + r;
        float mt = fmaxf(redM[ktp][0][row], redM[ktp][1][row]);
        float mn = fmaxf(m_i[x], mt);
        alpha[x] = __expf(m_i[x] - mn);
        m_i[x] = mn;
      }
    float ts[16];
#pragma unroll
    for (int x = 0; x < 16; x++) ts[x] = 0.f;
#pragma unroll
    for (int i = 0; i < 4; i++)
#pragma unroll
      for (int j = 0; j < 4; j++)
#pragma unroll
        for (int r = 0; r < 4; r++) {
          int x = i * 4 + r;
          float p = __expf(accS[i][j][r] - m_i[x]);
          ts[x] += p;
          int prow = wm + i * 16 + quad * 4 + r;
          int key = (quad ^ r) & 3;
          int g = (wn + j * 16 + lrow) >> 3;
          Ps[prow * 128 + ((g ^ (key << 1)) << 3) + (lrow & 7)] = f2bf_trunc(p);
        }
#pragma unroll
    for (int mask = 1; mask < 16; mask <<= 1)
#pragma unroll
      for (int x = 0; x < 16; x++) ts[x] += __shfl_xor(ts[x], mask);
    if (lrow == 0) {
#pragma unroll
      for (int i = 0; i < 4; i++)
#pragma unroll
        for (int r = 0; r < 4; r++)
          redL[ktp][wave & 1][wm + i * 16 + quad * 4 + r] = ts[i * 4 + r];
    }
    // rescale O before the barrier (independent of redL)
#pragma unroll
    for (int h = 0; h < NH; h++)
#pragma unroll
      for (int i = 0; i < 4; i++)
#pragma unroll
        for (int j = 0; j < 4; j++)
#pragma unroll
          for (int r = 0; r < 4; r++) accO[h][i][j][r] *= alpha[i * 4 + r];

    // ---- Phase 3: O += P @ V (dbuf over NH*4 chunks; last slot prefetches
    //      next kt's K chunk 0 into Bs[0]) ----
    const bool hasNext = (kt + 128 < kv0 + kvPerSplit);
    for (int cc = 0; cc < NH * 4; cc++) {
      const int buf = cc & 1;
      __syncthreads();   // cc=0: Ps + redL + V0 visible
      if (cc == 0) {
#pragma unroll
        for (int i = 0; i < 4; i++)
#pragma unroll
          for (int r = 0; r < 4; r++) {
            int x = i * 4 + r, row = wm + i * 16 + quad * 4 + r;
            l_i[x] = l_i[x] * alpha[x] + redL[ktp][0][row] + redL[ktp][1][row];
          }
      }
      if (cc + 1 < NH * 4) {
        const int h2 = (cc + 1) >> 2, kbc2 = (cc + 1) & 3;
        const unsigned short* vsrc =
            Vt + (size_t)(h2 * 128 + sr) * NN + kt + kbc2 * 32 + sch * 8;
        load_lds16(vsrc, (char*)Bs[buf ^ 1] + t * 16);
        load_lds16(vsrc + (size_t)64 * NN, (char*)Bs[buf ^ 1] + t * 16 + 4096);
      } else if (hasNext) {  // buf==1 here (NH*4-1 odd) -> target Bs[0]
        const unsigned short* ksrc = K + (size_t)(kt + 128 + sr) * DIN + sch * 8;
        load_lds16(ksrc, (char*)Bs[buf ^ 1] + t * 16);
        load_lds16(ksrc + (size_t)64 * DIN, (char*)Bs[buf ^ 1] + t * 16 + 4096);
      }
      const int h = cc >> 2, kbc = cc & 3;
      bf16x8 af[4], bfr[4];
#pragma unroll
      for (int i = 0; i < 4; i++) {
        int g = kbc * 4 + quad;
        af[i] = *(const bf16x8*)&Ps[(wm + i * 16 + lrow) * 128 + ((g ^ (pkey << 1)) << 3)];
      }
#pragma unroll
      for (int j = 0; j < 4; j++)
        bfr[j] = *(const bf16x8*)&Bs[buf][(wn + j * 16 + lrow) * 32 + quad * 8];
#pragma unroll
      for (int i = 0; i < 4; i++)
#pragma unroll
        for (int j = 0; j < 4; j++)
          accO[h][i][j] = __builtin_amdgcn_mfma_f32_16x16x32_bf16(af[i], bfr[j], accO[h][i][j], 0, 0, 0);
    }
  }

  // ---- epilogue: un-normalized partials ----
#pragma unroll
  for (int h = 0; h < NH; h++)
#pragma unroll
    for (int i = 0; i < 4; i++)
#pragma unroll
      for (int j = 0; j < 4; j++)
#pragma unroll
        for (int r = 0; r < 4; r++) {
          int row = rowBase + wm + i * 16 + quad * 4 + r;
          int col = h * 128 + wn + j * 16 + lrow;
          Opart[((size_t)split * NN + row) * DIN + col] = f2bf(accO[h][i][j][r]);
        }
  if (lrow == 0) {
#pragma unroll
    for (int i = 0; i < 4; i++)
#pragma unroll
      for (int r = 0; r < 4; r++) {
        int row = rowBase + wm + i * 16 + quad * 4 + r;
        mpart[(size_t)split * NN + row] = m_i[i * 4 + r];
        lpart[(size_t)split * NN + row] = l_i[i * 4 + r];
      }
  }
}

// combine NSPLIT flash partials
__global__ void flash_merge(const unsigned short* __restrict__ Op, const float* __restrict__ mp,
                            const float* __restrict__ lp, float* __restrict__ att,
                            int din, int dshift) {
  int idx = blockIdx.x * 256 + threadIdx.x;
  int pair = idx * 2;
  int row = pair >> dshift;
  int f = pair & (din - 1);
  float m[NSPLIT], w[NSPLIT];
  float M = -3.0e38f;
#pragma unroll
  for (int s = 0; s < NSPLIT; s++) { m[s] = mp[(size_t)s * NN + row]; M = fmaxf(M, m[s]); }
  float L = 0.f;
#pragma unroll
  for (int s = 0; s < NSPLIT; s++) { w[s] = __expf(m[s] - M); L += lp[(size_t)s * NN + row] * w[s]; }
  float inv = 1.f / L;
  size_t base = (size_t)row * din + f;
  size_t stride = (size_t)NN * din;
  float a0 = 0.f, a1 = 0.f;
#pragma unroll
  for (int s = 0; s < NSPLIT; s++) {
    unsigned u = *(const unsigned*)(Op + (size_t)s * stride + base);
    a0 += w[s] * bf2f(u & 0xffffu);
    a1 += w[s] * bf2f(u >> 16);
  }
  float2 o; o.x = a0 * inv; o.y = a1 * inv;
  *(float2*)(att + base) = o;
}

// --------------------------- small kernels ---------------------------------

__global__ void ws_sentinel(float* out) { out[0] = 12345.0f; out[1] = 12345.0f; }

__global__ void cvt_bf16(const float* __restrict__ in, unsigned short* __restrict__ out, int n) {
  int i = (blockIdx.x * 256 + threadIdx.x) * 4;
  if (i < n) {
    f32x4 v = *(const f32x4*)(in + i);
    uint2 p;
    p.x = f2bf(v.x) | ((unsigned)f2bf(v.y) << 16);
    p.y = f2bf(v.z) | ((unsigned)f2bf(v.w) << 16);
    *(uint2*)(out + i) = p;
  }
}

__global__ void transpose_bf16(const float* __restrict__ src, unsigned short* __restrict__ dst,
                               int R, int C) {
  __shared__ float tile[32][33];
  int c0 = blockIdx.x * 32, r0 = blockIdx.y * 32;
  int x = threadIdx.x, y = threadIdx.y;
  for (int i = y; i < 32; i += 8) tile[i][x] = src[(size_t)(r0 + i) * C + c0 + x];
  __syncthreads();
  for (int i = y; i < 32; i += 8) dst[(size_t)(c0 + i) * R + r0 + x] = f2bf(tile[x][i]);
}

__global__ void deg_count(const int* __restrict__ dst, int* __restrict__ deg) {
  int e = blockIdx.x * 256 + threadIdx.x;
  atomicAdd(&deg[dst[e]], 1);
}

__global__ void make_dinv(const int* __restrict__ deg, float* __restrict__ dinv) {
  int v = blockIdx.x * 256 + threadIdx.x;
  dinv[v] = rsqrtf((float)(deg[v] + 1));
}

__global__ void scan_deg(const int* __restrict__ deg, int* __restrict__ rowstart) {
  __shared__ int part[1024];
  int t = threadIdx.x;
  int base = t * 8;
  int local[8];
  int s = 0;
#pragma unroll
  for (int i = 0; i < 8; i++) { local[i] = s; s += deg[base + i]; }
  part[t] = s;
  __syncthreads();
  for (int off = 1; off < 1024; off <<= 1) {
    int v = (t >= off) ? part[t - off] : 0;
    __syncthreads();
    part[t] += v;
    __syncthreads();
  }
  int offset = (t == 0) ? 0 : part[t - 1];
#pragma unroll
  for (int i = 0; i < 8; i++) rowstart[base + i] = offset + local[i];
  if (t == 1023) rowstart[8192] = offset + s;
}

__global__ void csr_fill(const int* __restrict__ src, const int* __restrict__ dst,
                         int* __restrict__ cursor, int* __restrict__ csr_src) {
  int e = blockIdx.x * 256 + threadIdx.x;
  int pos = atomicAdd(&cursor[dst[e]], 1);
  csr_src[pos] = src[e];
}

__global__ __launch_bounds__(256) void gcn_agg(
    const int* __restrict__ rowstart, const int* __restrict__ csr_src,
    const float* __restrict__ dinv, const float* __restrict__ h,
    float* __restrict__ c) {
  int node = blockIdx.x * 4 + (threadIdx.x >> 6);
  int lane = threadIdx.x & 63;
  float dn = dinv[node];
  f32x4 acc = *(const f32x4*)(h + (size_t)node * 256 + lane * 4);
  float w0 = dn * dn;
  acc.x *= w0; acc.y *= w0; acc.z *= w0; acc.w *= w0;
  int s0 = rowstart[node], s1 = rowstart[node + 1];
  for (int j = s0; j < s1; j++) {
    int s = csr_src[j];
    float w = dinv[s] * dn;
    f32x4 v = *(const f32x4*)(h + (size_t)s * 256 + lane * 4);
    acc.x += w * v.x; acc.y += w * v.y; acc.z += w * v.z; acc.w += w * v.w;
  }
  *(f32x4*)(c + (size_t)node * 256 + lane * 4) = acc;
}

__global__ void build_cat(const float* __restrict__ cbuf, const float* __restrict__ f,
                          const float* __restrict__ att, unsigned short* __restrict__ cat,
                          int din, int W) {
  int i = blockIdx.y;
  int c = blockIdx.x * 256 + threadIdx.x;
  float v;
  if (c < 256) v = cbuf[(size_t)i * 256 + c];
  else if (c < 256 + din) v = f[(size_t)i * din + (c - 256)];
  else v = f[(size_t)i * din + (c - 256 - din)] - att[(size_t)i * din + (c - 256 - din)];
  cat[(size_t)i * W + c] = f2bf(v);
}

__global__ void gated_pool(const float* __restrict__ q, const float* __restrict__ f,
                           float* __restrict__ p) {
  int col = threadIdx.x;
  int r0 = blockIdx.x * 128;
  float a = 0.f;
  for (int i = r0; i < r0 + 128; i++) {
    float qv = q[(size_t)i * 256 + col];
    a += f[(size_t)i * 256 + col] / (1.f + __expf(-qv));
  }
  atomicAdd(&p[col], a);
}

__global__ void ntn_bilinear(const float* __restrict__ p1, const float* __restrict__ tnW,
                             float* __restrict__ tmp) {
  int c = blockIdx.x * 256 + threadIdx.x;
  float a = 0.f;
#pragma unroll 8
  for (int i = 0; i < 256; i++) a += p1[i] * tnW[(size_t)i * 8192 + c];
  tmp[c] = a;
}

__global__ void ntn_final(const float* __restrict__ tmp, const float* __restrict__ p1,
                          const float* __restrict__ p2, const float* __restrict__ tnWb,
                          const float* __restrict__ tnb, const float* __restrict__ fc1W,
                          const float* __restrict__ fc1b, const float* __restrict__ scW,
                          const float* __restrict__ scb, const float* __restrict__ avgv,
                          float* __restrict__ out) {
  __shared__ float pc[512];
  __shared__ float ntn[32];
  __shared__ float sarr[16];
  int t = threadIdx.x;
  pc[t] = p1[t];
  pc[256 + t] = p2[t];
  __syncthreads();
  if (t < 32) {
    float sc = 0.f;
    for (int j = 0; j < 256; j++) sc += tmp[j * 32 + t] * pc[256 + j];
    float bl = 0.f;
    for (int k = 0; k < 512; k++) bl += tnWb[t * 512 + k] * pc[k];
    float v = sc + bl + tnb[t];
    ntn[t] = v > 0.f ? v : 0.f;
  }
  __syncthreads();
  if (t < 16) {
    float a = fc1b[t];
    for (int i = 0; i < 32; i++) a += ntn[i] * fc1W[i * 16 + t];
    sarr[t] = tanhf(a);
  }
  __syncthreads();
  if (t == 0) {
    float a = scb[0];
    for (int b = 0; b < 16; b++) a += sarr[b] * scW[b];
    float score = 1.f / (1.f + expf(-a));
    out[0] = score;
    out[1] = -logf(score) * avgv[0];
  }
}

// ---------------------------------------------------------------------------

extern "C" void kernel_launch(void* const* d_in, const int* in_sizes, int n_in,
                              void* d_out, int out_size, void* d_ws, size_t ws_size,
                              hipStream_t stream) {
  (void)in_sizes; (void)n_in; (void)out_size;
  const float* feat1 = (const float*)d_in[0];
  const float* feat2 = (const float*)d_in[1];
  const int* ei1 = (const int*)d_in[2];
  const int* ei2 = (const int*)d_in[3];
  const float* avgv = (const float*)d_in[4];
  const float* gcnW[3] = {(const float*)d_in[5], (const float*)d_in[8], (const float*)d_in[11]};
  const float* updW[3] = {(const float*)d_in[6], (const float*)d_in[9], (const float*)d_in[12]};
  const float* updb[3] = {(const float*)d_in[7], (const float*)d_in[10], (const float*)d_in[13]};
  const float* gatedW = (const float*)d_in[14];
  const float* gatedb = (const float*)d_in[15];
  const float* tnW = (const float*)d_in[16];
  const float* tnWb = (const float*)d_in[17];
  const float* tnb = (const float*)d_in[18];
  const float* fc1W = (const float*)d_in[19];
  const float* fc1b = (const float*)d_in[20];
  const float* scW = (const float*)d_in[21];
  const float* scb = (const float*)d_in[22];
  float* out = (float*)d_out;

  char* wp = (char*)d_ws;
  auto take = [&](size_t b) { char* p = wp; wp += (b + 255) & ~(size_t)255; return p; };
  unsigned short* Op = (unsigned short*)take((size_t)NSPLIT * NN * 256 * 2);
  unsigned short* cat1 = Op;
  unsigned short* cat2 = cat1 + (size_t)NN * 768;
  float* fb1 = (float*)take((size_t)NN * 256 * 4);
  float* fb2 = (float*)take((size_t)NN * 256 * 4);
  unsigned short* f1b = (unsigned short*)take((size_t)NN * 256 * 2);
  unsigned short* f2b = (unsigned short*)take((size_t)NN * 256 * 2);
  unsigned short* f1bT = (unsigned short*)take((size_t)NN * 256 * 2);
  unsigned short* f2bT = (unsigned short*)take((size_t)NN * 256 * 2);
  float* h1 = (float*)take((size_t)NN * 256 * 4);
  float* h2 = (float*)take((size_t)NN * 256 * 4);
  float* c1 = (float*)take((size_t)NN * 256 * 4);
  float* c2 = (float*)take((size_t)NN * 256 * 4);
  unsigned short* WgT[3], *WuT[3];
  for (int l = 0; l < 3; l++) WgT[l] = (unsigned short*)take(256 * 256 * 2);
  for (int l = 0; l < 3; l++) WuT[l] = (unsigned short*)take(256 * 768 * 2);
  unsigned short* gWT = (unsigned short*)take(256 * 256 * 2);
  int* deg1 = (int*)take(NN * 4);
  int* deg2 = (int*)take(NN * 4);
  float* dinv1 = (float*)take(NN * 4);
  float* dinv2 = (float*)take(NN * 4);
  int* rs1 = (int*)take((NN + 1) * 4);
  int* rs2 = (int*)take((NN + 1) * 4);
  int* cur1 = (int*)take(NN * 4);
  int* cur2 = (int*)take(NN * 4);
  int* csr1 = (int*)take((size_t)EDG * 4);
  int* csr2 = (int*)take((size_t)EDG * 4);
  float* mp = (float*)take((size_t)NSPLIT * NN * 4);
  float* lp = (float*)take((size_t)NSPLIT * NN * 4);
  float* p1 = (float*)take(1024);
  float* p2 = (float*)take(1024);
  float* tmp = (float*)take(NN * 4);

  size_t need = (size_t)(wp - (char*)d_ws);
  if (need > ws_size) {
    ws_sentinel<<<1, 1, 0, stream>>>(out);
    return;
  }

  // degree / dinv / CSR (edge structure is layer-invariant)
  hipMemsetAsync(deg1, 0, NN * 4, stream);
  hipMemsetAsync(deg2, 0, NN * 4, stream);
  deg_count<<<EDG / 256, 256, 0, stream>>>(ei1 + EDG, deg1);
  deg_count<<<EDG / 256, 256, 0, stream>>>(ei2 + EDG, deg2);
  make_dinv<<<NN / 256, 256, 0, stream>>>(deg1, dinv1);
  make_dinv<<<NN / 256, 256, 0, stream>>>(deg2, dinv2);
  scan_deg<<<1, 1024, 0, stream>>>(deg1, rs1);
  scan_deg<<<1, 1024, 0, stream>>>(deg2, rs2);
  hipMemcpyAsync(cur1, rs1, NN * 4, hipMemcpyDeviceToDevice, stream);
  hipMemcpyAsync(cur2, rs2, NN * 4, hipMemcpyDeviceToDevice, stream);
  csr_fill<<<EDG / 256, 256, 0, stream>>>(ei1, ei1 + EDG, cur1, csr1);
  csr_fill<<<EDG / 256, 256, 0, stream>>>(ei2, ei2 + EDG, cur2, csr2);

  // weights -> bf16 [out][in]
  for (int l = 0; l < 3; l++) {
    int din = (l == 0) ? 128 : 256;
    int W = 256 + 2 * din;
    transpose_bf16<<<dim3(8, din / 32), dim3(32, 8), 0, stream>>>(gcnW[l], WgT[l], din, 256);
    transpose_bf16<<<dim3(8, W / 32), dim3(32, 8), 0, stream>>>(updW[l], WuT[l], W, 256);
  }
  transpose_bf16<<<dim3(8, 8), dim3(32, 8), 0, stream>>>(gatedW, gWT, 256, 256);

  const float* f1 = feat1;
  const float* f2 = feat2;

  for (int l = 0; l < 3; l++) {
    const int din = (l == 0) ? 128 : 256;
    const int dshift = (l == 0) ? 7 : 8;
    const int W = 256 + 2 * din;
    const int nel = NN * din;

    cvt_bf16<<<nel / 1024, 256, 0, stream>>>(f1, f1b, nel);
    cvt_bf16<<<nel / 1024, 256, 0, stream>>>(f2, f2b, nel);
    transpose_bf16<<<dim3(din / 32, NN / 32), dim3(32, 8), 0, stream>>>(f1, f1bT, NN, din);
    transpose_bf16<<<dim3(din / 32, NN / 32), dim3(32, 8), 0, stream>>>(f2, f2bT, NN, din);

    // h = f @ Wg
    gemm_k<0><<<dim3(64, 2), 256, 0, stream>>>(f1b, din, WgT[l], din, nullptr, h1, 256, din);
    gemm_k<0><<<dim3(64, 2), 256, 0, stream>>>(f2b, din, WgT[l], din, nullptr, h2, 256, din);

    // c = D^-1/2 (A+I) D^-1/2 h — CSR gather, no atomics
    gcn_agg<<<NN / 4, 256, 0, stream>>>(rs1, csr1, dinv1, h1, c1);
    gcn_agg<<<NN / 4, 256, 0, stream>>>(rs2, csr2, dinv2, h2, c2);

    // att1 = Flash(Q=f1,K=f2,V=f2); att2 = Flash(Q=f2,K=f1,V=f1) — shared Op
    if (l == 0) {
      flash_att<128><<<dim3(NN / 128, NSPLIT), 256, 0, stream>>>(f1b, f2b, f2bT, Op, mp, lp, NN / NSPLIT);
      flash_merge<<<(NN * din / 2) / 256, 256, 0, stream>>>(Op, mp, lp, h1, din, dshift);
      flash_att<128><<<dim3(NN / 128, NSPLIT), 256, 0, stream>>>(f2b, f1b, f1bT, Op, mp, lp, NN / NSPLIT);
      flash_merge<<<(NN * din / 2) / 256, 256, 0, stream>>>(Op, mp, lp, h2, din, dshift);
    } else {
      flash_att<256><<<dim3(NN / 128, NSPLIT), 256, 0, stream>>>(f1b, f2b, f2bT, Op, mp, lp, NN / NSPLIT);
      flash_merge<<<(NN * din / 2) / 256, 256, 0, stream>>>(Op, mp, lp, h1, din, dshift);
      flash_att<256><<<dim3(NN / 128, NSPLIT), 256, 0, stream>>>(f2b, f1b, f1bT, Op, mp, lp, NN / NSPLIT);
      flash_merge<<<(NN * din / 2) / 256, 256, 0, stream>>>(Op, mp, lp, h2, din, dshift);
    }

    // g = tanh?(concat([c, f, f-att]) @ Wu + bu)  (cat overlaps dead Op)
    build_cat<<<dim3(W / 256, NN), 256, 0, stream>>>(c1, f1, h1, cat1, din, W);
    build_cat<<<dim3(W / 256, NN), 256, 0, stream>>>(c2, f2, h2, cat2, din, W);
    if (l < 2) {
      gemm_k<3><<<dim3(64, 2), 256, 0, stream>>>(cat1, W, WuT[l], W, updb[l], fb1, 256, W);
      gemm_k<3><<<dim3(64, 2), 256, 0, stream>>>(cat2, W, WuT[l], W, updb[l], fb2, 256, W);
    } else {
      gemm_k<2><<<dim3(64, 2), 256, 0, stream>>>(cat1, W, WuT[l], W, updb[l], fb1, 256, W);
      gemm_k<2><<<dim3(64, 2), 256, 0, stream>>>(cat2, W, WuT[l], W, updb[l], fb2, 256, W);
    }
    f1 = fb1;
    f2 = fb2;
  }

  // gated readout
  cvt_bf16<<<NN * 256 / 1024, 256, 0, stream>>>(f1, f1b, NN * 256);
  cvt_bf16<<<NN * 256 / 1024, 256, 0, stream>>>(f2, f2b, NN * 256);
  gemm_k<2><<<dim3(64, 2), 256, 0, stream>>>(f1b, 256, gWT, 256, gatedb, c1, 256, 256);
  gemm_k<2><<<dim3(64, 2), 256, 0, stream>>>(f2b, 256, gWT, 256, gatedb, c2, 256, 256);
  hipMemsetAsync(p1, 0, 256 * 4, stream);
  hipMemsetAsync(p2, 0, 256 * 4, stream);
  gated_pool<<<64, 256, 0, stream>>>(c1, f1, p1);
  gated_pool<<<64, 256, 0, stream>>>(c2, f2, p2);

  // NTN + scoring head
  ntn_bilinear<<<32, 256, 0, stream>>>(p1, tnW, tmp);
  ntn_final<<<1, 256, 0, stream>>>(tmp, p1, p2, tnWb, tnb, fc1W, fc1b, scW, scb, avgv, out);
}

// Round 8
// 1426.253 us; speedup vs baseline: 4.8216x; 1.0994x over previous
//
#include <hip/hip_runtime.h>
#include <hip/hip_bf16.h>
#include <stdint.h>

#define NN 8192
#define EDG 131072
#define NSPLIT 8

typedef __attribute__((ext_vector_type(8))) short bf16x8;
typedef __attribute__((ext_vector_type(4))) float f32x4;

__device__ __forceinline__ unsigned short f2bf(float f) {
  union { float f; unsigned u; } v; v.f = f;
  return (unsigned short)((v.u + 0x7fffu + ((v.u >> 16) & 1u)) >> 16);
}

__device__ __forceinline__ unsigned short f2bf_trunc(float f) {
  union { float f; unsigned u; } v; v.f = f;
  return (unsigned short)(v.u >> 16);
}

__device__ __forceinline__ float bf2f(unsigned short u) {
  union { unsigned u; float f; } v; v.u = ((unsigned)u) << 16;
  return v.f;
}

__device__ __forceinline__ void load_lds16(const void* g, void* l) {
  __builtin_amdgcn_global_load_lds(
      (__attribute__((address_space(1))) void*)(uintptr_t)g,
      (__attribute__((address_space(3))) void*)(uintptr_t)l,
      16, 0, 0);
}

// ---------------------------------------------------------------------------
// C[M,N] = A[M,K] * Bt[N,K]^T (+bias, +tanh)   bf16 in, fp32 accum
// EPI 0: store; 2: +bias[col]; 3: tanh(+bias[col])
// ---------------------------------------------------------------------------
template <int EPI>
__global__ __launch_bounds__(256) void gemm_k(
    const unsigned short* __restrict__ A, int lda,
    const unsigned short* __restrict__ Bt, int ldb,
    const float* __restrict__ bias, float* __restrict__ C, int ldc, int K) {
  __shared__ alignas(16) unsigned short As[128 * 32];
  __shared__ alignas(16) unsigned short Bs[128 * 32];
  const int t = threadIdx.x;
  const int wave = t >> 6, lane = t & 63;
  const int wm = (wave >> 1) * 64, wn = (wave & 1) * 64;
  const int lrow = lane & 15, quad = lane >> 4;
  const int rowBase = blockIdx.x * 128;
  const int colBase = blockIdx.y * 128;

  f32x4 acc[4][4];
#pragma unroll
  for (int i = 0; i < 4; i++)
#pragma unroll
    for (int j = 0; j < 4; j++) acc[i][j] = f32x4{0.f, 0.f, 0.f, 0.f};

  const int sr = t >> 2, sch = t & 3;

  for (int kb = 0; kb < K; kb += 32) {
    __syncthreads();
    const unsigned short* bsrc = Bt + (size_t)(colBase + sr) * ldb + kb + sch * 8;
    load_lds16(bsrc, (char*)Bs + t * 16);
    load_lds16(bsrc + (size_t)64 * ldb, (char*)Bs + t * 16 + 4096);
    const unsigned short* asrc = A + (size_t)(rowBase + sr) * lda + kb + sch * 8;
    load_lds16(asrc, (char*)As + t * 16);
    load_lds16(asrc + (size_t)64 * lda, (char*)As + t * 16 + 4096);
    __syncthreads();

    bf16x8 af[4], bfr[4];
#pragma unroll
    for (int i = 0; i < 4; i++)
      af[i] = *(const bf16x8*)&As[(wm + i * 16 + lrow) * 32 + quad * 8];
#pragma unroll
    for (int j = 0; j < 4; j++)
      bfr[j] = *(const bf16x8*)&Bs[(wn + j * 16 + lrow) * 32 + quad * 8];
#pragma unroll
    for (int i = 0; i < 4; i++)
#pragma unroll
      for (int j = 0; j < 4; j++)
        acc[i][j] = __builtin_amdgcn_mfma_f32_16x16x32_bf16(af[i], bfr[j], acc[i][j], 0, 0, 0);
  }

#pragma unroll
  for (int i = 0; i < 4; i++) {
    int row = rowBase + wm + i * 16 + quad * 4;
#pragma unroll
    for (int j = 0; j < 4; j++) {
      int col = colBase + wn + j * 16 + lrow;
#pragma unroll
      for (int r = 0; r < 4; r++) {
        float v = acc[i][j][r];
        size_t idx = (size_t)(row + r) * ldc + col;
        if (EPI == 0) C[idx] = v;
        else {
          v += bias[col];
          if (EPI == 3) v = tanhf(v);
          C[idx] = v;
        }
      }
    }
  }
}

// ---------------------------------------------------------------------------
// Flash attention, register-lean 64-row Q tile for 2 blocks/CU.
// Q[NN][DIN], K[NN][DIN] bf16; Vt[DIN][NN] bf16. grid=(NN/64, NSPLIT).
// Block: 64 Q-rows x 128 KV-cols per kt step. Waves 2x2:
//   S phase: wave covers 32 rows x 64 cols; PV: 32 rows x DIN/2 cols.
// R1 (16 KB) holds the K double-buffer during S, then aliases Ps (64x128).
// Vs single-buffered (DIN x 32). Q persistent in LDS.
// ---------------------------------------------------------------------------
template <int DIN>
__global__ __launch_bounds__(256, 2) void flash_att(
    const unsigned short* __restrict__ Q, const unsigned short* __restrict__ K,
    const unsigned short* __restrict__ Vt, unsigned short* __restrict__ Opart,
    float* __restrict__ mpart, float* __restrict__ lpart, int kvPerSplit) {
  constexpr int NKC = DIN / 32;   // S-phase k chunks
  constexpr int OJ = DIN / 32;    // O col-tiles per wave (DIN/2 cols / 16)
  __shared__ alignas(16) unsigned short Qs[NKC][64 * 32];   // persistent Q
  __shared__ alignas(16) unsigned short R1[2][128 * 32];    // K dbuf; Ps alias
  __shared__ alignas(16) unsigned short Vs[DIN * 32];       // V single buffer
  __shared__ float redM[2][64];
  __shared__ float redL[2][64];
  unsigned short* Ps = &R1[0][0];                           // 64*128 bf16

  const int t = threadIdx.x;
  const int wave = t >> 6, lane = t & 63;
  const int wrow = (wave >> 1) * 32;          // S/O row base (within 64)
  const int wcol = (wave & 1) * 64;           // S col base (within 128)
  const int wcolO = (wave & 1) * (DIN / 2);   // O col base
  const int lrow = lane & 15, quad = lane >> 4;
  const int rowBase = blockIdx.x * 64;
  const int split = blockIdx.y;
  const int kv0 = split * kvPerSplit;
  const int sr = t >> 2, sch = t & 3;
  const int pkey = ((lrow >> 2) ^ lrow) & 3;  // P-read swizzle key
  const int ch = wave & 1;                    // col-half for reductions

  // stage all Q chunks once (chunk-blocked: 64x32 per chunk, 16B per thread)
#pragma unroll
  for (int kc = 0; kc < NKC; kc++) {
    const unsigned short* qsrc = Q + (size_t)(rowBase + sr) * DIN + kc * 32 + sch * 8;
    load_lds16(qsrc, (char*)&Qs[kc][0] + t * 16);
  }

  float m_i[8], l_i[8];   // x = i*4 + r ; row(within 64) = wrow + i*16 + quad*4 + r
#pragma unroll
  for (int x = 0; x < 8; x++) { m_i[x] = -3.0e38f; l_i[x] = 0.f; }
  f32x4 accO[2][OJ];
#pragma unroll
  for (int i = 0; i < 2; i++)
#pragma unroll
    for (int j = 0; j < OJ; j++) accO[i][j] = f32x4{0.f, 0.f, 0.f, 0.f};

  for (int kt = kv0; kt < kv0 + kvPerSplit; kt += 128) {
    // protect R1 (prev kt's Ps still being read until all waves arrive)
    __syncthreads();
    { // K chunk 0 -> R1[0]  (128 kv-rows x 32 k)
      const unsigned short* ksrc = K + (size_t)(kt + sr) * DIN + sch * 8;
      load_lds16(ksrc, (char*)&R1[0][0] + t * 16);
      load_lds16(ksrc + (size_t)64 * DIN, (char*)&R1[0][0] + t * 16 + 4096);
    }

    // ---- Phase 1: S = Q_tile @ K_tile^T ----
    f32x4 accS[2][4];
#pragma unroll
    for (int i = 0; i < 2; i++)
#pragma unroll
      for (int j = 0; j < 4; j++) accS[i][j] = f32x4{0.f, 0.f, 0.f, 0.f};

    for (int kc = 0; kc < NKC; kc++) {
      const int buf = kc & 1;
      __syncthreads();                       // drain K[kc]
      if (kc + 1 < NKC) {                    // prefetch next K chunk
        const unsigned short* ksrc =
            K + (size_t)(kt + sr) * DIN + (kc + 1) * 32 + sch * 8;
        load_lds16(ksrc, (char*)&R1[buf ^ 1][0] + t * 16);
        load_lds16(ksrc + (size_t)64 * DIN, (char*)&R1[buf ^ 1][0] + t * 16 + 4096);
      }
      bf16x8 af[2], bfr[4];
#pragma unroll
      for (int i = 0; i < 2; i++)
        af[i] = *(const bf16x8*)&Qs[kc][(wrow + i * 16 + lrow) * 32 + quad * 8];
#pragma unroll
      for (int j = 0; j < 4; j++)
        bfr[j] = *(const bf16x8*)&R1[buf][(wcol + j * 16 + lrow) * 32 + quad * 8];
#pragma unroll
      for (int i = 0; i < 2; i++)
#pragma unroll
        for (int j = 0; j < 4; j++)
          accS[i][j] = __builtin_amdgcn_mfma_f32_16x16x32_bf16(af[i], bfr[j], accS[i][j], 0, 0, 0);
    }

    // prefetch V chunk 0 into Vs (overlaps softmax; drained at B2)
#pragma unroll
    for (int p = 0; p < DIN / 64; p++) {
      const unsigned short* vsrc = Vt + (size_t)(p * 64 + sr) * NN + kt + sch * 8;
      load_lds16(vsrc, (char*)Vs + p * 4096 + t * 16);
    }

    // ---- Phase 2: online softmax ----
    float tm[8];
#pragma unroll
    for (int i = 0; i < 2; i++)
#pragma unroll
      for (int r = 0; r < 4; r++)
        tm[i * 4 + r] = fmaxf(fmaxf(accS[i][0][r], accS[i][1][r]),
                              fmaxf(accS[i][2][r], accS[i][3][r]));
#pragma unroll
    for (int mask = 1; mask < 16; mask <<= 1)
#pragma unroll
      for (int x = 0; x < 8; x++) tm[x] = fmaxf(tm[x], __shfl_xor(tm[x], mask));
    if (lrow == 0) {
#pragma unroll
      for (int i = 0; i < 2; i++)
#pragma unroll
        for (int r = 0; r < 4; r++)
          redM[ch][wrow + i * 16 + quad * 4 + r] = tm[i * 4 + r];
    }
    __syncthreads();   // B1: redM visible; all S MFMAs done -> Ps writes safe
    float alpha[8];
#pragma unroll
    for (int i = 0; i < 2; i++)
#pragma unroll
      for (int r = 0; r < 4; r++) {
        int x = i * 4 + r, row = wrow + i * 16 + quad * 4 + r;
        float mt = fmaxf(redM[0][row], redM[1][row]);
        float mn = fmaxf(m_i[x], mt);
        alpha[x] = __expf(m_i[x] - mn);
        m_i[x] = mn;
      }
    float ts[8];
#pragma unroll
    for (int x = 0; x < 8; x++) ts[x] = 0.f;
#pragma unroll
    for (int i = 0; i < 2; i++)
#pragma unroll
      for (int j = 0; j < 4; j++)
#pragma unroll
        for (int r = 0; r < 4; r++) {
          int x = i * 4 + r;
          float p = __expf(accS[i][j][r] - m_i[x]);
          ts[x] += p;
          int prow = wrow + i * 16 + quad * 4 + r;
          int key = (quad ^ r) & 3;
          int g = (wcol + j * 16 + lrow) >> 3;
          Ps[prow * 128 + ((g ^ (key << 1)) << 3) + (lrow & 7)] = f2bf_trunc(p);
        }
#pragma unroll
    for (int mask = 1; mask < 16; mask <<= 1)
#pragma unroll
      for (int x = 0; x < 8; x++) ts[x] += __shfl_xor(ts[x], mask);
    if (lrow == 0) {
#pragma unroll
      for (int i = 0; i < 2; i++)
#pragma unroll
        for (int r = 0; r < 4; r++)
          redL[ch][wrow + i * 16 + quad * 4 + r] = ts[i * 4 + r];
    }
    // rescale O while redL propagates
#pragma unroll
    for (int i = 0; i < 2; i++)
#pragma unroll
      for (int j = 0; j < OJ; j++)
#pragma unroll
        for (int r = 0; r < 4; r++) accO[i][j][r] *= alpha[i * 4 + r];
    __syncthreads();   // B2: Ps + redL + V0 drained
#pragma unroll
    for (int i = 0; i < 2; i++)
#pragma unroll
      for (int r = 0; r < 4; r++) {
        int x = i * 4 + r, row = wrow + i * 16 + quad * 4 + r;
        l_i[x] = l_i[x] * alpha[x] + redL[0][row] + redL[1][row];
      }

    // ---- Phase 3: O += P @ V, 4 k-chunks, single-buffered V ----
    for (int cc = 0; cc < 4; cc++) {
      bf16x8 af[2], bfr[OJ];
      const int gk = cc * 4 + quad;
#pragma unroll
      for (int i = 0; i < 2; i++)
        af[i] = *(const bf16x8*)&Ps[(wrow + i * 16 + lrow) * 128 + ((gk ^ (pkey << 1)) << 3)];
#pragma unroll
      for (int j = 0; j < OJ; j++)
        bfr[j] = *(const bf16x8*)&Vs[(wcolO + j * 16 + lrow) * 32 + quad * 8];
#pragma unroll
      for (int i = 0; i < 2; i++)
#pragma unroll
        for (int j = 0; j < OJ; j++)
          accO[i][j] = __builtin_amdgcn_mfma_f32_16x16x32_bf16(af[i], bfr[j], accO[i][j], 0, 0, 0);
      if (cc < 3) {
        __syncthreads();   // all reads of Vs[cc] landed in regs
#pragma unroll
        for (int p = 0; p < DIN / 64; p++) {
          const unsigned short* vsrc =
              Vt + (size_t)(p * 64 + sr) * NN + kt + (cc + 1) * 32 + sch * 8;
          load_lds16(vsrc, (char*)Vs + p * 4096 + t * 16);
        }
        __syncthreads();   // drain V[cc+1]
      }
    }
  }

  // ---- epilogue: un-normalized partials ----
#pragma unroll
  for (int i = 0; i < 2; i++)
#pragma unroll
    for (int j = 0; j < OJ; j++)
#pragma unroll
      for (int r = 0; r < 4; r++) {
        int row = rowBase + wrow + i * 16 + quad * 4 + r;
        int col = wcolO + j * 16 + lrow;
        Opart[((size_t)split * NN + row) * DIN + col] = f2bf(accO[i][j][r]);
      }
  if (lrow == 0 && ch == 0) {
#pragma unroll
    for (int i = 0; i < 2; i++)
#pragma unroll
      for (int r = 0; r < 4; r++) {
        int row = rowBase + wrow + i * 16 + quad * 4 + r;
        mpart[(size_t)split * NN + row] = m_i[i * 4 + r];
        lpart[(size_t)split * NN + row] = l_i[i * 4 + r];
      }
  }
}

// combine NSPLIT flash partials
__global__ void flash_merge(const unsigned short* __restrict__ Op, const float* __restrict__ mp,
                            const float* __restrict__ lp, float* __restrict__ att,
                            int din, int dshift) {
  int idx = blockIdx.x * 256 + threadIdx.x;
  int pair = idx * 2;
  int row = pair >> dshift;
  int f = pair & (din - 1);
  float m[NSPLIT], w[NSPLIT];
  float M = -3.0e38f;
#pragma unroll
  for (int s = 0; s < NSPLIT; s++) { m[s] = mp[(size_t)s * NN + row]; M = fmaxf(M, m[s]); }
  float L = 0.f;
#pragma unroll
  for (int s = 0; s < NSPLIT; s++) { w[s] = __expf(m[s] - M); L += lp[(size_t)s * NN + row] * w[s]; }
  float inv = 1.f / L;
  size_t base = (size_t)row * din + f;
  size_t stride = (size_t)NN * din;
  float a0 = 0.f, a1 = 0.f;
#pragma unroll
  for (int s = 0; s < NSPLIT; s++) {
    unsigned u = *(const unsigned*)(Op + (size_t)s * stride + base);
    a0 += w[s] * bf2f(u & 0xffffu);
    a1 += w[s] * bf2f(u >> 16);
  }
  float2 o; o.x = a0 * inv; o.y = a1 * inv;
  *(float2*)(att + base) = o;
}

// --------------------------- small kernels ---------------------------------

__global__ void ws_sentinel(float* out) { out[0] = 12345.0f; out[1] = 12345.0f; }

__global__ void cvt_bf16(const float* __restrict__ in, unsigned short* __restrict__ out, int n) {
  int i = (blockIdx.x * 256 + threadIdx.x) * 4;
  if (i < n) {
    f32x4 v = *(const f32x4*)(in + i);
    uint2 p;
    p.x = f2bf(v.x) | ((unsigned)f2bf(v.y) << 16);
    p.y = f2bf(v.z) | ((unsigned)f2bf(v.w) << 16);
    *(uint2*)(out + i) = p;
  }
}

__global__ void transpose_bf16(const float* __restrict__ src, unsigned short* __restrict__ dst,
                               int R, int C) {
  __shared__ float tile[32][33];
  int c0 = blockIdx.x * 32, r0 = blockIdx.y * 32;
  int x = threadIdx.x, y = threadIdx.y;
  for (int i = y; i < 32; i += 8) tile[i][x] = src[(size_t)(r0 + i) * C + c0 + x];
  __syncthreads();
  for (int i = y; i < 32; i += 8) dst[(size_t)(c0 + i) * R + r0 + x] = f2bf(tile[x][i]);
}

__global__ void deg_count(const int* __restrict__ dst, int* __restrict__ deg) {
  int e = blockIdx.x * 256 + threadIdx.x;
  atomicAdd(&deg[dst[e]], 1);
}

__global__ void make_dinv(const int* __restrict__ deg, float* __restrict__ dinv) {
  int v = blockIdx.x * 256 + threadIdx.x;
  dinv[v] = rsqrtf((float)(deg[v] + 1));
}

__global__ void scan_deg(const int* __restrict__ deg, int* __restrict__ rowstart) {
  __shared__ int part[1024];
  int t = threadIdx.x;
  int base = t * 8;
  int local[8];
  int s = 0;
#pragma unroll
  for (int i = 0; i < 8; i++) { local[i] = s; s += deg[base + i]; }
  part[t] = s;
  __syncthreads();
  for (int off = 1; off < 1024; off <<= 1) {
    int v = (t >= off) ? part[t - off] : 0;
    __syncthreads();
    part[t] += v;
    __syncthreads();
  }
  int offset = (t == 0) ? 0 : part[t - 1];
#pragma unroll
  for (int i = 0; i < 8; i++) rowstart[base + i] = offset + local[i];
  if (t == 1023) rowstart[8192] = offset + s;
}

__global__ void csr_fill(const int* __restrict__ src, const int* __restrict__ dst,
                         int* __restrict__ cursor, int* __restrict__ csr_src) {
  int e = blockIdx.x * 256 + threadIdx.x;
  int pos = atomicAdd(&cursor[dst[e]], 1);
  csr_src[pos] = src[e];
}

__global__ __launch_bounds__(256) void gcn_agg(
    const int* __restrict__ rowstart, const int* __restrict__ csr_src,
    const float* __restrict__ dinv, const float* __restrict__ h,
    float* __restrict__ c) {
  int node = blockIdx.x * 4 + (threadIdx.x >> 6);
  int lane = threadIdx.x & 63;
  float dn = dinv[node];
  f32x4 acc = *(const f32x4*)(h + (size_t)node * 256 + lane * 4);
  float w0 = dn * dn;
  acc.x *= w0; acc.y *= w0; acc.z *= w0; acc.w *= w0;
  int s0 = rowstart[node], s1 = rowstart[node + 1];
  for (int j = s0; j < s1; j++) {
    int s = csr_src[j];
    float w = dinv[s] * dn;
    f32x4 v = *(const f32x4*)(h + (size_t)s * 256 + lane * 4);
    acc.x += w * v.x; acc.y += w * v.y; acc.z += w * v.z; acc.w += w * v.w;
  }
  *(f32x4*)(c + (size_t)node * 256 + lane * 4) = acc;
}

__global__ void build_cat(const float* __restrict__ cbuf, const float* __restrict__ f,
                          const float* __restrict__ att, unsigned short* __restrict__ cat,
                          int din, int W) {
  int i = blockIdx.y;
  int c = blockIdx.x * 256 + threadIdx.x;
  float v;
  if (c < 256) v = cbuf[(size_t)i * 256 + c];
  else if (c < 256 + din) v = f[(size_t)i * din + (c - 256)];
  else v = f[(size_t)i * din + (c - 256 - din)] - att[(size_t)i * din + (c - 256 - din)];
  cat[(size_t)i * W + c] = f2bf(v);
}

__global__ void gated_pool(const float* __restrict__ q, const float* __restrict__ f,
                           float* __restrict__ p) {
  int col = threadIdx.x;
  int r0 = blockIdx.x * 128;
  float a = 0.f;
  for (int i = r0; i < r0 + 128; i++) {
    float qv = q[(size_t)i * 256 + col];
    a += f[(size_t)i * 256 + col] / (1.f + __expf(-qv));
  }
  atomicAdd(&p[col], a);
}

__global__ void ntn_bilinear(const float* __restrict__ p1, const float* __restrict__ tnW,
                             float* __restrict__ tmp) {
  int c = blockIdx.x * 256 + threadIdx.x;
  float a = 0.f;
#pragma unroll 8
  for (int i = 0; i < 256; i++) a += p1[i] * tnW[(size_t)i * 8192 + c];
  tmp[c] = a;
}

__global__ void ntn_final(const float* __restrict__ tmp, const float* __restrict__ p1,
                          const float* __restrict__ p2, const float* __restrict__ tnWb,
                          const float* __restrict__ tnb, const float* __restrict__ fc1W,
                          const float* __restrict__ fc1b, const float* __restrict__ scW,
                          const float* __restrict__ scb, const float* __restrict__ avgv,
                          float* __restrict__ out) {
  __shared__ float pc[512];
  __shared__ float ntn[32];
  __shared__ float sarr[16];
  int t = threadIdx.x;
  pc[t] = p1[t];
  pc[256 + t] = p2[t];
  __syncthreads();
  if (t < 32) {
    float sc = 0.f;
    for (int j = 0; j < 256; j++) sc += tmp[j * 32 + t] * pc[256 + j];
    float bl = 0.f;
    for (int k = 0; k < 512; k++) bl += tnWb[t * 512 + k] * pc[k];
    float v = sc + bl + tnb[t];
    ntn[t] = v > 0.f ? v : 0.f;
  }
  __syncthreads();
  if (t < 16) {
    float a = fc1b[t];
    for (int i = 0; i < 32; i++) a += ntn[i] * fc1W[i * 16 + t];
    sarr[t] = tanhf(a);
  }
  __syncthreads();
  if (t == 0) {
    float a = scb[0];
    for (int b = 0; b < 16; b++) a += sarr[b] * scW[b];
    float score = 1.f / (1.f + expf(-a));
    out[0] = score;
    out[1] = -logf(score) * avgv[0];
  }
}

// ---------------------------------------------------------------------------

extern "C" void kernel_launch(void* const* d_in, const int* in_sizes, int n_in,
                              void* d_out, int out_size, void* d_ws, size_t ws_size,
                              hipStream_t stream) {
  (void)in_sizes; (void)n_in; (void)out_size;
  const float* feat1 = (const float*)d_in[0];
  const float* feat2 = (const float*)d_in[1];
  const int* ei1 = (const int*)d_in[2];
  const int* ei2 = (const int*)d_in[3];
  const float* avgv = (const float*)d_in[4];
  const float* gcnW[3] = {(const float*)d_in[5], (const float*)d_in[8], (const float*)d_in[11]};
  const float* updW[3] = {(const float*)d_in[6], (const float*)d_in[9], (const float*)d_in[12]};
  const float* updb[3] = {(const float*)d_in[7], (const float*)d_in[10], (const float*)d_in[13]};
  const float* gatedW = (const float*)d_in[14];
  const float* gatedb = (const float*)d_in[15];
  const float* tnW = (const float*)d_in[16];
  const float* tnWb = (const float*)d_in[17];
  const float* tnb = (const float*)d_in[18];
  const float* fc1W = (const float*)d_in[19];
  const float* fc1b = (const float*)d_in[20];
  const float* scW = (const float*)d_in[21];
  const float* scb = (const float*)d_in[22];
  float* out = (float*)d_out;

  char* wp = (char*)d_ws;
  auto take = [&](size_t b) { char* p = wp; wp += (b + 255) & ~(size_t)255; return p; };
  unsigned short* Op = (unsigned short*)take((size_t)NSPLIT * NN * 256 * 2);
  unsigned short* cat1 = Op;
  unsigned short* cat2 = cat1 + (size_t)NN * 768;
  float* fb1 = (float*)take((size_t)NN * 256 * 4);
  float* fb2 = (float*)take((size_t)NN * 256 * 4);
  unsigned short* f1b = (unsigned short*)take((size_t)NN * 256 * 2);
  unsigned short* f2b = (unsigned short*)take((size_t)NN * 256 * 2);
  unsigned short* f1bT = (unsigned short*)take((size_t)NN * 256 * 2);
  unsigned short* f2bT = (unsigned short*)take((size_t)NN * 256 * 2);
  float* h1 = (float*)take((size_t)NN * 256 * 4);
  float* h2 = (float*)take((size_t)NN * 256 * 4);
  float* c1 = (float*)take((size_t)NN * 256 * 4);
  float* c2 = (float*)take((size_t)NN * 256 * 4);
  unsigned short* WgT[3], *WuT[3];
  for (int l = 0; l < 3; l++) WgT[l] = (unsigned short*)take(256 * 256 * 2);
  for (int l = 0; l < 3; l++) WuT[l] = (unsigned short*)take(256 * 768 * 2);
  unsigned short* gWT = (unsigned short*)take(256 * 256 * 2);
  int* deg1 = (int*)take(NN * 4);
  int* deg2 = (int*)take(NN * 4);
  float* dinv1 = (float*)take(NN * 4);
  float* dinv2 = (float*)take(NN * 4);
  int* rs1 = (int*)take((NN + 1) * 4);
  int* rs2 = (int*)take((NN + 1) * 4);
  int* cur1 = (int*)take(NN * 4);
  int* cur2 = (int*)take(NN * 4);
  int* csr1 = (int*)take((size_t)EDG * 4);
  int* csr2 = (int*)take((size_t)EDG * 4);
  float* mp = (float*)take((size_t)NSPLIT * NN * 4);
  float* lp = (float*)take((size_t)NSPLIT * NN * 4);
  float* p1 = (float*)take(1024);
  float* p2 = (float*)take(1024);
  float* tmp = (float*)take(NN * 4);

  size_t need = (size_t)(wp - (char*)d_ws);
  if (need > ws_size) {
    ws_sentinel<<<1, 1, 0, stream>>>(out);
    return;
  }

  // degree / dinv / CSR (edge structure is layer-invariant)
  hipMemsetAsync(deg1, 0, NN * 4, stream);
  hipMemsetAsync(deg2, 0, NN * 4, stream);
  deg_count<<<EDG / 256, 256, 0, stream>>>(ei1 + EDG, deg1);
  deg_count<<<EDG / 256, 256, 0, stream>>>(ei2 + EDG, deg2);
  make_dinv<<<NN / 256, 256, 0, stream>>>(deg1, dinv1);
  make_dinv<<<NN / 256, 256, 0, stream>>>(deg2, dinv2);
  scan_deg<<<1, 1024, 0, stream>>>(deg1, rs1);
  scan_deg<<<1, 1024, 0, stream>>>(deg2, rs2);
  hipMemcpyAsync(cur1, rs1, NN * 4, hipMemcpyDeviceToDevice, stream);
  hipMemcpyAsync(cur2, rs2, NN * 4, hipMemcpyDeviceToDevice, stream);
  csr_fill<<<EDG / 256, 256, 0, stream>>>(ei1, ei1 + EDG, cur1, csr1);
  csr_fill<<<EDG / 256, 256, 0, stream>>>(ei2, ei2 + EDG, cur2, csr2);

  // weights -> bf16 [out][in]
  for (int l = 0; l < 3; l++) {
    int din = (l == 0) ? 128 : 256;
    int W = 256 + 2 * din;
    transpose_bf16<<<dim3(8, din / 32), dim3(32, 8), 0, stream>>>(gcnW[l], WgT[l], din, 256);
    transpose_bf16<<<dim3(8, W / 32), dim3(32, 8), 0, stream>>>(updW[l], WuT[l], W, 256);
  }
  transpose_bf16<<<dim3(8, 8), dim3(32, 8), 0, stream>>>(gatedW, gWT, 256, 256);

  const float* f1 = feat1;
  const float* f2 = feat2;

  for (int l = 0; l < 3; l++) {
    const int din = (l == 0) ? 128 : 256;
    const int dshift = (l == 0) ? 7 : 8;
    const int W = 256 + 2 * din;
    const int nel = NN * din;

    cvt_bf16<<<nel / 1024, 256, 0, stream>>>(f1, f1b, nel);
    cvt_bf16<<<nel / 1024, 256, 0, stream>>>(f2, f2b, nel);
    transpose_bf16<<<dim3(din / 32, NN / 32), dim3(32, 8), 0, stream>>>(f1, f1bT, NN, din);
    transpose_bf16<<<dim3(din / 32, NN / 32), dim3(32, 8), 0, stream>>>(f2, f2bT, NN, din);

    // h = f @ Wg
    gemm_k<0><<<dim3(64, 2), 256, 0, stream>>>(f1b, din, WgT[l], din, nullptr, h1, 256, din);
    gemm_k<0><<<dim3(64, 2), 256, 0, stream>>>(f2b, din, WgT[l], din, nullptr, h2, 256, din);

    // c = D^-1/2 (A+I) D^-1/2 h — CSR gather, no atomics
    gcn_agg<<<NN / 4, 256, 0, stream>>>(rs1, csr1, dinv1, h1, c1);
    gcn_agg<<<NN / 4, 256, 0, stream>>>(rs2, csr2, dinv2, h2, c2);

    // att1 = Flash(Q=f1,K=f2,V=f2); att2 = Flash(Q=f2,K=f1,V=f1) — shared Op
    if (l == 0) {
      flash_att<128><<<dim3(NN / 64, NSPLIT), 256, 0, stream>>>(f1b, f2b, f2bT, Op, mp, lp, NN / NSPLIT);
      flash_merge<<<(NN * din / 2) / 256, 256, 0, stream>>>(Op, mp, lp, h1, din, dshift);
      flash_att<128><<<dim3(NN / 64, NSPLIT), 256, 0, stream>>>(f2b, f1b, f1bT, Op, mp, lp, NN / NSPLIT);
      flash_merge<<<(NN * din / 2) / 256, 256, 0, stream>>>(Op, mp, lp, h2, din, dshift);
    } else {
      flash_att<256><<<dim3(NN / 64, NSPLIT), 256, 0, stream>>>(f1b, f2b, f2bT, Op, mp, lp, NN / NSPLIT);
      flash_merge<<<(NN * din / 2) / 256, 256, 0, stream>>>(Op, mp, lp, h1, din, dshift);
      flash_att<256><<<dim3(NN / 64, NSPLIT), 256, 0, stream>>>(f2b, f1b, f1bT, Op, mp, lp, NN / NSPLIT);
      flash_merge<<<(NN * din / 2) / 256, 256, 0, stream>>>(Op, mp, lp, h2, din, dshift);
    }

    // g = tanh?(concat([c, f, f-att]) @ Wu + bu)  (cat overlaps dead Op)
    build_cat<<<dim3(W / 256, NN), 256, 0, stream>>>(c1, f1, h1, cat1, din, W);
    build_cat<<<dim3(W / 256, NN), 256, 0, stream>>>(c2, f2, h2, cat2, din, W);
    if (l < 2) {
      gemm_k<3><<<dim3(64, 2), 256, 0, stream>>>(cat1, W, WuT[l], W, updb[l], fb1, 256, W);
      gemm_k<3><<<dim3(64, 2), 256, 0, stream>>>(cat2, W, WuT[l], W, updb[l], fb2, 256, W);
    } else {
      gemm_k<2><<<dim3(64, 2), 256, 0, stream>>>(cat1, W, WuT[l], W, updb[l], fb1, 256, W);
      gemm_k<2><<<dim3(64, 2), 256, 0, stream>>>(cat2, W, WuT[l], W, updb[l], fb2, 256, W);
    }
    f1 = fb1;
    f2 = fb2;
  }

  // gated readout
  cvt_bf16<<<NN * 256 / 1024, 256, 0, stream>>>(f1, f1b, NN * 256);
  cvt_bf16<<<NN * 256 / 1024, 256, 0, stream>>>(f2, f2b, NN * 256);
  gemm_k<2><<<dim3(64, 2), 256, 0, stream>>>(f1b, 256, gWT, 256, gatedb, c1, 256, 256);
  gemm_k<2><<<dim3(64, 2), 256, 0, stream>>>(f2b, 256, gWT, 256, gatedb, c2, 256, 256);
  hipMemsetAsync(p1, 0, 256 * 4, stream);
  hipMemsetAsync(p2, 0, 256 * 4, stream);
  gated_pool<<<64, 256, 0, stream>>>(c1, f1, p1);
  gated_pool<<<64, 256, 0, stream>>>(c2, f2, p2);

  // NTN + scoring head
  ntn_bilinear<<<32, 256, 0, stream>>>(p1, tnW, tmp);
  ntn_final<<<1, 256, 0, stream>>>(tmp, p1, p2, tnWb, tnb, fc1W, fc1b, scW, scb, avgv, out);
}

// Round 9
// 1209.173 us; speedup vs baseline: 5.6873x; 1.1795x over previous
//
#include <hip/hip_runtime.h>
#include <hip/hip_bf16.h>
#include <stdint.h>

#define NN 8192
#define EDG 131072
#define NSPLIT 4

typedef __attribute__((ext_vector_type(8))) short bf16x8;
typedef __attribute__((ext_vector_type(4))) float f32x4;
typedef unsigned short us;

__device__ __forceinline__ us f2bf(float f) {
  union { float f; unsigned u; } v; v.f = f;
  return (us)((v.u + 0x7fffu + ((v.u >> 16) & 1u)) >> 16);
}

__device__ __forceinline__ us f2bf_trunc(float f) {
  union { float f; unsigned u; } v; v.f = f;
  return (us)(v.u >> 16);
}

__device__ __forceinline__ float bf2f(us u) {
  union { unsigned u; float f; } v; v.u = ((unsigned)u) << 16;
  return v.f;
}

__device__ __forceinline__ void load_lds16(const void* g, void* l) {
  __builtin_amdgcn_global_load_lds(
      (__attribute__((address_space(1))) void*)(uintptr_t)g,
      (__attribute__((address_space(3))) void*)(uintptr_t)l,
      16, 0, 0);
}

// ---------------------------------------------------------------------------
// C[M,N] = A[M,K]*Bt[N,K]^T, 64x128 tile, wave-per-16-rows. grid=(M/64,N/128).
// EPI 0: fp32; 2: fp32 +bias; 4: bf16 +bias; 5: bf16 tanh(+bias)
// ---------------------------------------------------------------------------
template <int EPI>
__global__ __launch_bounds__(256) void gemm_k(
    const us* __restrict__ A, int lda, const us* __restrict__ Bt, int ldb,
    const float* __restrict__ bias, void* __restrict__ Cv, int ldc, int K) {
  __shared__ alignas(16) us As[64 * 32];
  __shared__ alignas(16) us Bs[128 * 32];
  const int t = threadIdx.x;
  const int wave = t >> 6, lane = t & 63;
  const int wrow = wave * 16;
  const int lrow = lane & 15, quad = lane >> 4;
  const int rowBase = blockIdx.x * 64;
  const int colBase = blockIdx.y * 128;
  const int sr = t >> 2, sch = t & 3;

  f32x4 acc[8];
#pragma unroll
  for (int j = 0; j < 8; j++) acc[j] = f32x4{0.f, 0.f, 0.f, 0.f};

  for (int kb = 0; kb < K; kb += 32) {
    __syncthreads();
    const us* asrc = A + (size_t)(rowBase + sr) * lda + kb + sch * 8;
    load_lds16(asrc, (char*)As + t * 16);
    const us* bsrc = Bt + (size_t)(colBase + sr) * ldb + kb + sch * 8;
    load_lds16(bsrc, (char*)Bs + t * 16);
    load_lds16(bsrc + (size_t)64 * ldb, (char*)Bs + t * 16 + 4096);
    __syncthreads();
    bf16x8 af = *(const bf16x8*)&As[(wrow + lrow) * 32 + quad * 8];
#pragma unroll
    for (int j = 0; j < 8; j++) {
      bf16x8 bfr = *(const bf16x8*)&Bs[(j * 16 + lrow) * 32 + quad * 8];
      acc[j] = __builtin_amdgcn_mfma_f32_16x16x32_bf16(af, bfr, acc[j], 0, 0, 0);
    }
  }

#pragma unroll
  for (int j = 0; j < 8; j++) {
    int col = colBase + j * 16 + lrow;
#pragma unroll
    for (int r = 0; r < 4; r++) {
      int row = rowBase + wrow + quad * 4 + r;
      size_t idx = (size_t)row * ldc + col;
      float v = acc[j][r];
      if (EPI == 0) ((float*)Cv)[idx] = v;
      else if (EPI == 2) ((float*)Cv)[idx] = v + bias[col];
      else if (EPI == 4) ((us*)Cv)[idx] = f2bf(v + bias[col]);
      else ((us*)Cv)[idx] = f2bf(tanhf(v + bias[col]));
    }
  }
}

// ---------------------------------------------------------------------------
// Flash attention, wave-per-16-rows (wave-local softmax), full dbuf staging.
// Q[NN][DIN],K[NN][DIN] bf16; Vt[DIN][NN] bf16. grid=(NN/64, NSPLIT).
// Ps (64x128) aliases the K double-buffer; Q/K/V all double-buffered with
// cross-kt V0/Q0 prefetch. LDS 56 KB (DIN=256, 2 blk/CU) / 40 KB (128, 3).
// ---------------------------------------------------------------------------
template <int DIN>
__global__ __launch_bounds__(256, (DIN == 128) ? 3 : 2) void flash_att(
    const us* __restrict__ Q, const us* __restrict__ K,
    const us* __restrict__ Vt, us* __restrict__ Opart,
    float* __restrict__ mpart, float* __restrict__ lpart, int kvPerSplit) {
  constexpr int NKC = DIN / 32;   // S-phase k chunks
  constexpr int OJ = DIN / 16;    // O col-tiles per wave (full DIN)
  __shared__ alignas(16) us As[2][64 * 32];     // Q dbuf (8 KB)
  __shared__ alignas(16) us KB[2][128 * 32];    // K dbuf (16 KB); Ps alias
  __shared__ alignas(16) us Vs[2][DIN * 32];    // V dbuf (16/32 KB)
  us* Ps = &KB[0][0];                           // 64x128

  const int t = threadIdx.x;
  const int wave = t >> 6, lane = t & 63;
  const int wrow = wave * 16;
  const int lrow = lane & 15, quad = lane >> 4;
  const int rowBase = blockIdx.x * 64;
  const int split = blockIdx.y;
  const int kv0 = split * kvPerSplit;
  const int sr = t >> 2, sch = t & 3;
  const int pkey = ((lrow >> 2) ^ lrow) & 3;

  auto stageQ = [&](int kc, int buf) {
    const us* qsrc = Q + (size_t)(rowBase + sr) * DIN + kc * 32 + sch * 8;
    load_lds16(qsrc, (char*)&As[buf][0] + t * 16);
  };
  auto stageK = [&](int kt, int kc, int buf) {
    const us* ksrc = K + (size_t)(kt + sr) * DIN + kc * 32 + sch * 8;
    load_lds16(ksrc, (char*)&KB[buf][0] + t * 16);
    load_lds16(ksrc + (size_t)64 * DIN, (char*)&KB[buf][0] + t * 16 + 4096);
  };
  auto stageV = [&](int kt, int cc, int buf) {
#pragma unroll
    for (int p = 0; p < DIN / 64; p++) {
      const us* vsrc = Vt + (size_t)(p * 64 + sr) * NN + kt + cc * 32 + sch * 8;
      load_lds16(vsrc, (char*)&Vs[buf][0] + p * 4096 + t * 16);
    }
  };

  stageQ(0, 0);
  stageV(kv0, 0, 0);

  float m_i[4], l_i[4];
#pragma unroll
  for (int r = 0; r < 4; r++) { m_i[r] = -3.0e38f; l_i[r] = 0.f; }
  f32x4 accO[OJ];
#pragma unroll
  for (int j = 0; j < OJ; j++) accO[j] = f32x4{0.f, 0.f, 0.f, 0.f};

  for (int kt = kv0; kt < kv0 + kvPerSplit; kt += 128) {
    __syncthreads();                 // E: prev PV's Ps (KB) + Vs reads done
    stageK(kt, 0, 0);

    // ---- Phase 1: S = Q @ K^T ----
    f32x4 accS[8];
#pragma unroll
    for (int j = 0; j < 8; j++) accS[j] = f32x4{0.f, 0.f, 0.f, 0.f};
    for (int kc = 0; kc < NKC; kc++) {
      const int buf = kc & 1;
      __syncthreads();               // drain Q/K chunk kc
      if (kc + 1 < NKC) { stageK(kt, kc + 1, buf ^ 1); stageQ(kc + 1, buf ^ 1); }
      bf16x8 af = *(const bf16x8*)&As[buf][(wrow + lrow) * 32 + quad * 8];
#pragma unroll
      for (int j = 0; j < 8; j++) {
        bf16x8 bfr = *(const bf16x8*)&KB[buf][(j * 16 + lrow) * 32 + quad * 8];
        accS[j] = __builtin_amdgcn_mfma_f32_16x16x32_bf16(af, bfr, accS[j], 0, 0, 0);
      }
    }

    // ---- Phase 2: wave-local online softmax (rows wrow..wrow+15) ----
    float alpha[4];
#pragma unroll
    for (int r = 0; r < 4; r++) {
      float v = accS[0][r];
#pragma unroll
      for (int j = 1; j < 8; j++) v = fmaxf(v, accS[j][r]);
#pragma unroll
      for (int mask = 1; mask < 16; mask <<= 1) v = fmaxf(v, __shfl_xor(v, mask));
      float mn = fmaxf(m_i[r], v);
      alpha[r] = __expf(m_i[r] - mn);
      m_i[r] = mn;
    }
    __syncthreads();                 // B1: all KB reads done -> Ps writes safe;
                                     //     also drains V0 (long in flight)
    float ts[4] = {0.f, 0.f, 0.f, 0.f};
#pragma unroll
    for (int j = 0; j < 8; j++)
#pragma unroll
      for (int r = 0; r < 4; r++) {
        float p = __expf(accS[j][r] - m_i[r]);
        ts[r] += p;
        int prow = wrow + quad * 4 + r;
        int key = (quad ^ r) & 3;
        int g = (j * 16 + lrow) >> 3;
        Ps[prow * 128 + ((g ^ (key << 1)) << 3) + (lrow & 7)] = f2bf_trunc(p);
      }
#pragma unroll
    for (int r = 0; r < 4; r++) {
      float v = ts[r];
#pragma unroll
      for (int mask = 1; mask < 16; mask <<= 1) v += __shfl_xor(v, mask);
      l_i[r] = l_i[r] * alpha[r] + v;
    }
#pragma unroll
    for (int j = 0; j < OJ; j++)
#pragma unroll
      for (int r = 0; r < 4; r++) accO[j][r] *= alpha[r];

    // ---- Phase 3: O += P @ V (Ps rows are wave-private; V dbuf) ----
    const bool hasNext = (kt + 128 < kv0 + kvPerSplit);
    for (int cc = 0; cc < 4; cc++) {
      if (cc) __syncthreads();       // drain V[cc]
      if (cc + 1 < 4) stageV(kt, cc + 1, (cc + 1) & 1);
      else if (hasNext) { stageV(kt + 128, 0, 0); stageQ(0, 0); }
      const int gk = cc * 4 + quad;
      bf16x8 af = *(const bf16x8*)&Ps[(wrow + lrow) * 128 + ((gk ^ (pkey << 1)) << 3)];
      const us* vb = &Vs[cc & 1][0];
#pragma unroll
      for (int j = 0; j < OJ; j++) {
        bf16x8 bfr = *(const bf16x8*)&vb[(j * 16 + lrow) * 32 + quad * 8];
        accO[j] = __builtin_amdgcn_mfma_f32_16x16x32_bf16(af, bfr, accO[j], 0, 0, 0);
      }
    }
  }

  // ---- epilogue: un-normalized partials ----
#pragma unroll
  for (int j = 0; j < OJ; j++)
#pragma unroll
    for (int r = 0; r < 4; r++) {
      int row = rowBase + wrow + quad * 4 + r;
      int col = j * 16 + lrow;
      Opart[((size_t)split * NN + row) * DIN + col] = f2bf(accO[j][r]);
    }
  if (lrow == 0) {
#pragma unroll
    for (int r = 0; r < 4; r++) {
      int row = rowBase + wrow + quad * 4 + r;
      mpart[(size_t)split * NN + row] = m_i[r];
      lpart[(size_t)split * NN + row] = l_i[r];
    }
  }
}

// fused: merge NSPLIT flash partials + build cat = bf16([c | f | f-att])
__global__ void merge_cat(const us* __restrict__ Op, const float* __restrict__ mp,
                          const float* __restrict__ lp, const float* __restrict__ cbuf,
                          const us* __restrict__ fbf, us* __restrict__ cat,
                          int din, int W) {
  int i = blockIdx.y;
  int c = blockIdx.x * 256 + threadIdx.x;
  us o;
  if (c < 256) {
    o = f2bf(cbuf[(size_t)i * 256 + c]);
  } else if (c < 256 + din) {
    o = fbf[(size_t)i * din + (c - 256)];
  } else {
    int f = c - 256 - din;
    float m[NSPLIT], w[NSPLIT];
    float M = -3.0e38f;
#pragma unroll
    for (int s = 0; s < NSPLIT; s++) { m[s] = mp[(size_t)s * NN + i]; M = fmaxf(M, m[s]); }
    float L = 0.f;
#pragma unroll
    for (int s = 0; s < NSPLIT; s++) { w[s] = __expf(m[s] - M); L += lp[(size_t)s * NN + i] * w[s]; }
    float a = 0.f;
#pragma unroll
    for (int s = 0; s < NSPLIT; s++)
      a += w[s] * bf2f(Op[((size_t)s * NN + i) * din + f]);
    o = f2bf(bf2f(fbf[(size_t)i * din + f]) - a / L);
  }
  cat[(size_t)i * W + c] = o;
}

// --------------------------- small kernels ---------------------------------

__global__ void ws_sentinel(float* out) { out[0] = 12345.0f; out[1] = 12345.0f; }

__global__ void cvt_bf16(const float* __restrict__ in, us* __restrict__ out, int n) {
  int i = (blockIdx.x * 256 + threadIdx.x) * 4;
  if (i < n) {
    f32x4 v = *(const f32x4*)(in + i);
    uint2 p;
    p.x = f2bf(v.x) | ((unsigned)f2bf(v.y) << 16);
    p.y = f2bf(v.z) | ((unsigned)f2bf(v.w) << 16);
    *(uint2*)(out + i) = p;
  }
}

// dst[C][R] = bf16(src[R][C]), fp32 source
__global__ void transpose_bf16(const float* __restrict__ src, us* __restrict__ dst,
                               int R, int C) {
  __shared__ float tile[32][33];
  int c0 = blockIdx.x * 32, r0 = blockIdx.y * 32;
  int x = threadIdx.x, y = threadIdx.y;
  for (int i = y; i < 32; i += 8) tile[i][x] = src[(size_t)(r0 + i) * C + c0 + x];
  __syncthreads();
  for (int i = y; i < 32; i += 8) dst[(size_t)(c0 + i) * R + r0 + x] = f2bf(tile[x][i]);
}

// dst[C][R] = src[R][C], bf16 source
__global__ void transpose_bb(const us* __restrict__ src, us* __restrict__ dst,
                             int R, int C) {
  __shared__ us tile[32][33];
  int c0 = blockIdx.x * 32, r0 = blockIdx.y * 32;
  int x = threadIdx.x, y = threadIdx.y;
  for (int i = y; i < 32; i += 8) tile[i][x] = src[(size_t)(r0 + i) * C + c0 + x];
  __syncthreads();
  for (int i = y; i < 32; i += 8) dst[(size_t)(c0 + i) * R + r0 + x] = tile[x][i];
}

__global__ void deg_count(const int* __restrict__ dst, int* __restrict__ deg) {
  int e = blockIdx.x * 256 + threadIdx.x;
  atomicAdd(&deg[dst[e]], 1);
}

__global__ void make_dinv(const int* __restrict__ deg, float* __restrict__ dinv) {
  int v = blockIdx.x * 256 + threadIdx.x;
  dinv[v] = rsqrtf((float)(deg[v] + 1));
}

__global__ void scan_deg(const int* __restrict__ deg, int* __restrict__ rowstart) {
  __shared__ int part[1024];
  int t = threadIdx.x;
  int base = t * 8;
  int local[8];
  int s = 0;
#pragma unroll
  for (int i = 0; i < 8; i++) { local[i] = s; s += deg[base + i]; }
  part[t] = s;
  __syncthreads();
  for (int off = 1; off < 1024; off <<= 1) {
    int v = (t >= off) ? part[t - off] : 0;
    __syncthreads();
    part[t] += v;
    __syncthreads();
  }
  int offset = (t == 0) ? 0 : part[t - 1];
#pragma unroll
  for (int i = 0; i < 8; i++) rowstart[base + i] = offset + local[i];
  if (t == 1023) rowstart[8192] = offset + s;
}

__global__ void csr_fill(const int* __restrict__ src, const int* __restrict__ dst,
                         int* __restrict__ cursor, int* __restrict__ csr_src) {
  int e = blockIdx.x * 256 + threadIdx.x;
  int pos = atomicAdd(&cursor[dst[e]], 1);
  csr_src[pos] = src[e];
}

__global__ __launch_bounds__(256) void gcn_agg(
    const int* __restrict__ rowstart, const int* __restrict__ csr_src,
    const float* __restrict__ dinv, const float* __restrict__ h,
    float* __restrict__ c) {
  int node = blockIdx.x * 4 + (threadIdx.x >> 6);
  int lane = threadIdx.x & 63;
  float dn = dinv[node];
  f32x4 acc = *(const f32x4*)(h + (size_t)node * 256 + lane * 4);
  float w0 = dn * dn;
  acc.x *= w0; acc.y *= w0; acc.z *= w0; acc.w *= w0;
  int s0 = rowstart[node], s1 = rowstart[node + 1];
  for (int j = s0; j < s1; j++) {
    int s = csr_src[j];
    float w = dinv[s] * dn;
    f32x4 v = *(const f32x4*)(h + (size_t)s * 256 + lane * 4);
    acc.x += w * v.x; acc.y += w * v.y; acc.z += w * v.z; acc.w += w * v.w;
  }
  *(f32x4*)(c + (size_t)node * 256 + lane * 4) = acc;
}

__global__ void gated_pool(const float* __restrict__ q, const us* __restrict__ f,
                           float* __restrict__ p) {
  int col = threadIdx.x;
  int r0 = blockIdx.x * 128;
  float a = 0.f;
  for (int i = r0; i < r0 + 128; i++) {
    float qv = q[(size_t)i * 256 + col];
    a += bf2f(f[(size_t)i * 256 + col]) / (1.f + __expf(-qv));
  }
  atomicAdd(&p[col], a);
}

__global__ void ntn_bilinear(const float* __restrict__ p1, const float* __restrict__ tnW,
                             float* __restrict__ tmp) {
  int c = blockIdx.x * 256 + threadIdx.x;
  float a = 0.f;
#pragma unroll 8
  for (int i = 0; i < 256; i++) a += p1[i] * tnW[(size_t)i * 8192 + c];
  tmp[c] = a;
}

__global__ void ntn_final(const float* __restrict__ tmp, const float* __restrict__ p1,
                          const float* __restrict__ p2, const float* __restrict__ tnWb,
                          const float* __restrict__ tnb, const float* __restrict__ fc1W,
                          const float* __restrict__ fc1b, const float* __restrict__ scW,
                          const float* __restrict__ scb, const float* __restrict__ avgv,
                          float* __restrict__ out) {
  __shared__ float pc[512];
  __shared__ float ntn[32];
  __shared__ float sarr[16];
  int t = threadIdx.x;
  pc[t] = p1[t];
  pc[256 + t] = p2[t];
  __syncthreads();
  if (t < 32) {
    float sc = 0.f;
    for (int j = 0; j < 256; j++) sc += tmp[j * 32 + t] * pc[256 + j];
    float bl = 0.f;
    for (int k = 0; k < 512; k++) bl += tnWb[t * 512 + k] * pc[k];
    float v = sc + bl + tnb[t];
    ntn[t] = v > 0.f ? v : 0.f;
  }
  __syncthreads();
  if (t < 16) {
    float a = fc1b[t];
    for (int i = 0; i < 32; i++) a += ntn[i] * fc1W[i * 16 + t];
    sarr[t] = tanhf(a);
  }
  __syncthreads();
  if (t == 0) {
    float a = scb[0];
    for (int b = 0; b < 16; b++) a += sarr[b] * scW[b];
    float score = 1.f / (1.f + expf(-a));
    out[0] = score;
    out[1] = -logf(score) * avgv[0];
  }
}

// ---------------------------------------------------------------------------

extern "C" void kernel_launch(void* const* d_in, const int* in_sizes, int n_in,
                              void* d_out, int out_size, void* d_ws, size_t ws_size,
                              hipStream_t stream) {
  (void)in_sizes; (void)n_in; (void)out_size;
  const float* feat1 = (const float*)d_in[0];
  const float* feat2 = (const float*)d_in[1];
  const int* ei1 = (const int*)d_in[2];
  const int* ei2 = (const int*)d_in[3];
  const float* avgv = (const float*)d_in[4];
  const float* gcnW[3] = {(const float*)d_in[5], (const float*)d_in[8], (const float*)d_in[11]};
  const float* updW[3] = {(const float*)d_in[6], (const float*)d_in[9], (const float*)d_in[12]};
  const float* updb[3] = {(const float*)d_in[7], (const float*)d_in[10], (const float*)d_in[13]};
  const float* gatedW = (const float*)d_in[14];
  const float* gatedb = (const float*)d_in[15];
  const float* tnW = (const float*)d_in[16];
  const float* tnWb = (const float*)d_in[17];
  const float* tnb = (const float*)d_in[18];
  const float* fc1W = (const float*)d_in[19];
  const float* fc1b = (const float*)d_in[20];
  const float* scW = (const float*)d_in[21];
  const float* scb = (const float*)d_in[22];
  float* out = (float*)d_out;

  char* wp = (char*)d_ws;
  auto take = [&](size_t b) { char* p = wp; wp += (b + 255) & ~(size_t)255; return p; };
  us* Op = (us*)take((size_t)NSPLIT * NN * 256 * 2);           // 16 MB
  us* cat1 = (us*)take((size_t)NN * 768 * 2);
  us* cat2 = (us*)take((size_t)NN * 768 * 2);
  us* fA1 = (us*)take((size_t)NN * 256 * 2);                   // f (bf16), ping
  us* fA2 = (us*)take((size_t)NN * 256 * 2);
  us* fB1 = (us*)take((size_t)NN * 256 * 2);                   // pong
  us* fB2 = (us*)take((size_t)NN * 256 * 2);
  us* f1bT = (us*)take((size_t)NN * 256 * 2);
  us* f2bT = (us*)take((size_t)NN * 256 * 2);
  float* h1 = (float*)take((size_t)NN * 256 * 4);
  float* h2 = (float*)take((size_t)NN * 256 * 4);
  float* c1 = (float*)take((size_t)NN * 256 * 4);
  float* c2 = (float*)take((size_t)NN * 256 * 4);
  us* WgT[3], *WuT[3];
  for (int l = 0; l < 3; l++) WgT[l] = (us*)take(256 * 256 * 2);
  for (int l = 0; l < 3; l++) WuT[l] = (us*)take(256 * 768 * 2);
  us* gWT = (us*)take(256 * 256 * 2);
  int* deg1 = (int*)take(NN * 4);
  int* deg2 = (int*)take(NN * 4);
  float* dinv1 = (float*)take(NN * 4);
  float* dinv2 = (float*)take(NN * 4);
  int* rs1 = (int*)take((NN + 1) * 4);
  int* rs2 = (int*)take((NN + 1) * 4);
  int* cur1 = (int*)take(NN * 4);
  int* cur2 = (int*)take(NN * 4);
  int* csr1 = (int*)take((size_t)EDG * 4);
  int* csr2 = (int*)take((size_t)EDG * 4);
  float* mp = (float*)take((size_t)NSPLIT * NN * 4);
  float* lp = (float*)take((size_t)NSPLIT * NN * 4);
  float* p1 = (float*)take(1024);
  float* p2 = (float*)take(1024);
  float* tmp = (float*)take(NN * 4);

  size_t need = (size_t)(wp - (char*)d_ws);
  if (need > ws_size) {
    ws_sentinel<<<1, 1, 0, stream>>>(out);
    return;
  }

  // degree / dinv / CSR (edge structure is layer-invariant)
  hipMemsetAsync(deg1, 0, NN * 4, stream);
  hipMemsetAsync(deg2, 0, NN * 4, stream);
  deg_count<<<EDG / 256, 256, 0, stream>>>(ei1 + EDG, deg1);
  deg_count<<<EDG / 256, 256, 0, stream>>>(ei2 + EDG, deg2);
  make_dinv<<<NN / 256, 256, 0, stream>>>(deg1, dinv1);
  make_dinv<<<NN / 256, 256, 0, stream>>>(deg2, dinv2);
  scan_deg<<<1, 1024, 0, stream>>>(deg1, rs1);
  scan_deg<<<1, 1024, 0, stream>>>(deg2, rs2);
  hipMemcpyAsync(cur1, rs1, NN * 4, hipMemcpyDeviceToDevice, stream);
  hipMemcpyAsync(cur2, rs2, NN * 4, hipMemcpyDeviceToDevice, stream);
  csr_fill<<<EDG / 256, 256, 0, stream>>>(ei1, ei1 + EDG, cur1, csr1);
  csr_fill<<<EDG / 256, 256, 0, stream>>>(ei2, ei2 + EDG, cur2, csr2);

  // weights -> bf16 [out][in]
  for (int l = 0; l < 3; l++) {
    int din = (l == 0) ? 128 : 256;
    int W = 256 + 2 * din;
    transpose_bf16<<<dim3(8, din / 32), dim3(32, 8), 0, stream>>>(gcnW[l], WgT[l], din, 256);
    transpose_bf16<<<dim3(8, W / 32), dim3(32, 8), 0, stream>>>(updW[l], WuT[l], W, 256);
  }
  transpose_bf16<<<dim3(8, 8), dim3(32, 8), 0, stream>>>(gatedW, gWT, 256, 256);

  // f (bf16) ping-pong
  us* f1 = fA1; us* f2 = fA2;
  us* fn1 = fB1; us* fn2 = fB2;
  cvt_bf16<<<NN * 128 / 1024, 256, 0, stream>>>(feat1, f1, NN * 128);
  cvt_bf16<<<NN * 128 / 1024, 256, 0, stream>>>(feat2, f2, NN * 128);

  for (int l = 0; l < 3; l++) {
    const int din = (l == 0) ? 128 : 256;
    const int W = 256 + 2 * din;

    if (l == 0) {
      transpose_bf16<<<dim3(din / 32, NN / 32), dim3(32, 8), 0, stream>>>(feat1, f1bT, NN, din);
      transpose_bf16<<<dim3(din / 32, NN / 32), dim3(32, 8), 0, stream>>>(feat2, f2bT, NN, din);
    } else {
      transpose_bb<<<dim3(din / 32, NN / 32), dim3(32, 8), 0, stream>>>(f1, f1bT, NN, din);
      transpose_bb<<<dim3(din / 32, NN / 32), dim3(32, 8), 0, stream>>>(f2, f2bT, NN, din);
    }

    // h = f @ Wg  (fp32 out)
    gemm_k<0><<<dim3(128, 2), 256, 0, stream>>>(f1, din, WgT[l], din, nullptr, h1, 256, din);
    gemm_k<0><<<dim3(128, 2), 256, 0, stream>>>(f2, din, WgT[l], din, nullptr, h2, 256, din);

    // c = D^-1/2 (A+I) D^-1/2 h
    gcn_agg<<<NN / 4, 256, 0, stream>>>(rs1, csr1, dinv1, h1, c1);
    gcn_agg<<<NN / 4, 256, 0, stream>>>(rs2, csr2, dinv2, h2, c2);

    // att1 = Flash(Q=f1,K=f2,V=f2) -> fused merge+cat; then att2 reuses Op
    if (l == 0) {
      flash_att<128><<<dim3(NN / 64, NSPLIT), 256, 0, stream>>>(f1, f2, f2bT, Op, mp, lp, NN / NSPLIT);
      merge_cat<<<dim3(W / 256, NN), 256, 0, stream>>>(Op, mp, lp, c1, f1, cat1, din, W);
      flash_att<128><<<dim3(NN / 64, NSPLIT), 256, 0, stream>>>(f2, f1, f1bT, Op, mp, lp, NN / NSPLIT);
      merge_cat<<<dim3(W / 256, NN), 256, 0, stream>>>(Op, mp, lp, c2, f2, cat2, din, W);
    } else {
      flash_att<256><<<dim3(NN / 64, NSPLIT), 256, 0, stream>>>(f1, f2, f2bT, Op, mp, lp, NN / NSPLIT);
      merge_cat<<<dim3(W / 256, NN), 256, 0, stream>>>(Op, mp, lp, c1, f1, cat1, din, W);
      flash_att<256><<<dim3(NN / 64, NSPLIT), 256, 0, stream>>>(f2, f1, f1bT, Op, mp, lp, NN / NSPLIT);
      merge_cat<<<dim3(W / 256, NN), 256, 0, stream>>>(Op, mp, lp, c2, f2, cat2, din, W);
    }

    // g = tanh?(cat @ Wu + bu) -> bf16 directly
    if (l < 2) {
      gemm_k<5><<<dim3(128, 2), 256, 0, stream>>>(cat1, W, WuT[l], W, updb[l], fn1, 256, W);
      gemm_k<5><<<dim3(128, 2), 256, 0, stream>>>(cat2, W, WuT[l], W, updb[l], fn2, 256, W);
    } else {
      gemm_k<4><<<dim3(128, 2), 256, 0, stream>>>(cat1, W, WuT[l], W, updb[l], fn1, 256, W);
      gemm_k<4><<<dim3(128, 2), 256, 0, stream>>>(cat2, W, WuT[l], W, updb[l], fn2, 256, W);
    }
    us* s;
    s = f1; f1 = fn1; fn1 = s;
    s = f2; f2 = fn2; fn2 = s;
  }

  // gated readout: q = f@gW+gb (fp32), p = sum sigmoid(q)*f
  gemm_k<2><<<dim3(128, 2), 256, 0, stream>>>(f1, 256, gWT, 256, gatedb, c1, 256, 256);
  gemm_k<2><<<dim3(128, 2), 256, 0, stream>>>(f2, 256, gWT, 256, gatedb, c2, 256, 256);
  hipMemsetAsync(p1, 0, 256 * 4, stream);
  hipMemsetAsync(p2, 0, 256 * 4, stream);
  gated_pool<<<64, 256, 0, stream>>>(c1, f1, p1);
  gated_pool<<<64, 256, 0, stream>>>(c2, f2, p2);

  // NTN + scoring head
  ntn_bilinear<<<32, 256, 0, stream>>>(p1, tnW, tmp);
  ntn_final<<<1, 256, 0, stream>>>(tmp, p1, p2, tnWb, tnb, fc1W, fc1b, scW, scb, avgv, out);
}